// Round 2
// 1038.593 us; speedup vs baseline: 1.0445x; 1.0445x over previous
//
#include <hip/hip_runtime.h>
#include <cstddef>

typedef __attribute__((ext_vector_type(8))) short bf16x8;
typedef __attribute__((ext_vector_type(4))) float f32x4;

#define DEV __device__ __forceinline__
#define MFMA16(a,b,c) __builtin_amdgcn_mfma_f32_16x16x32_bf16((a),(b),(c),0,0,0)

DEV unsigned short f2bf(float f){
  unsigned int x = __float_as_uint(f);
  x += 0x7fffu + ((x >> 16) & 1u);
  return (unsigned short)(x >> 16);
}
DEV unsigned int pack2(float a, float b){
  return (unsigned int)f2bf(a) | ((unsigned int)f2bf(b) << 16);
}
// branchless erf-GELU, Abramowitz-Stegun 7.1.26 (|err| <= 1.5e-7)
DEV float gelu_f(float x){
  float z = fabsf(x) * 0.7071067811865475f;
  float tt = 1.f / (1.f + 0.3275911f * z);
  float poly = tt*(0.254829592f + tt*(-0.284496736f + tt*(1.421413741f +
               tt*(-1.453152027f + tt*1.061405429f))));
  float er = 1.f - poly * __expf(-z*z);
  er = (x < 0.f) ? -er : er;
  return 0.5f * x * (1.f + er);
}

// ---------------- all weight transposes + bf16 cast in one launch ----------------
__global__ void transpose_cast_all(const float* __restrict__ qkvw, const float* __restrict__ projw,
                                   const float* __restrict__ fc1w, const float* __restrict__ fc2w,
                                   unsigned short* __restrict__ qkvB, unsigned short* __restrict__ projB,
                                   unsigned short* __restrict__ fc1B, unsigned short* __restrict__ fc2B){
  int blk = blockIdx.x;
  const float* in; unsigned short* outp; int K, N, idx;
  if (blk < 432){        in = qkvw; outp = qkvB; K = 192; N = 576; idx = blk*256 + threadIdx.x; }
  else if (blk < 576){   in = projw; outp = projB; K = 192; N = 192; idx = (blk-432)*256 + threadIdx.x; }
  else if (blk < 1152){  in = fc1w; outp = fc1B; K = 192; N = 768; idx = (blk-576)*256 + threadIdx.x; }
  else {                 in = fc2w; outp = fc2B; K = 768; N = 192; idx = (blk-1152)*256 + threadIdx.x; }
  if (idx < K * N){
    int n = idx / K, k = idx - n * K;
    outp[idx] = f2bf(in[k * N + n]);
  }
}

// ---------------- GroupNorm stage 1 ----------------
__global__ void gn_partial(const float* __restrict__ x, float* __restrict__ part){
  int bc = blockIdx.x, tid = threadIdx.x;
  const float4* p = (const float4*)(x + (size_t)bc * 16384);
  float s = 0.f, s2 = 0.f;
  for (int i = tid; i < 4096; i += 256){
    float4 v = p[i];
    s  += v.x + v.y + v.z + v.w;
    s2 += v.x*v.x + v.y*v.y + v.z*v.z + v.w*v.w;
  }
  #pragma unroll
  for (int off = 32; off; off >>= 1){ s += __shfl_down(s, off); s2 += __shfl_down(s2, off); }
  __shared__ float red[8];
  int wid = tid >> 6;
  if ((tid & 63) == 0){ red[wid*2] = s; red[wid*2+1] = s2; }
  __syncthreads();
  if (tid == 0){
    part[bc*2]   = red[0] + red[2] + red[4] + red[6];
    part[bc*2+1] = red[1] + red[3] + red[5] + red[7];
  }
}

// ---------------- GroupNorm stage 2 ----------------
__global__ void gn_final(const float* __restrict__ part, float* __restrict__ stats){
  int b = blockIdx.x, tid = threadIdx.x;
  float s = 0.f, s2 = 0.f;
  for (int c = tid; c < 192; c += 64){
    s  += part[(b*192 + c)*2];
    s2 += part[(b*192 + c)*2 + 1];
  }
  #pragma unroll
  for (int off = 32; off; off >>= 1){ s += __shfl_down(s, off); s2 += __shfl_down(s2, off); }
  if (tid == 0){
    const float inv = 1.f / (192.f * 16384.f);
    float mean = s * inv;
    float var  = s2 * inv - mean*mean;
    stats[b*2]   = mean;
    stats[b*2+1] = rsqrtf(var + 1e-5f);
  }
}

// ---------------- GN apply + NCHW -> NHWC ----------------
__global__ void gn_apply(const float* __restrict__ x, const float* __restrict__ stats,
                         const float* __restrict__ gnw, const float* __restrict__ gnb,
                         float* __restrict__ xb){
  __shared__ float tile[192*64];
  int blk = blockIdx.x, tid = threadIdx.x;
  int b = blk >> 8, p0 = (blk & 255) * 64;
  float mean = stats[b*2], rstd = stats[b*2+1];
  #pragma unroll 1
  for (int i = 0; i < 12; i++){
    int idx4 = i*256 + tid;
    int c = idx4 >> 4, pq = idx4 & 15;
    float4 v = *(const float4*)(x + (((size_t)b*192 + c) << 14) + p0 + pq*4);
    float w  = gnw[c] * rstd;
    float bb = gnb[c] - mean * rstd * gnw[c];
    int pb_ = pq*4;
    tile[c*64 + ((pb_     + c) & 63)] = v.x * w + bb;
    tile[c*64 + ((pb_ + 1 + c) & 63)] = v.y * w + bb;
    tile[c*64 + ((pb_ + 2 + c) & 63)] = v.z * w + bb;
    tile[c*64 + ((pb_ + 3 + c) & 63)] = v.w * w + bb;
  }
  __syncthreads();
  #pragma unroll 1
  for (int i = 0; i < 12; i++){
    int idx4 = i*256 + tid;
    int pix = idx4 / 48, c4 = idx4 - pix*48;
    int cb = c4 * 4;
    float4 o;
    o.x = tile[(cb  )*64 + ((pix + cb    ) & 63)];
    o.y = tile[(cb+1)*64 + ((pix + cb + 1) & 63)];
    o.z = tile[(cb+2)*64 + ((pix + cb + 2) & 63)];
    o.w = tile[(cb+3)*64 + ((pix + cb + 3) & 63)];
    *(float4*)(xb + ((size_t)blk*64 + pix)*192 + cb) = o;
  }
}

// ---------------- fused window attention (MFMA) ----------------
// LDS (XOR-swizzled rows: byte_in_row ^= (row&7)<<4; rows are 128B/384B pow2):
//   h16 @0      [64 tok][384B]     LN1 out (rewritten from regs each pair)  24576
//   ps  @0      [64 tok][128B]     P bf16  (alias of h16, attention phase)   8192
//   ctx @8192   [64 tok][128B]     pair attention out (2 heads x 32d)        8192
//   qkp @24576  [2 head][64 tok][128B: q(64B)|k(64B)]                       16384
//   vT  @40960  [2 head][32 d][128B = 64 tok bf16]                           8192
//   regions @49152 int[64]                                                    256
//   ep  @0      [64 tok][768B] fp32 epilogue staging (alias)                49152
// total 49408 B -> 3 blocks/CU (was 64768 -> 2 blocks/CU)
__launch_bounds__(256, 3)
__global__ void attn_kernel(const float* __restrict__ xb, float* __restrict__ xb2,
                            const float* __restrict__ ln1w, const float* __restrict__ ln1b,
                            const unsigned short* __restrict__ qkvB, const float* __restrict__ qkvb,
                            const unsigned short* __restrict__ projB, const float* __restrict__ projb,
                            const float* __restrict__ rpb){
  __shared__ __align__(16) unsigned char smem[49408];
  int* regions = (int*)(smem + 49152);

  const int tid = threadIdx.x;
  const int blk = blockIdx.x;
  const int b = blk >> 8, wloc = blk & 255, wh = wloc >> 4, ww = wloc & 15;
  const int lane = tid & 63, wv = tid >> 6;
  const int ln15 = lane & 15, l16 = lane >> 4;
  const f32x4 zero4 = {0.f, 0.f, 0.f, 0.f};

  const int t = tid >> 2, q4 = tid & 3, c0 = q4 * 48;
  const int tr = t >> 3, tc = t & 7;
  const int sh = (wh*8 + tr + 4) & 127, sw = (ww*8 + tc + 4) & 127;
  const float* xrow = xb + (size_t)((((b << 7) + sh) << 7) + sw) * 192;
  float4 xv[12];     // kept live: epilogue shortcut + h16 rewrites
  float lnm, lnr;
  const int hswz = (t & 7) << 4;

  // ---- LN1 (thread t = token, q4 = channel quarter) ----
  {
    float s = 0.f, s2 = 0.f;
    #pragma unroll
    for (int i = 0; i < 12; i++){
      xv[i] = *(const float4*)(xrow + c0 + i*4);
      s  += xv[i].x + xv[i].y + xv[i].z + xv[i].w;
      s2 += xv[i].x*xv[i].x + xv[i].y*xv[i].y + xv[i].z*xv[i].z + xv[i].w*xv[i].w;
    }
    s  += __shfl_xor(s, 1);  s  += __shfl_xor(s, 2);
    s2 += __shfl_xor(s2, 1); s2 += __shfl_xor(s2, 2);
    lnm = s * (1.f/192.f);
    lnr = rsqrtf(s2 * (1.f/192.f) - lnm*lnm + 1e-5f);
    #pragma unroll
    for (int i = 0; i < 12; i++){
      int cb = c0 + i*4;
      float4 w4 = *(const float4*)(ln1w + cb);
      float4 b4 = *(const float4*)(ln1b + cb);
      uint2 u;
      u.x = pack2((xv[i].x - lnm)*lnr*w4.x + b4.x, (xv[i].y - lnm)*lnr*w4.y + b4.y);
      u.y = pack2((xv[i].z - lnm)*lnr*w4.z + b4.z, (xv[i].w - lnm)*lnr*w4.w + b4.w);
      *(uint2*)(smem + t*384 + ((cb*2) ^ hswz)) = u;
    }
    if (q4 == 0){
      int gh = wh*8 + tr, gw = ww*8 + tc;
      regions[t] = (gh < 120 ? 0 : (gh < 124 ? 1 : 2)) * 3 + (gw < 120 ? 0 : (gw < 124 ? 1 : 2));
    }
  }
  __syncthreads();

  f32x4 pacc[4][3];
  #pragma unroll
  for (int mt = 0; mt < 4; mt++)
    #pragma unroll
    for (int nt = 0; nt < 3; nt++)
      pacc[mt][nt] = zero4;

  const float scale = 0.17677669529663687f;

  #pragma unroll 1
  for (int hp = 0; hp < 3; hp++){
    const int h0 = hp * 2;
    if (hp){
      __syncthreads();       // prior proj done reading ctx (regionA)
      #pragma unroll
      for (int i = 0; i < 12; i++){    // rewrite h16 from registers (bitwise same values)
        int cb = c0 + i*4;
        float4 w4 = *(const float4*)(ln1w + cb);
        float4 b4 = *(const float4*)(ln1b + cb);
        uint2 u;
        u.x = pack2((xv[i].x - lnm)*lnr*w4.x + b4.x, (xv[i].y - lnm)*lnr*w4.y + b4.y);
        u.y = pack2((xv[i].z - lnm)*lnr*w4.z + b4.z, (xv[i].w - lnm)*lnr*w4.w + b4.w);
        *(uint2*)(smem + t*384 + ((cb*2) ^ hswz)) = u;
      }
      __syncthreads();       // h16 ready
    }

    // ---- phase a: qkv for heads h0,h0+1 (12 col-tiles of 16; wave does 3) ----
    #pragma unroll 1
    for (int tt0 = 0; tt0 < 3; tt0++){
      const int tt = wv*3 + tt0;
      const int which = tt >> 2, sub = tt & 3;     // wave-uniform
      const int colb = which*192 + h0*32 + sub*16;
      const unsigned short* bp = qkvB + (size_t)(colb + ln15)*192 + l16*8;
      bf16x8 bw[6];
      #pragma unroll
      for (int ks = 0; ks < 6; ks++) bw[ks] = *(const bf16x8*)(bp + ks*32);
      f32x4 acc[4];
      #pragma unroll
      for (int mt = 0; mt < 4; mt++){
        acc[mt] = zero4;
        const int arow = mt*16 + ln15;
        const unsigned char* ap = smem + arow*384;
        const int aswz = (arow & 7) << 4;
        #pragma unroll
        for (int ks = 0; ks < 6; ks++){
          bf16x8 af = *(const bf16x8*)(ap + ((ks*64 + l16*16) ^ aswz));
          acc[mt] = MFMA16(af, bw[ks], acc[mt]);
        }
      }
      // scatter to q/k/vT (writes disjoint from h16 -> no barrier needed)
      const float bias = qkvb[colb + ln15];
      const int local = sub*16 + ln15;
      const int hl = local >> 5, d = local & 31;
      if (which == 2){
        unsigned char* vbase = smem + 40960 + hl*4096 + d*128;
        const int vswz = (d & 7) << 4;
        #pragma unroll
        for (int mt = 0; mt < 4; mt++){
          const int tk2 = (mt*16 + l16*4) * 2;
          *(unsigned int*)(vbase + ((tk2    ) ^ vswz)) = pack2(acc[mt][0] + bias, acc[mt][1] + bias);
          *(unsigned int*)(vbase + ((tk2 + 4) ^ vswz)) = pack2(acc[mt][2] + bias, acc[mt][3] + bias);
        }
      } else {
        unsigned char* qkb = smem + 24576 + hl*8192;
        const int koff = which ? 64 : 0;
        const float mul = which ? 1.f : scale;
        #pragma unroll
        for (int mt = 0; mt < 4; mt++)
          #pragma unroll
          for (int reg = 0; reg < 4; reg++){
            const int tok = mt*16 + l16*4 + reg;
            *(unsigned short*)(qkb + tok*128 + ((koff + d*2) ^ ((tok & 7) << 4))) =
                f2bf((acc[mt][reg] + bias) * mul);
          }
      }
    }
    __syncthreads();   // qkv ready

    // ---- attention: both heads, barrier-free (ps, ctx writes are wave-private rows) ----
    #pragma unroll 1
    for (int e = 0; e < 2; e++){
      const int h = h0 + e;
      const unsigned char* qkb = smem + 24576 + e*8192;
      const int arow = wv*16 + ln15;
      const int aswz = (arow & 7) << 4;
      bf16x8 aq = *(const bf16x8*)(qkb + arow*128 + ((l16*16) ^ aswz));
      f32x4 sacc[4];
      #pragma unroll
      for (int nt = 0; nt < 4; nt++){
        const int brow = nt*16 + ln15;
        bf16x8 bk = *(const bf16x8*)(qkb + brow*128 + ((64 + l16*16) ^ ((brow & 7) << 4)));
        sacc[nt] = MFMA16(aq, bk, zero4);
      }
      // bias + mask
      #pragma unroll
      for (int nt = 0; nt < 4; nt++){
        const int j_tok = nt*16 + ln15;
        const int rj = j_tok >> 3, cj = j_tok & 7;
        const int regj = regions[j_tok];
        #pragma unroll
        for (int reg = 0; reg < 4; reg++){
          const int i_tok = wv*16 + l16*4 + reg;
          const int ri = i_tok >> 3, ci = i_tok & 7;
          float bias = rpb[((ri - rj + 7)*15 + (ci - cj + 7))*6 + h];
          sacc[nt][reg] += bias + ((regions[i_tok] == regj) ? 0.f : -100.f);
        }
      }
      // softmax across 16 lanes (cols) x 4 nt, per reg
      float mx[4], sum[4];
      #pragma unroll
      for (int reg = 0; reg < 4; reg++){
        float m = fmaxf(fmaxf(sacc[0][reg], sacc[1][reg]), fmaxf(sacc[2][reg], sacc[3][reg]));
        m = fmaxf(m, __shfl_xor(m, 1));
        m = fmaxf(m, __shfl_xor(m, 2));
        m = fmaxf(m, __shfl_xor(m, 4));
        m = fmaxf(m, __shfl_xor(m, 8));
        mx[reg] = m; sum[reg] = 0.f;
      }
      #pragma unroll
      for (int nt = 0; nt < 4; nt++)
        #pragma unroll
        for (int reg = 0; reg < 4; reg++){
          float ex = __expf(sacc[nt][reg] - mx[reg]);
          sacc[nt][reg] = ex;
          sum[reg] += ex;
        }
      #pragma unroll
      for (int reg = 0; reg < 4; reg++){
        float sm = sum[reg];
        sm += __shfl_xor(sm, 1);
        sm += __shfl_xor(sm, 2);
        sm += __shfl_xor(sm, 4);
        sm += __shfl_xor(sm, 8);
        sum[reg] = 1.f / sm;
      }
      // write P (own rows only)
      #pragma unroll
      for (int nt = 0; nt < 4; nt++)
        #pragma unroll
        for (int reg = 0; reg < 4; reg++){
          const int tok = wv*16 + l16*4 + reg;
          *(unsigned short*)(smem + tok*128 + (((nt*16 + ln15)*2) ^ ((tok & 7) << 4))) =
              f2bf(sacc[nt][reg] * sum[reg]);
        }
      // PV (K=64 -> 2 ks; 2 d-tiles)
      f32x4 cacc[2] = {zero4, zero4};
      #pragma unroll
      for (int ks = 0; ks < 2; ks++){
        bf16x8 pa = *(const bf16x8*)(smem + arow*128 + ((ks*64 + l16*16) ^ aswz));
        #pragma unroll
        for (int nt2 = 0; nt2 < 2; nt2++){
          const int drow = nt2*16 + ln15;
          bf16x8 bv = *(const bf16x8*)(smem + 40960 + e*4096 + drow*128 +
                                       ((ks*64 + l16*16) ^ ((drow & 7) << 4)));
          cacc[nt2] = MFMA16(pa, bv, cacc[nt2]);
        }
      }
      // ctx (own rows, this head's 32 cols)
      #pragma unroll
      for (int nt2 = 0; nt2 < 2; nt2++)
        #pragma unroll
        for (int reg = 0; reg < 4; reg++){
          const int tok = wv*16 + l16*4 + reg;
          const int col = e*32 + nt2*16 + ln15;
          *(unsigned short*)(smem + 8192 + tok*128 + ((col*2) ^ ((tok & 7) << 4))) =
              f2bf(cacc[nt2][reg]);
        }
    }
    __syncthreads();   // ctx ready (all 64 rows x both heads)

    // ---- proj accumulate for this pair: out cols [wv*48,+48), K = 64 pair dims ----
    #pragma unroll
    for (int ks = 0; ks < 2; ks++){
      bf16x8 bw3[3];
      #pragma unroll
      for (int nt3 = 0; nt3 < 3; nt3++)
        bw3[nt3] = *(const bf16x8*)(projB + (size_t)(wv*48 + nt3*16 + ln15)*192 + h0*32 + ks*32 + l16*8);
      #pragma unroll
      for (int mt = 0; mt < 4; mt++){
        const int crow = mt*16 + ln15;
        bf16x8 ac = *(const bf16x8*)(smem + 8192 + crow*128 + ((ks*64 + l16*16) ^ ((crow & 7) << 4)));
        #pragma unroll
        for (int nt3 = 0; nt3 < 3; nt3++)
          pacc[mt][nt3] = MFMA16(ac, bw3[nt3], pacc[mt][nt3]);
      }
    }
  }
  __syncthreads();   // regionA/qkp/vT all dead; reuse as fp32 ep

  // ---- epilogue: stage proj result, write coalesced float4 rows ----
  #pragma unroll
  for (int nt3 = 0; nt3 < 3; nt3++){
    const int col4 = (wv*48 + nt3*16 + ln15) * 4;
    #pragma unroll
    for (int mt = 0; mt < 4; mt++)
      #pragma unroll
      for (int reg = 0; reg < 4; reg++){
        const int row = mt*16 + l16*4 + reg;
        *(float*)(smem + row*768 + (col4 ^ ((row & 7) << 4))) = pacc[mt][nt3][reg];
      }
  }
  __syncthreads();
  {
    float* orow = xb2 + (size_t)((((b << 7) + sh) << 7) + sw) * 192;
    #pragma unroll
    for (int i = 0; i < 12; i++){
      const int off = c0*4 + i*16;
      float4 pv  = *(const float4*)(smem + t*768 + (off ^ hswz));
      float4 pb4 = *(const float4*)(projb + c0 + i*4);
      float4 o;
      o.x = xv[i].x + pv.x + pb4.x;
      o.y = xv[i].y + pv.y + pb4.y;
      o.z = xv[i].z + pv.z + pb4.z;
      o.w = xv[i].w + pv.w + pb4.w;
      *(float4*)(orow + c0 + i*4) = o;
    }
  }
}

// ---------------- fused MLP (MFMA): LN2 + fc1 + GELU + fc2 + residuals ----------------
// fuse=1: also does final NCHW transpose + clamp (final_k eliminated); requires xb != outp.
__launch_bounds__(256, 3)
__global__ void mlp_kernel(const float* __restrict__ xb, float* __restrict__ xb2,
                           const float* __restrict__ ln2w, const float* __restrict__ ln2b,
                           const unsigned short* __restrict__ fc1B, const float* __restrict__ fc1b,
                           const unsigned short* __restrict__ fc2B, const float* __restrict__ fc2b,
                           float* __restrict__ outp, const int fuse){
  // LDS union: aln [64][200] bf16 @0 (25600) | hid [64][136] bf16 @25600 (17408)
  //            ep [64][196] fp32 @0 (50176, epilogue only)
  __shared__ __align__(16) unsigned char smem[50176];
  unsigned short* aln = (unsigned short*)smem;
  unsigned short* hid = (unsigned short*)(smem + 25600);
  float*          ep  = (float*)smem;

  const int tid = threadIdx.x;
  const int lane = tid & 63, wv = tid >> 6;
  const int ln15 = lane & 15, l16 = lane >> 4;
  const size_t p0 = (size_t)blockIdx.x * 64;
  const f32x4 zero4 = {0.f, 0.f, 0.f, 0.f};

  const int t = tid >> 2, q4 = tid & 3, c0 = q4 * 48;
  float4 xv[12];   // xb2 row, kept live for epilogue residual

  // ---- LN2 ----
  {
    const float* xrow2 = xb2 + (p0 + t)*192;
    float s = 0.f, s2 = 0.f;
    #pragma unroll
    for (int i = 0; i < 12; i++){
      xv[i] = *(const float4*)(xrow2 + c0 + i*4);
      s  += xv[i].x + xv[i].y + xv[i].z + xv[i].w;
      s2 += xv[i].x*xv[i].x + xv[i].y*xv[i].y + xv[i].z*xv[i].z + xv[i].w*xv[i].w;
    }
    s  += __shfl_xor(s, 1);  s  += __shfl_xor(s, 2);
    s2 += __shfl_xor(s2, 1); s2 += __shfl_xor(s2, 2);
    const float mean = s * (1.f/192.f);
    const float rstd = rsqrtf(s2 * (1.f/192.f) - mean*mean + 1e-5f);
    #pragma unroll
    for (int i = 0; i < 12; i++){
      int cb = c0 + i*4;
      float v0 = (xv[i].x - mean) * rstd * ln2w[cb  ] + ln2b[cb  ];
      float v1 = (xv[i].y - mean) * rstd * ln2w[cb+1] + ln2b[cb+1];
      float v2 = (xv[i].z - mean) * rstd * ln2w[cb+2] + ln2b[cb+2];
      float v3 = (xv[i].w - mean) * rstd * ln2w[cb+3] + ln2b[cb+3];
      unsigned int* dst = (unsigned int*)(aln + t*200 + cb);
      dst[0] = pack2(v0, v1);
      dst[1] = pack2(v2, v3);
    }
  }
  __syncthreads();

  f32x4 o2[4][3];
  #pragma unroll
  for (int mt = 0; mt < 4; mt++)
    #pragma unroll
    for (int nt = 0; nt < 3; nt++)
      o2[mt][nt] = zero4;

  #pragma unroll 1
  for (int ch = 0; ch < 6; ch++){
    // ---- fc1 + GELU (merged per sub-tile: no runtime-indexed accumulator array) ----
    #pragma unroll 1
    for (int nt = 0; nt < 2; nt++){
      const unsigned short* bp = fc1B + (size_t)(ch*128 + wv*32 + nt*16 + ln15)*192 + l16*8;
      bf16x8 bw[6];
      #pragma unroll
      for (int ks = 0; ks < 6; ks++) bw[ks] = *(const bf16x8*)(bp + ks*32);
      f32x4 facc[4];
      #pragma unroll
      for (int mt = 0; mt < 4; mt++){
        facc[mt] = zero4;
        const unsigned short* ap = aln + (mt*16 + ln15)*200 + l16*8;
        #pragma unroll
        for (int ks = 0; ks < 6; ks++){
          bf16x8 af = *(const bf16x8*)(ap + ks*32);
          facc[mt] = MFMA16(af, bw[ks], facc[mt]);
        }
      }
      const int hcol = wv*32 + nt*16 + ln15;
      const float b1 = fc1b[ch*128 + hcol];
      #pragma unroll
      for (int mt = 0; mt < 4; mt++)
        #pragma unroll
        for (int reg = 0; reg < 4; reg++)
          hid[(mt*16 + l16*4 + reg)*136 + hcol] = f2bf(gelu_f(facc[mt][reg] + b1));
    }
    __syncthreads();
    // ---- fc2 partial: out cols [wv*48, +48), K = 128 chunk ----
    #pragma unroll 1
    for (int ks = 0; ks < 4; ks++){
      bf16x8 bw2[3];
      #pragma unroll
      for (int nt3 = 0; nt3 < 3; nt3++)
        bw2[nt3] = *(const bf16x8*)(fc2B + (size_t)(wv*48 + nt3*16 + ln15)*768 + ch*128 + ks*32 + l16*8);
      #pragma unroll
      for (int mt = 0; mt < 4; mt++){
        bf16x8 af = *(const bf16x8*)(&hid[(mt*16 + ln15)*136 + ks*32 + l16*8]);
        #pragma unroll
        for (int nt3 = 0; nt3 < 3; nt3++)
          o2[mt][nt3] = MFMA16(af, bw2[nt3], o2[mt][nt3]);
      }
    }
    __syncthreads();
  }
  // ---- epilogue: stage to LDS ----
  #pragma unroll
  for (int nt3 = 0; nt3 < 3; nt3++){
    const int col = wv*48 + nt3*16 + ln15;
    #pragma unroll
    for (int mt = 0; mt < 4; mt++)
      #pragma unroll
      for (int reg = 0; reg < 4; reg++)
        ep[(mt*16 + l16*4 + reg)*196 + col] = o2[mt][nt3][reg];
  }
  __syncthreads();
  const float* xrow = xb + (p0 + t)*192;
  if (!fuse){
    float* orow = xb2 + (p0 + t)*192;
    #pragma unroll
    for (int i = 0; i < 12; i++){
      float4 mv  = *(float4*)(ep + t*196 + c0 + i*4);
      float4 xr  = *(const float4*)(xrow + c0 + i*4);
      float4 fb4 = *(const float4*)(fc2b + c0 + i*4);
      float4 o;
      o.x = xv[i].x + xr.x + fb4.x + mv.x;
      o.y = xv[i].y + xr.y + fb4.y + mv.y;
      o.z = xv[i].z + xr.z + fb4.z + mv.z;
      o.w = xv[i].w + xr.w + fb4.w + mv.w;
      *(float4*)(orow + c0 + i*4) = o;
    }
  } else {
    // final value + clamp back into ep, then NCHW transposed write (replaces final_k)
    #pragma unroll
    for (int i = 0; i < 12; i++){
      float4 mv  = *(float4*)(ep + t*196 + c0 + i*4);
      float4 xr  = *(const float4*)(xrow + c0 + i*4);
      float4 fb4 = *(const float4*)(fc2b + c0 + i*4);
      float4 o;
      o.x = fminf(fmaxf(xv[i].x + xr.x + fb4.x + mv.x, -10.f), 10.f);
      o.y = fminf(fmaxf(xv[i].y + xr.y + fb4.y + mv.y, -10.f), 10.f);
      o.z = fminf(fmaxf(xv[i].z + xr.z + fb4.z + mv.z, -10.f), 10.f);
      o.w = fminf(fmaxf(xv[i].w + xr.w + fb4.w + mv.w, -10.f), 10.f);
      *(float4*)(ep + t*196 + c0 + i*4) = o;
    }
    __syncthreads();
    // NCHW transposed write: 12 x 256 threads cover all 64 pixels x 192 channels
    const int bidx   = (int)(p0 >> 14);
    const int imgoff = (int)(p0 & 16383);
    #pragma unroll 1
    for (int i = 0; i < 12; i++){
      const int id = i*256 + tid;
      const int c = id >> 4, pq = id & 15;
      float4 o4;
      o4.x = ep[(pq*4    )*196 + c];
      o4.y = ep[(pq*4 + 1)*196 + c];
      o4.z = ep[(pq*4 + 2)*196 + c];
      o4.w = ep[(pq*4 + 3)*196 + c];
      *(float4*)(outp + (((size_t)(bidx*192 + c)) << 14) + imgoff + pq*4) = o4;
    }
  }
}

// ---------------- final NHWC -> NCHW + clamp (legacy path only) ----------------
__global__ void final_k(const float* __restrict__ xb2, float* __restrict__ out){
  __shared__ float tile[192*64];
  int blk = blockIdx.x, tid = threadIdx.x;
  int b = blk >> 8, p0 = (blk & 255) * 64;
  #pragma unroll 1
  for (int i = 0; i < 12; i++){
    int idx4 = i*256 + tid;
    int tt = idx4 / 48, c4 = idx4 - tt*48;
    int cb = c4 * 4;
    float4 v = *(const float4*)(xb2 + ((size_t)blk*64 + tt)*192 + cb);
    tile[(cb  )*64 + ((tt + cb    ) & 63)] = v.x;
    tile[(cb+1)*64 + ((tt + cb + 1) & 63)] = v.y;
    tile[(cb+2)*64 + ((tt + cb + 2) & 63)] = v.z;
    tile[(cb+3)*64 + ((tt + cb + 3) & 63)] = v.w;
  }
  __syncthreads();
  #pragma unroll 1
  for (int i = 0; i < 12; i++){
    int idx4 = i*256 + tid;
    int c = idx4 >> 4, pq = idx4 & 15;
    int pb_ = pq*4;
    float4 o;
    o.x = tile[c*64 + ((pb_     + c) & 63)];
    o.y = tile[c*64 + ((pb_ + 1 + c) & 63)];
    o.z = tile[c*64 + ((pb_ + 2 + c) & 63)];
    o.w = tile[c*64 + ((pb_ + 3 + c) & 63)];
    o.x = fminf(fmaxf(o.x, -10.f), 10.f);
    o.y = fminf(fmaxf(o.y, -10.f), 10.f);
    o.z = fminf(fmaxf(o.z, -10.f), 10.f);
    o.w = fminf(fmaxf(o.w, -10.f), 10.f);
    *(float4*)(out + (((size_t)b*192 + c) << 14) + p0 + pb_) = o;
  }
}

extern "C" void kernel_launch(void* const* d_in, const int* in_sizes, int n_in,
                              void* d_out, int out_size, void* d_ws, size_t ws_size,
                              hipStream_t stream){
  (void)in_sizes; (void)n_in; (void)out_size;
  const float* x     = (const float*)d_in[0];
  const float* gnw   = (const float*)d_in[1];
  const float* gnb   = (const float*)d_in[2];
  const float* ln1w  = (const float*)d_in[3];
  const float* ln1b  = (const float*)d_in[4];
  const float* qkvw  = (const float*)d_in[5];
  const float* qkvb  = (const float*)d_in[6];
  const float* projw = (const float*)d_in[7];
  const float* projb = (const float*)d_in[8];
  const float* rpb   = (const float*)d_in[9];
  const float* ln2w  = (const float*)d_in[10];
  const float* ln2b  = (const float*)d_in[11];
  const float* fc1w  = (const float*)d_in[12];
  const float* fc1b  = (const float*)d_in[13];
  const float* fc2w  = (const float*)d_in[14];
  const float* fc2b  = (const float*)d_in[15];
  float* out = (float*)d_out;

  float* ws    = (float*)d_ws;
  float* xb2   = ws;                       // [B,H,W,C] fp32
  float* part  = xb2  + 25165824;
  float* stats = part + 3072;
  unsigned short* qkvB = (unsigned short*)(stats + 16);  // [576][192] bf16
  unsigned short* projB = qkvB + 110592;                 // [192][192]
  unsigned short* fc1B  = projB + 36864;                 // [768][192]
  unsigned short* fc2B  = fc1B + 147456;                 // [192][768]

  // fused path: xb (GN out / residual base) lives in ws so mlp can write final NCHW
  // output directly to d_out (no aliasing race). float offset 25390096, need 202223680 B.
  const int fuse = (ws_size >= 202223680ULL) ? 1 : 0;
  float* xb = fuse ? (ws + 25390096) : out;

  transpose_cast_all<<<1728, 256, 0, stream>>>(qkvw, projw, fc1w, fc2w, qkvB, projB, fc1B, fc2B);
  gn_partial<<<1536, 256, 0, stream>>>(x, part);
  gn_final<<<8, 64, 0, stream>>>(part, stats);
  gn_apply<<<2048, 256, 0, stream>>>(x, stats, gnw, gnb, xb);
  attn_kernel<<<2048, 256, 0, stream>>>(xb, xb2, ln1w, ln1b, qkvB, qkvb, projB, projb, rpb);
  mlp_kernel<<<2048, 256, 0, stream>>>(xb, xb2, ln2w, ln2b, fc1B, fc1b, fc2B, fc2b, out, fuse);
  if (!fuse) final_k<<<2048, 256, 0, stream>>>(xb2, out);
}

// Round 4
// 924.327 us; speedup vs baseline: 1.1736x; 1.1236x over previous
//
#include <hip/hip_runtime.h>
#include <cstddef>

typedef __attribute__((ext_vector_type(8))) short bf16x8;
typedef __attribute__((ext_vector_type(4))) float f32x4;

#define DEV __device__ __forceinline__
#define MFMA16(a,b,c) __builtin_amdgcn_mfma_f32_16x16x32_bf16((a),(b),(c),0,0,0)

DEV unsigned short f2bf(float f){
  unsigned int x = __float_as_uint(f);
  x += 0x7fffu + ((x >> 16) & 1u);
  return (unsigned short)(x >> 16);
}
DEV unsigned int pack2(float a, float b){
  return (unsigned int)f2bf(a) | ((unsigned int)f2bf(b) << 16);
}
// branchless erf-GELU, Abramowitz-Stegun 7.1.26 (|err| <= 1.5e-7)
DEV float gelu_f(float x){
  float z = fabsf(x) * 0.7071067811865475f;
  float tt = 1.f / (1.f + 0.3275911f * z);
  float poly = tt*(0.254829592f + tt*(-0.284496736f + tt*(1.421413741f +
               tt*(-1.453152027f + tt*1.061405429f))));
  float er = 1.f - poly * __expf(-z*z);
  er = (x < 0.f) ? -er : er;
  return 0.5f * x * (1.f + er);
}

// ---------------- all weight transposes + bf16 cast in one launch ----------------
__global__ void transpose_cast_all(const float* __restrict__ qkvw, const float* __restrict__ projw,
                                   const float* __restrict__ fc1w, const float* __restrict__ fc2w,
                                   unsigned short* __restrict__ qkvB, unsigned short* __restrict__ projB,
                                   unsigned short* __restrict__ fc1B, unsigned short* __restrict__ fc2B){
  int blk = blockIdx.x;
  const float* in; unsigned short* outp; int K, N, idx;
  if (blk < 432){        in = qkvw; outp = qkvB; K = 192; N = 576; idx = blk*256 + threadIdx.x; }
  else if (blk < 576){   in = projw; outp = projB; K = 192; N = 192; idx = (blk-432)*256 + threadIdx.x; }
  else if (blk < 1152){  in = fc1w; outp = fc1B; K = 192; N = 768; idx = (blk-576)*256 + threadIdx.x; }
  else {                 in = fc2w; outp = fc2B; K = 768; N = 192; idx = (blk-1152)*256 + threadIdx.x; }
  if (idx < K * N){
    int n = idx / K, k = idx - n * K;
    outp[idx] = f2bf(in[k * N + n]);
  }
}

// ---------------- GroupNorm stage 1 ----------------
__global__ void gn_partial(const float* __restrict__ x, float* __restrict__ part){
  int bc = blockIdx.x, tid = threadIdx.x;
  const float4* p = (const float4*)(x + (size_t)bc * 16384);
  float s = 0.f, s2 = 0.f;
  for (int i = tid; i < 4096; i += 256){
    float4 v = p[i];
    s  += v.x + v.y + v.z + v.w;
    s2 += v.x*v.x + v.y*v.y + v.z*v.z + v.w*v.w;
  }
  #pragma unroll
  for (int off = 32; off; off >>= 1){ s += __shfl_down(s, off); s2 += __shfl_down(s2, off); }
  __shared__ float red[8];
  int wid = tid >> 6;
  if ((tid & 63) == 0){ red[wid*2] = s; red[wid*2+1] = s2; }
  __syncthreads();
  if (tid == 0){
    part[bc*2]   = red[0] + red[2] + red[4] + red[6];
    part[bc*2+1] = red[1] + red[3] + red[5] + red[7];
  }
}

// ---------------- GroupNorm stage 2 ----------------
__global__ void gn_final(const float* __restrict__ part, float* __restrict__ stats){
  int b = blockIdx.x, tid = threadIdx.x;
  float s = 0.f, s2 = 0.f;
  for (int c = tid; c < 192; c += 64){
    s  += part[(b*192 + c)*2];
    s2 += part[(b*192 + c)*2 + 1];
  }
  #pragma unroll
  for (int off = 32; off; off >>= 1){ s += __shfl_down(s, off); s2 += __shfl_down(s2, off); }
  if (tid == 0){
    const float inv = 1.f / (192.f * 16384.f);
    float mean = s * inv;
    float var  = s2 * inv - mean*mean;
    stats[b*2]   = mean;
    stats[b*2+1] = rsqrtf(var + 1e-5f);
  }
}

// ---------------- GN apply + NCHW -> NHWC ----------------
__global__ void gn_apply(const float* __restrict__ x, const float* __restrict__ stats,
                         const float* __restrict__ gnw, const float* __restrict__ gnb,
                         float* __restrict__ xb){
  __shared__ float tile[192*64];
  int blk = blockIdx.x, tid = threadIdx.x;
  int b = blk >> 8, p0 = (blk & 255) * 64;
  float mean = stats[b*2], rstd = stats[b*2+1];
  #pragma unroll 1
  for (int i = 0; i < 12; i++){
    int idx4 = i*256 + tid;
    int c = idx4 >> 4, pq = idx4 & 15;
    float4 v = *(const float4*)(x + (((size_t)b*192 + c) << 14) + p0 + pq*4);
    float w  = gnw[c] * rstd;
    float bb = gnb[c] - mean * rstd * gnw[c];
    int pb_ = pq*4;
    tile[c*64 + ((pb_     + c) & 63)] = v.x * w + bb;
    tile[c*64 + ((pb_ + 1 + c) & 63)] = v.y * w + bb;
    tile[c*64 + ((pb_ + 2 + c) & 63)] = v.z * w + bb;
    tile[c*64 + ((pb_ + 3 + c) & 63)] = v.w * w + bb;
  }
  __syncthreads();
  #pragma unroll 1
  for (int i = 0; i < 12; i++){
    int idx4 = i*256 + tid;
    int pix = idx4 / 48, c4 = idx4 - pix*48;
    int cb = c4 * 4;
    float4 o;
    o.x = tile[(cb  )*64 + ((pix + cb    ) & 63)];
    o.y = tile[(cb+1)*64 + ((pix + cb + 1) & 63)];
    o.z = tile[(cb+2)*64 + ((pix + cb + 2) & 63)];
    o.w = tile[(cb+3)*64 + ((pix + cb + 3) & 63)];
    *(float4*)(xb + ((size_t)blk*64 + pix)*192 + cb) = o;
  }
}

// ---------------- fused window attention (MFMA) ----------------
// LDS (XOR-swizzled rows: byte_in_row ^= (row&7)<<4; rows are 128B/384B pow2):
//   h16 @0      [64 tok][384B]     LN1 out (recomputed from xb each pair)   24576
//   ps  @0      [64 tok][128B]     P bf16  (alias of h16, attention phase)   8192
//   ctx @8192   [64 tok][128B]     pair attention out (2 heads x 32d)        8192
//   qkp @24576  [2 head][64 tok][128B: q(64B)|k(64B)]                       16384
//   vT  @40960  [2 head][32 d][128B = 64 tok bf16]                           8192
//   regions @49152 int[64]                                                    256
//   ep  @0      [64 tok][768B] fp32 epilogue staging (alias)                49152
// total 49408 B -> 3 blocks/CU. NO persistent xv[] registers (r2 spill lesson:
// 170-reg cap at 3 blk/CU; xv[12]+pacc overflowed it -> scratch traffic 800MB).
__launch_bounds__(256, 3)
__global__ void attn_kernel(const float* __restrict__ xb, float* __restrict__ xb2,
                            const float* __restrict__ ln1w, const float* __restrict__ ln1b,
                            const unsigned short* __restrict__ qkvB, const float* __restrict__ qkvb,
                            const unsigned short* __restrict__ projB, const float* __restrict__ projb,
                            const float* __restrict__ rpb){
  __shared__ __align__(16) unsigned char smem[49408];
  int* regions = (int*)(smem + 49152);

  const int tid = threadIdx.x;
  const int blk = blockIdx.x;
  const int b = blk >> 8, wloc = blk & 255, wh = wloc >> 4, ww = wloc & 15;
  const int lane = tid & 63, wv = tid >> 6;
  const int ln15 = lane & 15, l16 = lane >> 4;
  const f32x4 zero4 = {0.f, 0.f, 0.f, 0.f};

  const int t = tid >> 2, q4 = tid & 3, c0 = q4 * 48;
  const int tr = t >> 3, tc = t & 7;
  const int sh = (wh*8 + tr + 4) & 127, sw = (ww*8 + tc + 4) & 127;
  const float* xrow = xb + (size_t)((((b << 7) + sh) << 7) + sw) * 192;
  float lnm, lnr;                    // only 2 persistent regs for LN recompute
  const int hswz = (t & 7) << 4;

  // ---- LN1 (thread t = token, q4 = channel quarter); reads are scoped ----
  {
    float4 xt[12];
    float s = 0.f, s2 = 0.f;
    #pragma unroll
    for (int i = 0; i < 12; i++){
      xt[i] = *(const float4*)(xrow + c0 + i*4);
      s  += xt[i].x + xt[i].y + xt[i].z + xt[i].w;
      s2 += xt[i].x*xt[i].x + xt[i].y*xt[i].y + xt[i].z*xt[i].z + xt[i].w*xt[i].w;
    }
    s  += __shfl_xor(s, 1);  s  += __shfl_xor(s, 2);
    s2 += __shfl_xor(s2, 1); s2 += __shfl_xor(s2, 2);
    lnm = s * (1.f/192.f);
    lnr = rsqrtf(s2 * (1.f/192.f) - lnm*lnm + 1e-5f);
    #pragma unroll
    for (int i = 0; i < 12; i++){
      int cb = c0 + i*4;
      float4 w4 = *(const float4*)(ln1w + cb);
      float4 b4 = *(const float4*)(ln1b + cb);
      uint2 u;
      u.x = pack2((xt[i].x - lnm)*lnr*w4.x + b4.x, (xt[i].y - lnm)*lnr*w4.y + b4.y);
      u.y = pack2((xt[i].z - lnm)*lnr*w4.z + b4.z, (xt[i].w - lnm)*lnr*w4.w + b4.w);
      *(uint2*)(smem + t*384 + ((cb*2) ^ hswz)) = u;
    }
    if (q4 == 0){
      int gh = wh*8 + tr, gw = ww*8 + tc;
      regions[t] = (gh < 120 ? 0 : (gh < 124 ? 1 : 2)) * 3 + (gw < 120 ? 0 : (gw < 124 ? 1 : 2));
    }
  }
  __syncthreads();

  f32x4 pacc[4][3];
  #pragma unroll
  for (int mt = 0; mt < 4; mt++)
    #pragma unroll
    for (int nt = 0; nt < 3; nt++)
      pacc[mt][nt] = zero4;

  const float scale = 0.17677669529663687f;

  #pragma unroll 1
  for (int hp = 0; hp < 3; hp++){
    const int h0 = hp * 2;
    if (hp){
      __syncthreads();       // prior proj done reading ctx (aliases h16)
      // recompute h16 from xb (L2/L3-warm) with saved lnm/lnr; bounded unroll
      // keeps transient pressure low while pacc (48 acc regs) is live.
      #pragma unroll 2
      for (int i = 0; i < 12; i++){
        int cb = c0 + i*4;
        float4 xi = *(const float4*)(xrow + cb);
        float4 w4 = *(const float4*)(ln1w + cb);
        float4 b4 = *(const float4*)(ln1b + cb);
        uint2 u;
        u.x = pack2((xi.x - lnm)*lnr*w4.x + b4.x, (xi.y - lnm)*lnr*w4.y + b4.y);
        u.y = pack2((xi.z - lnm)*lnr*w4.z + b4.z, (xi.w - lnm)*lnr*w4.w + b4.w);
        *(uint2*)(smem + t*384 + ((cb*2) ^ hswz)) = u;
      }
      __syncthreads();       // h16 ready
    }

    // ---- phase a: qkv for heads h0,h0+1 (12 col-tiles of 16; wave does 3) ----
    #pragma unroll 1
    for (int tt0 = 0; tt0 < 3; tt0++){
      const int tt = wv*3 + tt0;
      const int which = tt >> 2, sub = tt & 3;     // wave-uniform
      const int colb = which*192 + h0*32 + sub*16;
      const unsigned short* bp = qkvB + (size_t)(colb + ln15)*192 + l16*8;
      bf16x8 bw[6];
      #pragma unroll
      for (int ks = 0; ks < 6; ks++) bw[ks] = *(const bf16x8*)(bp + ks*32);
      f32x4 acc[4];
      #pragma unroll
      for (int mt = 0; mt < 4; mt++){
        acc[mt] = zero4;
        const int arow = mt*16 + ln15;
        const unsigned char* ap = smem + arow*384;
        const int aswz = (arow & 7) << 4;
        #pragma unroll
        for (int ks = 0; ks < 6; ks++){
          bf16x8 af = *(const bf16x8*)(ap + ((ks*64 + l16*16) ^ aswz));
          acc[mt] = MFMA16(af, bw[ks], acc[mt]);
        }
      }
      // scatter to q/k/vT (writes disjoint from h16 -> no barrier needed)
      const float bias = qkvb[colb + ln15];
      const int local = sub*16 + ln15;
      const int hl = local >> 5, d = local & 31;
      if (which == 2){
        unsigned char* vbase = smem + 40960 + hl*4096 + d*128;
        const int vswz = (d & 7) << 4;
        #pragma unroll
        for (int mt = 0; mt < 4; mt++){
          const int tk2 = (mt*16 + l16*4) * 2;
          *(unsigned int*)(vbase + ((tk2    ) ^ vswz)) = pack2(acc[mt][0] + bias, acc[mt][1] + bias);
          *(unsigned int*)(vbase + ((tk2 + 4) ^ vswz)) = pack2(acc[mt][2] + bias, acc[mt][3] + bias);
        }
      } else {
        unsigned char* qkb = smem + 24576 + hl*8192;
        const int koff = which ? 64 : 0;
        const float mul = which ? 1.f : scale;
        #pragma unroll
        for (int mt = 0; mt < 4; mt++)
          #pragma unroll
          for (int reg = 0; reg < 4; reg++){
            const int tok = mt*16 + l16*4 + reg;
            *(unsigned short*)(qkb + tok*128 + ((koff + d*2) ^ ((tok & 7) << 4))) =
                f2bf((acc[mt][reg] + bias) * mul);
          }
      }
    }
    __syncthreads();   // qkv ready

    // ---- attention: both heads, barrier-free (ps, ctx writes are wave-private rows) ----
    #pragma unroll 1
    for (int e = 0; e < 2; e++){
      const int h = h0 + e;
      const unsigned char* qkb = smem + 24576 + e*8192;
      const int arow = wv*16 + ln15;
      const int aswz = (arow & 7) << 4;
      bf16x8 aq = *(const bf16x8*)(qkb + arow*128 + ((l16*16) ^ aswz));
      f32x4 sacc[4];
      #pragma unroll
      for (int nt = 0; nt < 4; nt++){
        const int brow = nt*16 + ln15;
        bf16x8 bk = *(const bf16x8*)(qkb + brow*128 + ((64 + l16*16) ^ ((brow & 7) << 4)));
        sacc[nt] = MFMA16(aq, bk, zero4);
      }
      // bias + mask
      #pragma unroll
      for (int nt = 0; nt < 4; nt++){
        const int j_tok = nt*16 + ln15;
        const int rj = j_tok >> 3, cj = j_tok & 7;
        const int regj = regions[j_tok];
        #pragma unroll
        for (int reg = 0; reg < 4; reg++){
          const int i_tok = wv*16 + l16*4 + reg;
          const int ri = i_tok >> 3, ci = i_tok & 7;
          float bias = rpb[((ri - rj + 7)*15 + (ci - cj + 7))*6 + h];
          sacc[nt][reg] += bias + ((regions[i_tok] == regj) ? 0.f : -100.f);
        }
      }
      // softmax across 16 lanes (cols) x 4 nt, per reg
      float mx[4], sum[4];
      #pragma unroll
      for (int reg = 0; reg < 4; reg++){
        float m = fmaxf(fmaxf(sacc[0][reg], sacc[1][reg]), fmaxf(sacc[2][reg], sacc[3][reg]));
        m = fmaxf(m, __shfl_xor(m, 1));
        m = fmaxf(m, __shfl_xor(m, 2));
        m = fmaxf(m, __shfl_xor(m, 4));
        m = fmaxf(m, __shfl_xor(m, 8));
        mx[reg] = m; sum[reg] = 0.f;
      }
      #pragma unroll
      for (int nt = 0; nt < 4; nt++)
        #pragma unroll
        for (int reg = 0; reg < 4; reg++){
          float ex = __expf(sacc[nt][reg] - mx[reg]);
          sacc[nt][reg] = ex;
          sum[reg] += ex;
        }
      #pragma unroll
      for (int reg = 0; reg < 4; reg++){
        float sm = sum[reg];
        sm += __shfl_xor(sm, 1);
        sm += __shfl_xor(sm, 2);
        sm += __shfl_xor(sm, 4);
        sm += __shfl_xor(sm, 8);
        sum[reg] = 1.f / sm;
      }
      // write P (own rows only)
      #pragma unroll
      for (int nt = 0; nt < 4; nt++)
        #pragma unroll
        for (int reg = 0; reg < 4; reg++){
          const int tok = wv*16 + l16*4 + reg;
          *(unsigned short*)(smem + tok*128 + (((nt*16 + ln15)*2) ^ ((tok & 7) << 4))) =
              f2bf(sacc[nt][reg] * sum[reg]);
        }
      // PV (K=64 -> 2 ks; 2 d-tiles)
      f32x4 cacc[2] = {zero4, zero4};
      #pragma unroll
      for (int ks = 0; ks < 2; ks++){
        bf16x8 pa = *(const bf16x8*)(smem + arow*128 + ((ks*64 + l16*16) ^ aswz));
        #pragma unroll
        for (int nt2 = 0; nt2 < 2; nt2++){
          const int drow = nt2*16 + ln15;
          bf16x8 bv = *(const bf16x8*)(smem + 40960 + e*4096 + drow*128 +
                                       ((ks*64 + l16*16) ^ ((drow & 7) << 4)));
          cacc[nt2] = MFMA16(pa, bv, cacc[nt2]);
        }
      }
      // ctx (own rows, this head's 32 cols)
      #pragma unroll
      for (int nt2 = 0; nt2 < 2; nt2++)
        #pragma unroll
        for (int reg = 0; reg < 4; reg++){
          const int tok = wv*16 + l16*4 + reg;
          const int col = e*32 + nt2*16 + ln15;
          *(unsigned short*)(smem + 8192 + tok*128 + ((col*2) ^ ((tok & 7) << 4))) =
              f2bf(cacc[nt2][reg]);
        }
    }
    __syncthreads();   // ctx ready (all 64 rows x both heads)

    // ---- proj accumulate for this pair: out cols [wv*48,+48), K = 64 pair dims ----
    #pragma unroll
    for (int ks = 0; ks < 2; ks++){
      bf16x8 bw3[3];
      #pragma unroll
      for (int nt3 = 0; nt3 < 3; nt3++)
        bw3[nt3] = *(const bf16x8*)(projB + (size_t)(wv*48 + nt3*16 + ln15)*192 + h0*32 + ks*32 + l16*8);
      #pragma unroll
      for (int mt = 0; mt < 4; mt++){
        const int crow = mt*16 + ln15;
        bf16x8 ac = *(const bf16x8*)(smem + 8192 + crow*128 + ((ks*64 + l16*16) ^ ((crow & 7) << 4)));
        #pragma unroll
        for (int nt3 = 0; nt3 < 3; nt3++)
          pacc[mt][nt3] = MFMA16(ac, bw3[nt3], pacc[mt][nt3]);
      }
    }
  }
  __syncthreads();   // qkp/vT/ctx dead; reuse smem as fp32 ep [64 rows][768B]

  // ---- epilogue: stage proj result (pacc dies here), then fully-coalesced
  //      read-modify-write: id-linear mapping, contiguous 768B row segments ----
  #pragma unroll
  for (int nt3 = 0; nt3 < 3; nt3++){
    const int col4 = (wv*48 + nt3*16 + ln15) * 4;
    #pragma unroll
    for (int mt = 0; mt < 4; mt++)
      #pragma unroll
      for (int reg = 0; reg < 4; reg++){
        const int row = mt*16 + l16*4 + reg;
        *(float*)(smem + row*768 + (col4 ^ ((row & 7) << 4))) = pacc[mt][nt3][reg];
      }
  }
  __syncthreads();
  {
    #pragma unroll
    for (int i = 0; i < 12; i++){
      const int id = i*256 + tid;
      const int tok = id / 48, c4 = id - tok*48;
      const int trr = tok >> 3, tcc = tok & 7;
      const int shh = (wh*8 + trr + 4) & 127, sww = (ww*8 + tcc + 4) & 127;
      const size_t goff = ((size_t)((((b << 7) + shh) << 7) + sww)) * 192 + c4*4;
      float4 pv  = *(const float4*)(smem + tok*768 + ((c4*16) ^ ((tok & 7) << 4)));
      float4 xr  = *(const float4*)(xb + goff);
      float4 pb4 = *(const float4*)(projb + c4*4);
      float4 o;
      o.x = xr.x + pv.x + pb4.x;
      o.y = xr.y + pv.y + pb4.y;
      o.z = xr.z + pv.z + pb4.z;
      o.w = xr.w + pv.w + pb4.w;
      *(float4*)(xb2 + goff) = o;
    }
  }
}

// ---------------- fused MLP (MFMA): LN2 + fc1 + GELU + fc2 + residuals ----------------
// fuse=1: also does final NCHW transpose + clamp (final_k eliminated); requires xb != outp.
// No persistent xv[] (same 170-reg cap as attn); shortcut re-read from xb2 in epilogue.
__launch_bounds__(256, 3)
__global__ void mlp_kernel(const float* __restrict__ xb, float* __restrict__ xb2,
                           const float* __restrict__ ln2w, const float* __restrict__ ln2b,
                           const unsigned short* __restrict__ fc1B, const float* __restrict__ fc1b,
                           const unsigned short* __restrict__ fc2B, const float* __restrict__ fc2b,
                           float* __restrict__ outp, const int fuse){
  // LDS union: aln [64][200] bf16 @0 (25600) | hid [64][136] bf16 @25600 (17408)
  //            ep [64][196] fp32 @0 (50176, epilogue only)
  __shared__ __align__(16) unsigned char smem[50176];
  unsigned short* aln = (unsigned short*)smem;
  unsigned short* hid = (unsigned short*)(smem + 25600);
  float*          ep  = (float*)smem;

  const int tid = threadIdx.x;
  const int lane = tid & 63, wv = tid >> 6;
  const int ln15 = lane & 15, l16 = lane >> 4;
  const size_t p0 = (size_t)blockIdx.x * 64;
  const f32x4 zero4 = {0.f, 0.f, 0.f, 0.f};

  const int t = tid >> 2, q4 = tid & 3, c0 = q4 * 48;
  const float* xrow2 = xb2 + (p0 + t)*192;

  // ---- LN2 (reads scoped; no persistent row registers) ----
  {
    float4 xt[12];
    float s = 0.f, s2 = 0.f;
    #pragma unroll
    for (int i = 0; i < 12; i++){
      xt[i] = *(const float4*)(xrow2 + c0 + i*4);
      s  += xt[i].x + xt[i].y + xt[i].z + xt[i].w;
      s2 += xt[i].x*xt[i].x + xt[i].y*xt[i].y + xt[i].z*xt[i].z + xt[i].w*xt[i].w;
    }
    s  += __shfl_xor(s, 1);  s  += __shfl_xor(s, 2);
    s2 += __shfl_xor(s2, 1); s2 += __shfl_xor(s2, 2);
    const float mean = s * (1.f/192.f);
    const float rstd = rsqrtf(s2 * (1.f/192.f) - mean*mean + 1e-5f);
    #pragma unroll
    for (int i = 0; i < 12; i++){
      int cb = c0 + i*4;
      float v0 = (xt[i].x - mean) * rstd * ln2w[cb  ] + ln2b[cb  ];
      float v1 = (xt[i].y - mean) * rstd * ln2w[cb+1] + ln2b[cb+1];
      float v2 = (xt[i].z - mean) * rstd * ln2w[cb+2] + ln2b[cb+2];
      float v3 = (xt[i].w - mean) * rstd * ln2w[cb+3] + ln2b[cb+3];
      unsigned int* dst = (unsigned int*)(aln + t*200 + cb);
      dst[0] = pack2(v0, v1);
      dst[1] = pack2(v2, v3);
    }
  }
  __syncthreads();

  f32x4 o2[4][3];
  #pragma unroll
  for (int mt = 0; mt < 4; mt++)
    #pragma unroll
    for (int nt = 0; nt < 3; nt++)
      o2[mt][nt] = zero4;

  #pragma unroll 1
  for (int ch = 0; ch < 6; ch++){
    // ---- fc1 + GELU (merged per sub-tile: no runtime-indexed accumulator array) ----
    #pragma unroll 1
    for (int nt = 0; nt < 2; nt++){
      const unsigned short* bp = fc1B + (size_t)(ch*128 + wv*32 + nt*16 + ln15)*192 + l16*8;
      bf16x8 bw[6];
      #pragma unroll
      for (int ks = 0; ks < 6; ks++) bw[ks] = *(const bf16x8*)(bp + ks*32);
      f32x4 facc[4];
      #pragma unroll
      for (int mt = 0; mt < 4; mt++){
        facc[mt] = zero4;
        const unsigned short* ap = aln + (mt*16 + ln15)*200 + l16*8;
        #pragma unroll
        for (int ks = 0; ks < 6; ks++){
          bf16x8 af = *(const bf16x8*)(ap + ks*32);
          facc[mt] = MFMA16(af, bw[ks], facc[mt]);
        }
      }
      const int hcol = wv*32 + nt*16 + ln15;
      const float b1 = fc1b[ch*128 + hcol];
      #pragma unroll
      for (int mt = 0; mt < 4; mt++)
        #pragma unroll
        for (int reg = 0; reg < 4; reg++)
          hid[(mt*16 + l16*4 + reg)*136 + hcol] = f2bf(gelu_f(facc[mt][reg] + b1));
    }
    __syncthreads();
    // ---- fc2 partial: out cols [wv*48, +48), K = 128 chunk ----
    #pragma unroll 1
    for (int ks = 0; ks < 4; ks++){
      bf16x8 bw2[3];
      #pragma unroll
      for (int nt3 = 0; nt3 < 3; nt3++)
        bw2[nt3] = *(const bf16x8*)(fc2B + (size_t)(wv*48 + nt3*16 + ln15)*768 + ch*128 + ks*32 + l16*8);
      #pragma unroll
      for (int mt = 0; mt < 4; mt++){
        bf16x8 af = *(const bf16x8*)(&hid[(mt*16 + ln15)*136 + ks*32 + l16*8]);
        #pragma unroll
        for (int nt3 = 0; nt3 < 3; nt3++)
          o2[mt][nt3] = MFMA16(af, bw2[nt3], o2[mt][nt3]);
      }
    }
    __syncthreads();
  }
  // ---- epilogue: stage to LDS (o2 dies) ----
  #pragma unroll
  for (int nt3 = 0; nt3 < 3; nt3++){
    const int col = wv*48 + nt3*16 + ln15;
    #pragma unroll
    for (int mt = 0; mt < 4; mt++)
      #pragma unroll
      for (int reg = 0; reg < 4; reg++)
        ep[(mt*16 + l16*4 + reg)*196 + col] = o2[mt][nt3][reg];
  }
  __syncthreads();
  const float* xrow = xb + (p0 + t)*192;
  if (!fuse){
    float* orow = xb2 + (p0 + t)*192;
    #pragma unroll
    for (int i = 0; i < 12; i++){
      float4 mv  = *(float4*)(ep + t*196 + c0 + i*4);
      float4 x2  = *(const float4*)(xrow2 + c0 + i*4);
      float4 xr  = *(const float4*)(xrow + c0 + i*4);
      float4 fb4 = *(const float4*)(fc2b + c0 + i*4);
      float4 o;
      o.x = x2.x + xr.x + fb4.x + mv.x;
      o.y = x2.y + xr.y + fb4.y + mv.y;
      o.z = x2.z + xr.z + fb4.z + mv.z;
      o.w = x2.w + xr.w + fb4.w + mv.w;
      *(float4*)(orow + c0 + i*4) = o;
    }
  } else {
    // final value + clamp back into ep, then NCHW transposed write (replaces final_k)
    #pragma unroll
    for (int i = 0; i < 12; i++){
      float4 mv  = *(float4*)(ep + t*196 + c0 + i*4);
      float4 x2  = *(const float4*)(xrow2 + c0 + i*4);
      float4 xr  = *(const float4*)(xrow + c0 + i*4);
      float4 fb4 = *(const float4*)(fc2b + c0 + i*4);
      float4 o;
      o.x = fminf(fmaxf(x2.x + xr.x + fb4.x + mv.x, -10.f), 10.f);
      o.y = fminf(fmaxf(x2.y + xr.y + fb4.y + mv.y, -10.f), 10.f);
      o.z = fminf(fmaxf(x2.z + xr.z + fb4.z + mv.z, -10.f), 10.f);
      o.w = fminf(fmaxf(x2.w + xr.w + fb4.w + mv.w, -10.f), 10.f);
      *(float4*)(ep + t*196 + c0 + i*4) = o;
    }
    __syncthreads();
    // NCHW transposed write: 12 x 256 threads cover all 64 pixels x 192 channels
    const int bidx   = (int)(p0 >> 14);
    const int imgoff = (int)(p0 & 16383);
    #pragma unroll 1
    for (int i = 0; i < 12; i++){
      const int id = i*256 + tid;
      const int c = id >> 4, pq = id & 15;
      float4 o4;
      o4.x = ep[(pq*4    )*196 + c];
      o4.y = ep[(pq*4 + 1)*196 + c];
      o4.z = ep[(pq*4 + 2)*196 + c];
      o4.w = ep[(pq*4 + 3)*196 + c];
      *(float4*)(outp + (((size_t)(bidx*192 + c)) << 14) + imgoff + pq*4) = o4;
    }
  }
}

// ---------------- final NHWC -> NCHW + clamp (legacy path only) ----------------
__global__ void final_k(const float* __restrict__ xb2, float* __restrict__ out){
  __shared__ float tile[192*64];
  int blk = blockIdx.x, tid = threadIdx.x;
  int b = blk >> 8, p0 = (blk & 255) * 64;
  #pragma unroll 1
  for (int i = 0; i < 12; i++){
    int idx4 = i*256 + tid;
    int tt = idx4 / 48, c4 = idx4 - tt*48;
    int cb = c4 * 4;
    float4 v = *(const float4*)(xb2 + ((size_t)blk*64 + tt)*192 + cb);
    tile[(cb  )*64 + ((tt + cb    ) & 63)] = v.x;
    tile[(cb+1)*64 + ((tt + cb + 1) & 63)] = v.y;
    tile[(cb+2)*64 + ((tt + cb + 2) & 63)] = v.z;
    tile[(cb+3)*64 + ((tt + cb + 3) & 63)] = v.w;
  }
  __syncthreads();
  #pragma unroll 1
  for (int i = 0; i < 12; i++){
    int idx4 = i*256 + tid;
    int c = idx4 >> 4, pq = idx4 & 15;
    int pb_ = pq*4;
    float4 o;
    o.x = tile[c*64 + ((pb_     + c) & 63)];
    o.y = tile[c*64 + ((pb_ + 1 + c) & 63)];
    o.z = tile[c*64 + ((pb_ + 2 + c) & 63)];
    o.w = tile[c*64 + ((pb_ + 3 + c) & 63)];
    o.x = fminf(fmaxf(o.x, -10.f), 10.f);
    o.y = fminf(fmaxf(o.y, -10.f), 10.f);
    o.z = fminf(fmaxf(o.z, -10.f), 10.f);
    o.w = fminf(fmaxf(o.w, -10.f), 10.f);
    *(float4*)(out + (((size_t)b*192 + c) << 14) + p0 + pb_) = o;
  }
}

extern "C" void kernel_launch(void* const* d_in, const int* in_sizes, int n_in,
                              void* d_out, int out_size, void* d_ws, size_t ws_size,
                              hipStream_t stream){
  (void)in_sizes; (void)n_in; (void)out_size;
  const float* x     = (const float*)d_in[0];
  const float* gnw   = (const float*)d_in[1];
  const float* gnb   = (const float*)d_in[2];
  const float* ln1w  = (const float*)d_in[3];
  const float* ln1b  = (const float*)d_in[4];
  const float* qkvw  = (const float*)d_in[5];
  const float* qkvb  = (const float*)d_in[6];
  const float* projw = (const float*)d_in[7];
  const float* projb = (const float*)d_in[8];
  const float* rpb   = (const float*)d_in[9];
  const float* ln2w  = (const float*)d_in[10];
  const float* ln2b  = (const float*)d_in[11];
  const float* fc1w  = (const float*)d_in[12];
  const float* fc1b  = (const float*)d_in[13];
  const float* fc2w  = (const float*)d_in[14];
  const float* fc2b  = (const float*)d_in[15];
  float* out = (float*)d_out;

  float* ws    = (float*)d_ws;
  float* xb2   = ws;                       // [B,H,W,C] fp32
  float* part  = xb2  + 25165824;
  float* stats = part + 3072;
  unsigned short* qkvB = (unsigned short*)(stats + 16);  // [576][192] bf16
  unsigned short* projB = qkvB + 110592;                 // [192][192]
  unsigned short* fc1B  = projB + 36864;                 // [768][192]
  unsigned short* fc2B  = fc1B + 147456;                 // [192][768]

  // fused path: xb (GN out / residual base) lives in ws so mlp can write final NCHW
  // output directly to d_out (no aliasing race). float offset 25390096, need 202223680 B.
  const int fuse = (ws_size >= 202223680ULL) ? 1 : 0;
  float* xb = fuse ? (ws + 25390096) : out;

  transpose_cast_all<<<1728, 256, 0, stream>>>(qkvw, projw, fc1w, fc2w, qkvB, projB, fc1B, fc2B);
  gn_partial<<<1536, 256, 0, stream>>>(x, part);
  gn_final<<<8, 64, 0, stream>>>(part, stats);
  gn_apply<<<2048, 256, 0, stream>>>(x, stats, gnw, gnb, xb);
  attn_kernel<<<2048, 256, 0, stream>>>(xb, xb2, ln1w, ln1b, qkvB, qkvb, projB, projb, rpb);
  mlp_kernel<<<2048, 256, 0, stream>>>(xb, xb2, ln2w, ln2b, fc1B, fc1b, fc2B, fc2b, out, fuse);
  if (!fuse) final_k<<<2048, 256, 0, stream>>>(xb2, out);
}

// Round 5
// 814.498 us; speedup vs baseline: 1.3318x; 1.1348x over previous
//
#include <hip/hip_runtime.h>
#include <cstddef>

typedef __attribute__((ext_vector_type(8))) short bf16x8;
typedef __attribute__((ext_vector_type(4))) float f32x4;
typedef __attribute__((ext_vector_type(4))) short s16x4;

#define DEV __device__ __forceinline__
#define MFMA16(a,b,c) __builtin_amdgcn_mfma_f32_16x16x32_bf16((a),(b),(c),0,0,0)

DEV unsigned short f2bf(float f){
  unsigned int x = __float_as_uint(f);
  x += 0x7fffu + ((x >> 16) & 1u);
  return (unsigned short)(x >> 16);
}
DEV unsigned int pack2(float a, float b){
  return (unsigned int)f2bf(a) | ((unsigned int)f2bf(b) << 16);
}
// branchless erf-GELU, Abramowitz-Stegun 7.1.26 (|err| <= 1.5e-7)
DEV float gelu_f(float x){
  float z = fabsf(x) * 0.7071067811865475f;
  float tt = 1.f / (1.f + 0.3275911f * z);
  float poly = tt*(0.254829592f + tt*(-0.284496736f + tt*(1.421413741f +
               tt*(-1.453152027f + tt*1.061405429f))));
  float er = 1.f - poly * __expf(-z*z);
  er = (x < 0.f) ? -er : er;
  return 0.5f * x * (1.f + er);
}

// ---------------- all weight transposes + bf16 cast in one launch ----------------
__global__ void transpose_cast_all(const float* __restrict__ qkvw, const float* __restrict__ projw,
                                   const float* __restrict__ fc1w, const float* __restrict__ fc2w,
                                   unsigned short* __restrict__ qkvB, unsigned short* __restrict__ projB,
                                   unsigned short* __restrict__ fc1B, unsigned short* __restrict__ fc2B){
  int blk = blockIdx.x;
  const float* in; unsigned short* outp; int K, N, idx;
  if (blk < 432){        in = qkvw; outp = qkvB; K = 192; N = 576; idx = blk*256 + threadIdx.x; }
  else if (blk < 576){   in = projw; outp = projB; K = 192; N = 192; idx = (blk-432)*256 + threadIdx.x; }
  else if (blk < 1152){  in = fc1w; outp = fc1B; K = 192; N = 768; idx = (blk-576)*256 + threadIdx.x; }
  else {                 in = fc2w; outp = fc2B; K = 768; N = 192; idx = (blk-1152)*256 + threadIdx.x; }
  if (idx < K * N){
    int n = idx / K, k = idx - n * K;
    outp[idx] = f2bf(in[k * N + n]);
  }
}

// ---------------- GroupNorm stage 1 ----------------
__global__ void gn_partial(const float* __restrict__ x, float* __restrict__ part){
  int bc = blockIdx.x, tid = threadIdx.x;
  const float4* p = (const float4*)(x + (size_t)bc * 16384);
  float s = 0.f, s2 = 0.f;
  for (int i = tid; i < 4096; i += 256){
    float4 v = p[i];
    s  += v.x + v.y + v.z + v.w;
    s2 += v.x*v.x + v.y*v.y + v.z*v.z + v.w*v.w;
  }
  #pragma unroll
  for (int off = 32; off; off >>= 1){ s += __shfl_down(s, off); s2 += __shfl_down(s2, off); }
  __shared__ float red[8];
  int wid = tid >> 6;
  if ((tid & 63) == 0){ red[wid*2] = s; red[wid*2+1] = s2; }
  __syncthreads();
  if (tid == 0){
    part[bc*2]   = red[0] + red[2] + red[4] + red[6];
    part[bc*2+1] = red[1] + red[3] + red[5] + red[7];
  }
}

// ---------------- GroupNorm stage 2 ----------------
__global__ void gn_final(const float* __restrict__ part, float* __restrict__ stats){
  int b = blockIdx.x, tid = threadIdx.x;
  float s = 0.f, s2 = 0.f;
  for (int c = tid; c < 192; c += 64){
    s  += part[(b*192 + c)*2];
    s2 += part[(b*192 + c)*2 + 1];
  }
  #pragma unroll
  for (int off = 32; off; off >>= 1){ s += __shfl_down(s, off); s2 += __shfl_down(s2, off); }
  if (tid == 0){
    const float inv = 1.f / (192.f * 16384.f);
    float mean = s * inv;
    float var  = s2 * inv - mean*mean;
    stats[b*2]   = mean;
    stats[b*2+1] = rsqrtf(var + 1e-5f);
  }
}

// ---------------- GN apply + NCHW -> NHWC ----------------
__global__ void gn_apply(const float* __restrict__ x, const float* __restrict__ stats,
                         const float* __restrict__ gnw, const float* __restrict__ gnb,
                         float* __restrict__ xb){
  __shared__ float tile[192*64];
  int blk = blockIdx.x, tid = threadIdx.x;
  int b = blk >> 8, p0 = (blk & 255) * 64;
  float mean = stats[b*2], rstd = stats[b*2+1];
  #pragma unroll 1
  for (int i = 0; i < 12; i++){
    int idx4 = i*256 + tid;
    int c = idx4 >> 4, pq = idx4 & 15;
    float4 v = *(const float4*)(x + (((size_t)b*192 + c) << 14) + p0 + pq*4);
    float w  = gnw[c] * rstd;
    float bb = gnb[c] - mean * rstd * gnw[c];
    int pb_ = pq*4;
    tile[c*64 + ((pb_     + c) & 63)] = v.x * w + bb;
    tile[c*64 + ((pb_ + 1 + c) & 63)] = v.y * w + bb;
    tile[c*64 + ((pb_ + 2 + c) & 63)] = v.z * w + bb;
    tile[c*64 + ((pb_ + 3 + c) & 63)] = v.w * w + bb;
  }
  __syncthreads();
  #pragma unroll 1
  for (int i = 0; i < 12; i++){
    int idx4 = i*256 + tid;
    int pix = idx4 / 48, c4 = idx4 - pix*48;
    int cb = c4 * 4;
    float4 o;
    o.x = tile[(cb  )*64 + ((pix + cb    ) & 63)];
    o.y = tile[(cb+1)*64 + ((pix + cb + 1) & 63)];
    o.z = tile[(cb+2)*64 + ((pix + cb + 2) & 63)];
    o.w = tile[(cb+3)*64 + ((pix + cb + 3) & 63)];
    *(float4*)(xb + ((size_t)blk*64 + pix)*192 + cb) = o;
  }
}

// ---------------- fused window attention (MFMA) ----------------
// (unchanged from round 4 — passing, spill-free)
__launch_bounds__(256, 3)
__global__ void attn_kernel(const float* __restrict__ xb, float* __restrict__ xb2,
                            const float* __restrict__ ln1w, const float* __restrict__ ln1b,
                            const unsigned short* __restrict__ qkvB, const float* __restrict__ qkvb,
                            const unsigned short* __restrict__ projB, const float* __restrict__ projb,
                            const float* __restrict__ rpb){
  __shared__ __align__(16) unsigned char smem[49408];
  int* regions = (int*)(smem + 49152);

  const int tid = threadIdx.x;
  const int blk = blockIdx.x;
  const int b = blk >> 8, wloc = blk & 255, wh = wloc >> 4, ww = wloc & 15;
  const int lane = tid & 63, wv = tid >> 6;
  const int ln15 = lane & 15, l16 = lane >> 4;
  const f32x4 zero4 = {0.f, 0.f, 0.f, 0.f};

  const int t = tid >> 2, q4 = tid & 3, c0 = q4 * 48;
  const int tr = t >> 3, tc = t & 7;
  const int sh = (wh*8 + tr + 4) & 127, sw = (ww*8 + tc + 4) & 127;
  const float* xrow = xb + (size_t)((((b << 7) + sh) << 7) + sw) * 192;
  float lnm, lnr;
  const int hswz = (t & 7) << 4;

  // ---- LN1 ----
  {
    float4 xt[12];
    float s = 0.f, s2 = 0.f;
    #pragma unroll
    for (int i = 0; i < 12; i++){
      xt[i] = *(const float4*)(xrow + c0 + i*4);
      s  += xt[i].x + xt[i].y + xt[i].z + xt[i].w;
      s2 += xt[i].x*xt[i].x + xt[i].y*xt[i].y + xt[i].z*xt[i].z + xt[i].w*xt[i].w;
    }
    s  += __shfl_xor(s, 1);  s  += __shfl_xor(s, 2);
    s2 += __shfl_xor(s2, 1); s2 += __shfl_xor(s2, 2);
    lnm = s * (1.f/192.f);
    lnr = rsqrtf(s2 * (1.f/192.f) - lnm*lnm + 1e-5f);
    #pragma unroll
    for (int i = 0; i < 12; i++){
      int cb = c0 + i*4;
      float4 w4 = *(const float4*)(ln1w + cb);
      float4 b4 = *(const float4*)(ln1b + cb);
      uint2 u;
      u.x = pack2((xt[i].x - lnm)*lnr*w4.x + b4.x, (xt[i].y - lnm)*lnr*w4.y + b4.y);
      u.y = pack2((xt[i].z - lnm)*lnr*w4.z + b4.z, (xt[i].w - lnm)*lnr*w4.w + b4.w);
      *(uint2*)(smem + t*384 + ((cb*2) ^ hswz)) = u;
    }
    if (q4 == 0){
      int gh = wh*8 + tr, gw = ww*8 + tc;
      regions[t] = (gh < 120 ? 0 : (gh < 124 ? 1 : 2)) * 3 + (gw < 120 ? 0 : (gw < 124 ? 1 : 2));
    }
  }
  __syncthreads();

  f32x4 pacc[4][3];
  #pragma unroll
  for (int mt = 0; mt < 4; mt++)
    #pragma unroll
    for (int nt = 0; nt < 3; nt++)
      pacc[mt][nt] = zero4;

  const float scale = 0.17677669529663687f;

  #pragma unroll 1
  for (int hp = 0; hp < 3; hp++){
    const int h0 = hp * 2;
    if (hp){
      __syncthreads();
      #pragma unroll 2
      for (int i = 0; i < 12; i++){
        int cb = c0 + i*4;
        float4 xi = *(const float4*)(xrow + cb);
        float4 w4 = *(const float4*)(ln1w + cb);
        float4 b4 = *(const float4*)(ln1b + cb);
        uint2 u;
        u.x = pack2((xi.x - lnm)*lnr*w4.x + b4.x, (xi.y - lnm)*lnr*w4.y + b4.y);
        u.y = pack2((xi.z - lnm)*lnr*w4.z + b4.z, (xi.w - lnm)*lnr*w4.w + b4.w);
        *(uint2*)(smem + t*384 + ((cb*2) ^ hswz)) = u;
      }
      __syncthreads();
    }

    // ---- qkv for heads h0,h0+1 ----
    #pragma unroll 1
    for (int tt0 = 0; tt0 < 3; tt0++){
      const int tt = wv*3 + tt0;
      const int which = tt >> 2, sub = tt & 3;
      const int colb = which*192 + h0*32 + sub*16;
      const unsigned short* bp = qkvB + (size_t)(colb + ln15)*192 + l16*8;
      bf16x8 bw[6];
      #pragma unroll
      for (int ks = 0; ks < 6; ks++) bw[ks] = *(const bf16x8*)(bp + ks*32);
      f32x4 acc[4];
      #pragma unroll
      for (int mt = 0; mt < 4; mt++){
        acc[mt] = zero4;
        const int arow = mt*16 + ln15;
        const unsigned char* ap = smem + arow*384;
        const int aswz = (arow & 7) << 4;
        #pragma unroll
        for (int ks = 0; ks < 6; ks++){
          bf16x8 af = *(const bf16x8*)(ap + ((ks*64 + l16*16) ^ aswz));
          acc[mt] = MFMA16(af, bw[ks], acc[mt]);
        }
      }
      const float bias = qkvb[colb + ln15];
      const int local = sub*16 + ln15;
      const int hl = local >> 5, d = local & 31;
      if (which == 2){
        unsigned char* vbase = smem + 40960 + hl*4096 + d*128;
        const int vswz = (d & 7) << 4;
        #pragma unroll
        for (int mt = 0; mt < 4; mt++){
          const int tk2 = (mt*16 + l16*4) * 2;
          *(unsigned int*)(vbase + ((tk2    ) ^ vswz)) = pack2(acc[mt][0] + bias, acc[mt][1] + bias);
          *(unsigned int*)(vbase + ((tk2 + 4) ^ vswz)) = pack2(acc[mt][2] + bias, acc[mt][3] + bias);
        }
      } else {
        unsigned char* qkb = smem + 24576 + hl*8192;
        const int koff = which ? 64 : 0;
        const float mul = which ? 1.f : scale;
        #pragma unroll
        for (int mt = 0; mt < 4; mt++)
          #pragma unroll
          for (int reg = 0; reg < 4; reg++){
            const int tok = mt*16 + l16*4 + reg;
            *(unsigned short*)(qkb + tok*128 + ((koff + d*2) ^ ((tok & 7) << 4))) =
                f2bf((acc[mt][reg] + bias) * mul);
          }
      }
    }
    __syncthreads();

    // ---- attention: both heads ----
    #pragma unroll 1
    for (int e = 0; e < 2; e++){
      const int h = h0 + e;
      const unsigned char* qkb = smem + 24576 + e*8192;
      const int arow = wv*16 + ln15;
      const int aswz = (arow & 7) << 4;
      bf16x8 aq = *(const bf16x8*)(qkb + arow*128 + ((l16*16) ^ aswz));
      f32x4 sacc[4];
      #pragma unroll
      for (int nt = 0; nt < 4; nt++){
        const int brow = nt*16 + ln15;
        bf16x8 bk = *(const bf16x8*)(qkb + brow*128 + ((64 + l16*16) ^ ((brow & 7) << 4)));
        sacc[nt] = MFMA16(aq, bk, zero4);
      }
      #pragma unroll
      for (int nt = 0; nt < 4; nt++){
        const int j_tok = nt*16 + ln15;
        const int rj = j_tok >> 3, cj = j_tok & 7;
        const int regj = regions[j_tok];
        #pragma unroll
        for (int reg = 0; reg < 4; reg++){
          const int i_tok = wv*16 + l16*4 + reg;
          const int ri = i_tok >> 3, ci = i_tok & 7;
          float bias = rpb[((ri - rj + 7)*15 + (ci - cj + 7))*6 + h];
          sacc[nt][reg] += bias + ((regions[i_tok] == regj) ? 0.f : -100.f);
        }
      }
      float mx[4], sum[4];
      #pragma unroll
      for (int reg = 0; reg < 4; reg++){
        float m = fmaxf(fmaxf(sacc[0][reg], sacc[1][reg]), fmaxf(sacc[2][reg], sacc[3][reg]));
        m = fmaxf(m, __shfl_xor(m, 1));
        m = fmaxf(m, __shfl_xor(m, 2));
        m = fmaxf(m, __shfl_xor(m, 4));
        m = fmaxf(m, __shfl_xor(m, 8));
        mx[reg] = m; sum[reg] = 0.f;
      }
      #pragma unroll
      for (int nt = 0; nt < 4; nt++)
        #pragma unroll
        for (int reg = 0; reg < 4; reg++){
          float ex = __expf(sacc[nt][reg] - mx[reg]);
          sacc[nt][reg] = ex;
          sum[reg] += ex;
        }
      #pragma unroll
      for (int reg = 0; reg < 4; reg++){
        float sm = sum[reg];
        sm += __shfl_xor(sm, 1);
        sm += __shfl_xor(sm, 2);
        sm += __shfl_xor(sm, 4);
        sm += __shfl_xor(sm, 8);
        sum[reg] = 1.f / sm;
      }
      #pragma unroll
      for (int nt = 0; nt < 4; nt++)
        #pragma unroll
        for (int reg = 0; reg < 4; reg++){
          const int tok = wv*16 + l16*4 + reg;
          *(unsigned short*)(smem + tok*128 + (((nt*16 + ln15)*2) ^ ((tok & 7) << 4))) =
              f2bf(sacc[nt][reg] * sum[reg]);
        }
      f32x4 cacc[2] = {zero4, zero4};
      #pragma unroll
      for (int ks = 0; ks < 2; ks++){
        bf16x8 pa = *(const bf16x8*)(smem + arow*128 + ((ks*64 + l16*16) ^ aswz));
        #pragma unroll
        for (int nt2 = 0; nt2 < 2; nt2++){
          const int drow = nt2*16 + ln15;
          bf16x8 bv = *(const bf16x8*)(smem + 40960 + e*4096 + drow*128 +
                                       ((ks*64 + l16*16) ^ ((drow & 7) << 4)));
          cacc[nt2] = MFMA16(pa, bv, cacc[nt2]);
        }
      }
      #pragma unroll
      for (int nt2 = 0; nt2 < 2; nt2++)
        #pragma unroll
        for (int reg = 0; reg < 4; reg++){
          const int tok = wv*16 + l16*4 + reg;
          const int col = e*32 + nt2*16 + ln15;
          *(unsigned short*)(smem + 8192 + tok*128 + ((col*2) ^ ((tok & 7) << 4))) =
              f2bf(cacc[nt2][reg]);
        }
    }
    __syncthreads();

    // ---- proj accumulate ----
    #pragma unroll
    for (int ks = 0; ks < 2; ks++){
      bf16x8 bw3[3];
      #pragma unroll
      for (int nt3 = 0; nt3 < 3; nt3++)
        bw3[nt3] = *(const bf16x8*)(projB + (size_t)(wv*48 + nt3*16 + ln15)*192 + h0*32 + ks*32 + l16*8);
      #pragma unroll
      for (int mt = 0; mt < 4; mt++){
        const int crow = mt*16 + ln15;
        bf16x8 ac = *(const bf16x8*)(smem + 8192 + crow*128 + ((ks*64 + l16*16) ^ ((crow & 7) << 4)));
        #pragma unroll
        for (int nt3 = 0; nt3 < 3; nt3++)
          pacc[mt][nt3] = MFMA16(ac, bw3[nt3], pacc[mt][nt3]);
      }
    }
  }
  __syncthreads();

  // ---- epilogue ----
  #pragma unroll
  for (int nt3 = 0; nt3 < 3; nt3++){
    const int col4 = (wv*48 + nt3*16 + ln15) * 4;
    #pragma unroll
    for (int mt = 0; mt < 4; mt++)
      #pragma unroll
      for (int reg = 0; reg < 4; reg++){
        const int row = mt*16 + l16*4 + reg;
        *(float*)(smem + row*768 + (col4 ^ ((row & 7) << 4))) = pacc[mt][nt3][reg];
      }
  }
  __syncthreads();
  {
    #pragma unroll
    for (int i = 0; i < 12; i++){
      const int id = i*256 + tid;
      const int tok = id / 48, c4 = id - tok*48;
      const int trr = tok >> 3, tcc = tok & 7;
      const int shh = (wh*8 + trr + 4) & 127, sww = (ww*8 + tcc + 4) & 127;
      const size_t goff = ((size_t)((((b << 7) + shh) << 7) + sww)) * 192 + c4*4;
      float4 pv  = *(const float4*)(smem + tok*768 + ((c4*16) ^ ((tok & 7) << 4)));
      float4 xr  = *(const float4*)(xb + goff);
      float4 pb4 = *(const float4*)(projb + c4*4);
      float4 o;
      o.x = xr.x + pv.x + pb4.x;
      o.y = xr.y + pv.y + pb4.y;
      o.z = xr.z + pv.z + pb4.z;
      o.w = xr.w + pv.w + pb4.w;
      *(float4*)(xb2 + goff) = o;
    }
  }
}

// ---------------- fused MLP (MFMA): LN2 + fc1 + GELU + fc2 + residuals ----------------
// Rewritten r5: swapped-operand MFMA (D = [col][tok]) -> hid written as b64, ep as float4;
// XOR-swizzled pow2 LDS (aln [64][384B], hid 2x[64][128B], ep [64][768B]);
// hid double-buffered with fc2(ch-1) || fc1(ch) interleave (12 x 64-col chunks).
// fuse=1: final NCHW transpose + clamp fused (final_k eliminated).
__launch_bounds__(256, 3)
__global__ void mlp_kernel(const float* __restrict__ xb, float* __restrict__ xb2,
                           const float* __restrict__ ln2w, const float* __restrict__ ln2b,
                           const unsigned short* __restrict__ fc1B, const float* __restrict__ fc1b,
                           const unsigned short* __restrict__ fc2B, const float* __restrict__ fc2b,
                           float* __restrict__ outp, const int fuse){
  // aln @0      [64 tok][384B] bf16, swz ((tok&7)<<4)   24576
  // hid @24576  [2][64 tok][128B] bf16, swz ((tok&7)<<4) 16384  (total 40960)
  // ep  @0      [64 tok][768B] fp32, swz (epilogue alias) 49152
  __shared__ __align__(16) unsigned char smem[49152];

  const int tid = threadIdx.x;
  const int lane = tid & 63, wv = tid >> 6;
  const int ln15 = lane & 15, l16 = lane >> 4;
  const size_t p0 = (size_t)blockIdx.x * 64;
  const f32x4 zero4 = {0.f, 0.f, 0.f, 0.f};

  const int t = tid >> 2, q4 = tid & 3, c0 = q4 * 48;
  const int hswz = (t & 7) << 4;
  const float* xrow2 = xb2 + (p0 + t)*192;

  // ---- LN2 (reads scoped) ----
  {
    float4 xt[12];
    float s = 0.f, s2 = 0.f;
    #pragma unroll
    for (int i = 0; i < 12; i++){
      xt[i] = *(const float4*)(xrow2 + c0 + i*4);
      s  += xt[i].x + xt[i].y + xt[i].z + xt[i].w;
      s2 += xt[i].x*xt[i].x + xt[i].y*xt[i].y + xt[i].z*xt[i].z + xt[i].w*xt[i].w;
    }
    s  += __shfl_xor(s, 1);  s  += __shfl_xor(s, 2);
    s2 += __shfl_xor(s2, 1); s2 += __shfl_xor(s2, 2);
    const float mean = s * (1.f/192.f);
    const float rstd = rsqrtf(s2 * (1.f/192.f) - mean*mean + 1e-5f);
    #pragma unroll
    for (int i = 0; i < 12; i++){
      int cb = c0 + i*4;
      float4 w4 = *(const float4*)(ln2w + cb);
      float4 b4 = *(const float4*)(ln2b + cb);
      uint2 u;
      u.x = pack2((xt[i].x - mean)*rstd*w4.x + b4.x, (xt[i].y - mean)*rstd*w4.y + b4.y);
      u.y = pack2((xt[i].z - mean)*rstd*w4.z + b4.z, (xt[i].w - mean)*rstd*w4.w + b4.w);
      *(uint2*)(smem + t*384 + ((cb*2) ^ hswz)) = u;
    }
  }
  __syncthreads();

  f32x4 o2[4][3];
  #pragma unroll
  for (int mt = 0; mt < 4; mt++)
    #pragma unroll
    for (int nt = 0; nt < 3; nt++)
      o2[mt][nt] = zero4;

  // ---- fc1 chunk 0 (prologue) ----
  {
    const unsigned short* bp1 = fc1B + (size_t)(wv*16 + ln15)*192 + l16*8;
    bf16x8 w1[6];
    #pragma unroll
    for (int ks = 0; ks < 6; ks++) w1[ks] = *(const bf16x8*)(bp1 + ks*32);
    const float4 b1 = *(const float4*)(fc1b + wv*16 + l16*4);
    unsigned char* hb = smem + 24576;
    #pragma unroll
    for (int mt = 0; mt < 4; mt++){
      f32x4 facc = zero4;
      const int arow = mt*16 + ln15;
      const unsigned char* ap = smem + arow*384;
      const int aswz = (arow & 7) << 4;
      #pragma unroll
      for (int ks = 0; ks < 6; ks++){
        bf16x8 af = *(const bf16x8*)(ap + ((ks*64 + l16*16) ^ aswz));
        facc = MFMA16(w1[ks], af, facc);       // D[hcol][tok]
      }
      s16x4 hv;
      hv.x = (short)f2bf(gelu_f(facc[0] + b1.x));
      hv.y = (short)f2bf(gelu_f(facc[1] + b1.y));
      hv.z = (short)f2bf(gelu_f(facc[2] + b1.z));
      hv.w = (short)f2bf(gelu_f(facc[3] + b1.w));
      *(s16x4*)(hb + arow*128 + ((wv*32 + l16*8) ^ aswz)) = hv;
    }
  }
  __syncthreads();

  // ---- main pipeline: fc2(ch-1) || fc1(ch) ----
  #pragma unroll 1
  for (int ch = 1; ch < 12; ch++){
    // issue all weight loads up front
    bf16x8 w2[3][2];
    #pragma unroll
    for (int nt3 = 0; nt3 < 3; nt3++)
      #pragma unroll
      for (int ks = 0; ks < 2; ks++)
        w2[nt3][ks] = *(const bf16x8*)(fc2B + (size_t)(wv*48 + nt3*16 + ln15)*768 +
                                       (ch-1)*64 + ks*32 + l16*8);
    const unsigned short* bp1 = fc1B + (size_t)(ch*64 + wv*16 + ln15)*192 + l16*8;
    bf16x8 w1[6];
    #pragma unroll
    for (int ks = 0; ks < 6; ks++) w1[ks] = *(const bf16x8*)(bp1 + ks*32);
    const float4 b1 = *(const float4*)(fc1b + ch*64 + wv*16 + l16*4);

    // fc2(ch-1): reads hid buf[(ch-1)&1]
    {
      const unsigned char* hb = smem + 24576 + ((ch-1)&1)*8192;
      #pragma unroll
      for (int mt = 0; mt < 4; mt++){
        const int brow = mt*16 + ln15;
        const unsigned char* bp = hb + brow*128;
        const int bswz = (brow & 7) << 4;
        #pragma unroll
        for (int ks = 0; ks < 2; ks++){
          bf16x8 hf = *(const bf16x8*)(bp + ((ks*64 + l16*16) ^ bswz));
          #pragma unroll
          for (int nt3 = 0; nt3 < 3; nt3++)
            o2[mt][nt3] = MFMA16(w2[nt3][ks], hf, o2[mt][nt3]);   // D[outcol][tok]
        }
      }
    }
    // fc1(ch): writes hid buf[ch&1]
    {
      unsigned char* hb = smem + 24576 + (ch&1)*8192;
      #pragma unroll
      for (int mt = 0; mt < 4; mt++){
        f32x4 facc = zero4;
        const int arow = mt*16 + ln15;
        const unsigned char* ap = smem + arow*384;
        const int aswz = (arow & 7) << 4;
        #pragma unroll
        for (int ks = 0; ks < 6; ks++){
          bf16x8 af = *(const bf16x8*)(ap + ((ks*64 + l16*16) ^ aswz));
          facc = MFMA16(w1[ks], af, facc);
        }
        s16x4 hv;
        hv.x = (short)f2bf(gelu_f(facc[0] + b1.x));
        hv.y = (short)f2bf(gelu_f(facc[1] + b1.y));
        hv.z = (short)f2bf(gelu_f(facc[2] + b1.z));
        hv.w = (short)f2bf(gelu_f(facc[3] + b1.w));
        *(s16x4*)(hb + arow*128 + ((wv*32 + l16*8) ^ aswz)) = hv;
      }
    }
    __syncthreads();
  }

  // ---- fc2 chunk 11 (epilogue) ----
  {
    bf16x8 w2[3][2];
    #pragma unroll
    for (int nt3 = 0; nt3 < 3; nt3++)
      #pragma unroll
      for (int ks = 0; ks < 2; ks++)
        w2[nt3][ks] = *(const bf16x8*)(fc2B + (size_t)(wv*48 + nt3*16 + ln15)*768 +
                                       11*64 + ks*32 + l16*8);
    const unsigned char* hb = smem + 24576 + 8192;  // buf1
    #pragma unroll
    for (int mt = 0; mt < 4; mt++){
      const int brow = mt*16 + ln15;
      const unsigned char* bp = hb + brow*128;
      const int bswz = (brow & 7) << 4;
      #pragma unroll
      for (int ks = 0; ks < 2; ks++){
        bf16x8 hf = *(const bf16x8*)(bp + ((ks*64 + l16*16) ^ bswz));
        #pragma unroll
        for (int nt3 = 0; nt3 < 3; nt3++)
          o2[mt][nt3] = MFMA16(w2[nt3][ks], hf, o2[mt][nt3]);
      }
    }
  }
  __syncthreads();   // aln/hid dead; reuse smem as ep [64][768B] swz

  // ---- ep staging: float4 writes (thread holds 4 consecutive outcols / token) ----
  #pragma unroll
  for (int mt = 0; mt < 4; mt++){
    const int tok = mt*16 + ln15;
    const int tswz = (tok & 7) << 4;
    unsigned char* rp = smem + tok*768;
    #pragma unroll
    for (int nt3 = 0; nt3 < 3; nt3++){
      const int cb = wv*192 + nt3*64 + l16*16;
      *(f32x4*)(rp + (cb ^ tswz)) = o2[mt][nt3];
    }
  }
  __syncthreads();

  const float* xrow = xb + (p0 + t)*192;
  if (!fuse){
    float* orow = xb2 + (p0 + t)*192;
    #pragma unroll
    for (int i = 0; i < 12; i++){
      float4 mv  = *(const float4*)(smem + t*768 + ((c0*4 + i*16) ^ hswz));
      float4 x2  = *(const float4*)(xrow2 + c0 + i*4);
      float4 xr  = *(const float4*)(xrow + c0 + i*4);
      float4 fb4 = *(const float4*)(fc2b + c0 + i*4);
      float4 o;
      o.x = x2.x + xr.x + fb4.x + mv.x;
      o.y = x2.y + xr.y + fb4.y + mv.y;
      o.z = x2.z + xr.z + fb4.z + mv.z;
      o.w = x2.w + xr.w + fb4.w + mv.w;
      *(float4*)(orow + c0 + i*4) = o;
    }
  } else {
    // final value + clamp back into ep (swizzled), then NCHW transposed write
    #pragma unroll
    for (int i = 0; i < 12; i++){
      const int off = (c0*4 + i*16) ^ hswz;
      float4 mv  = *(const float4*)(smem + t*768 + off);
      float4 x2  = *(const float4*)(xrow2 + c0 + i*4);
      float4 xr  = *(const float4*)(xrow + c0 + i*4);
      float4 fb4 = *(const float4*)(fc2b + c0 + i*4);
      float4 o;
      o.x = fminf(fmaxf(x2.x + xr.x + fb4.x + mv.x, -10.f), 10.f);
      o.y = fminf(fmaxf(x2.y + xr.y + fb4.y + mv.y, -10.f), 10.f);
      o.z = fminf(fmaxf(x2.z + xr.z + fb4.z + mv.z, -10.f), 10.f);
      o.w = fminf(fmaxf(x2.w + xr.w + fb4.w + mv.w, -10.f), 10.f);
      *(float4*)(smem + t*768 + off) = o;
    }
    __syncthreads();
    const int bidx   = (int)(p0 >> 14);
    const int imgoff = (int)(p0 & 16383);
    #pragma unroll 1
    for (int i = 0; i < 12; i++){
      const int id = i*256 + tid;
      const int c = id >> 4, pq = id & 15;
      float4 o4;
      o4.x = *(const float*)(smem + (pq*4    )*768 + ((c*4) ^ (((pq*4    ) & 7) << 4)));
      o4.y = *(const float*)(smem + (pq*4 + 1)*768 + ((c*4) ^ (((pq*4 + 1) & 7) << 4)));
      o4.z = *(const float*)(smem + (pq*4 + 2)*768 + ((c*4) ^ (((pq*4 + 2) & 7) << 4)));
      o4.w = *(const float*)(smem + (pq*4 + 3)*768 + ((c*4) ^ (((pq*4 + 3) & 7) << 4)));
      *(float4*)(outp + (((size_t)(bidx*192 + c)) << 14) + imgoff + pq*4) = o4;
    }
  }
}

// ---------------- final NHWC -> NCHW + clamp (legacy path only) ----------------
__global__ void final_k(const float* __restrict__ xb2, float* __restrict__ out){
  __shared__ float tile[192*64];
  int blk = blockIdx.x, tid = threadIdx.x;
  int b = blk >> 8, p0 = (blk & 255) * 64;
  #pragma unroll 1
  for (int i = 0; i < 12; i++){
    int idx4 = i*256 + tid;
    int tt = idx4 / 48, c4 = idx4 - tt*48;
    int cb = c4 * 4;
    float4 v = *(const float4*)(xb2 + ((size_t)blk*64 + tt)*192 + cb);
    tile[(cb  )*64 + ((tt + cb    ) & 63)] = v.x;
    tile[(cb+1)*64 + ((tt + cb + 1) & 63)] = v.y;
    tile[(cb+2)*64 + ((tt + cb + 2) & 63)] = v.z;
    tile[(cb+3)*64 + ((tt + cb + 3) & 63)] = v.w;
  }
  __syncthreads();
  #pragma unroll 1
  for (int i = 0; i < 12; i++){
    int idx4 = i*256 + tid;
    int c = idx4 >> 4, pq = idx4 & 15;
    int pb_ = pq*4;
    float4 o;
    o.x = tile[c*64 + ((pb_     + c) & 63)];
    o.y = tile[c*64 + ((pb_ + 1 + c) & 63)];
    o.z = tile[c*64 + ((pb_ + 2 + c) & 63)];
    o.w = tile[c*64 + ((pb_ + 3 + c) & 63)];
    o.x = fminf(fmaxf(o.x, -10.f), 10.f);
    o.y = fminf(fmaxf(o.y, -10.f), 10.f);
    o.z = fminf(fmaxf(o.z, -10.f), 10.f);
    o.w = fminf(fmaxf(o.w, -10.f), 10.f);
    *(float4*)(out + (((size_t)b*192 + c) << 14) + p0 + pb_) = o;
  }
}

extern "C" void kernel_launch(void* const* d_in, const int* in_sizes, int n_in,
                              void* d_out, int out_size, void* d_ws, size_t ws_size,
                              hipStream_t stream){
  (void)in_sizes; (void)n_in; (void)out_size;
  const float* x     = (const float*)d_in[0];
  const float* gnw   = (const float*)d_in[1];
  const float* gnb   = (const float*)d_in[2];
  const float* ln1w  = (const float*)d_in[3];
  const float* ln1b  = (const float*)d_in[4];
  const float* qkvw  = (const float*)d_in[5];
  const float* qkvb  = (const float*)d_in[6];
  const float* projw = (const float*)d_in[7];
  const float* projb = (const float*)d_in[8];
  const float* rpb   = (const float*)d_in[9];
  const float* ln2w  = (const float*)d_in[10];
  const float* ln2b  = (const float*)d_in[11];
  const float* fc1w  = (const float*)d_in[12];
  const float* fc1b  = (const float*)d_in[13];
  const float* fc2w  = (const float*)d_in[14];
  const float* fc2b  = (const float*)d_in[15];
  float* out = (float*)d_out;

  float* ws    = (float*)d_ws;
  float* xb2   = ws;                       // [B,H,W,C] fp32
  float* part  = xb2  + 25165824;
  float* stats = part + 3072;
  unsigned short* qkvB = (unsigned short*)(stats + 16);  // [576][192] bf16
  unsigned short* projB = qkvB + 110592;                 // [192][192]
  unsigned short* fc1B  = projB + 36864;                 // [768][192]
  unsigned short* fc2B  = fc1B + 147456;                 // [192][768]

  // fused path: xb (GN out / residual base) lives in ws so mlp can write final NCHW
  // output directly to d_out (no aliasing race). float offset 25390096, need 202223680 B.
  const int fuse = (ws_size >= 202223680ULL) ? 1 : 0;
  float* xb = fuse ? (ws + 25390096) : out;

  transpose_cast_all<<<1728, 256, 0, stream>>>(qkvw, projw, fc1w, fc2w, qkvB, projB, fc1B, fc2B);
  gn_partial<<<1536, 256, 0, stream>>>(x, part);
  gn_final<<<8, 64, 0, stream>>>(part, stats);
  gn_apply<<<2048, 256, 0, stream>>>(x, stats, gnw, gnb, xb);
  attn_kernel<<<2048, 256, 0, stream>>>(xb, xb2, ln1w, ln1b, qkvB, qkvb, projB, projb, rpb);
  mlp_kernel<<<2048, 256, 0, stream>>>(xb, xb2, ln2w, ln2b, fc1B, fc1b, fc2B, fc2b, out, fuse);
  if (!fuse) final_k<<<2048, 256, 0, stream>>>(xb2, out);
}

// Round 6
// 670.681 us; speedup vs baseline: 1.6174x; 1.2144x over previous
//
#include <hip/hip_runtime.h>
#include <cstddef>

typedef __attribute__((ext_vector_type(8))) short bf16x8;
typedef __attribute__((ext_vector_type(4))) float f32x4;
typedef __attribute__((ext_vector_type(4))) short s16x4;

#define DEV __device__ __forceinline__
#define MFMA16(a,b,c) __builtin_amdgcn_mfma_f32_16x16x32_bf16((a),(b),(c),0,0,0)

DEV unsigned short f2bf(float f){
  unsigned int x = __float_as_uint(f);
  x += 0x7fffu + ((x >> 16) & 1u);
  return (unsigned short)(x >> 16);
}
DEV unsigned int pack2(float a, float b){
  return (unsigned int)f2bf(a) | ((unsigned int)f2bf(b) << 16);
}
// branchless erf-GELU, Abramowitz-Stegun 7.1.26 (|err| <= 1.5e-7)
DEV float gelu_f(float x){
  float z = fabsf(x) * 0.7071067811865475f;
  float tt = 1.f / (1.f + 0.3275911f * z);
  float poly = tt*(0.254829592f + tt*(-0.284496736f + tt*(1.421413741f +
               tt*(-1.453152027f + tt*1.061405429f))));
  float er = 1.f - poly * __expf(-z*z);
  er = (x < 0.f) ? -er : er;
  return 0.5f * x * (1.f + er);
}
// Swin shifted-window region id (unshifted window coords, standard mask)
DEV int region_of(int tok, int wh, int ww){
  int gh = wh*8 + (tok >> 3), gw = ww*8 + (tok & 7);
  return (gh < 120 ? 0 : (gh < 124 ? 1 : 2)) * 3 + (gw < 120 ? 0 : (gw < 124 ? 1 : 2));
}

// ---------------- all weight transposes + bf16 cast in one launch ----------------
__global__ void transpose_cast_all(const float* __restrict__ qkvw, const float* __restrict__ projw,
                                   const float* __restrict__ fc1w, const float* __restrict__ fc2w,
                                   unsigned short* __restrict__ qkvB, unsigned short* __restrict__ projB,
                                   unsigned short* __restrict__ fc1B, unsigned short* __restrict__ fc2B){
  int blk = blockIdx.x;
  const float* in; unsigned short* outp; int K, N, idx;
  if (blk < 432){        in = qkvw; outp = qkvB; K = 192; N = 576; idx = blk*256 + threadIdx.x; }
  else if (blk < 576){   in = projw; outp = projB; K = 192; N = 192; idx = (blk-432)*256 + threadIdx.x; }
  else if (blk < 1152){  in = fc1w; outp = fc1B; K = 192; N = 768; idx = (blk-576)*256 + threadIdx.x; }
  else {                 in = fc2w; outp = fc2B; K = 768; N = 192; idx = (blk-1152)*256 + threadIdx.x; }
  if (idx < K * N){
    int n = idx / K, k = idx - n * K;
    outp[idx] = f2bf(in[k * N + n]);
  }
}

// ---------------- GroupNorm stage 1 ----------------
__global__ void gn_partial(const float* __restrict__ x, float* __restrict__ part){
  int bc = blockIdx.x, tid = threadIdx.x;
  const float4* p = (const float4*)(x + (size_t)bc * 16384);
  float s = 0.f, s2 = 0.f;
  for (int i = tid; i < 4096; i += 256){
    float4 v = p[i];
    s  += v.x + v.y + v.z + v.w;
    s2 += v.x*v.x + v.y*v.y + v.z*v.z + v.w*v.w;
  }
  #pragma unroll
  for (int off = 32; off; off >>= 1){ s += __shfl_down(s, off); s2 += __shfl_down(s2, off); }
  __shared__ float red[8];
  int wid = tid >> 6;
  if ((tid & 63) == 0){ red[wid*2] = s; red[wid*2+1] = s2; }
  __syncthreads();
  if (tid == 0){
    part[bc*2]   = red[0] + red[2] + red[4] + red[6];
    part[bc*2+1] = red[1] + red[3] + red[5] + red[7];
  }
}

// ---------------- GroupNorm stage 2 ----------------
__global__ void gn_final(const float* __restrict__ part, float* __restrict__ stats){
  int b = blockIdx.x, tid = threadIdx.x;
  float s = 0.f, s2 = 0.f;
  for (int c = tid; c < 192; c += 64){
    s  += part[(b*192 + c)*2];
    s2 += part[(b*192 + c)*2 + 1];
  }
  #pragma unroll
  for (int off = 32; off; off >>= 1){ s += __shfl_down(s, off); s2 += __shfl_down(s2, off); }
  if (tid == 0){
    const float inv = 1.f / (192.f * 16384.f);
    float mean = s * inv;
    float var  = s2 * inv - mean*mean;
    stats[b*2]   = mean;
    stats[b*2+1] = rsqrtf(var + 1e-5f);
  }
}

// ---------------- GN apply + NCHW -> NHWC ----------------
__global__ void gn_apply(const float* __restrict__ x, const float* __restrict__ stats,
                         const float* __restrict__ gnw, const float* __restrict__ gnb,
                         float* __restrict__ xb){
  __shared__ float tile[192*64];
  int blk = blockIdx.x, tid = threadIdx.x;
  int b = blk >> 8, p0 = (blk & 255) * 64;
  float mean = stats[b*2], rstd = stats[b*2+1];
  #pragma unroll 1
  for (int i = 0; i < 12; i++){
    int idx4 = i*256 + tid;
    int c = idx4 >> 4, pq = idx4 & 15;
    float4 v = *(const float4*)(x + (((size_t)b*192 + c) << 14) + p0 + pq*4);
    float w  = gnw[c] * rstd;
    float bb = gnb[c] - mean * rstd * gnw[c];
    int pb_ = pq*4;
    tile[c*64 + ((pb_     + c) & 63)] = v.x * w + bb;
    tile[c*64 + ((pb_ + 1 + c) & 63)] = v.y * w + bb;
    tile[c*64 + ((pb_ + 2 + c) & 63)] = v.z * w + bb;
    tile[c*64 + ((pb_ + 3 + c) & 63)] = v.w * w + bb;
  }
  __syncthreads();
  #pragma unroll 1
  for (int i = 0; i < 12; i++){
    int idx4 = i*256 + tid;
    int pix = idx4 / 48, c4 = idx4 - pix*48;
    int cb = c4 * 4;
    float4 o;
    o.x = tile[(cb  )*64 + ((pix + cb    ) & 63)];
    o.y = tile[(cb+1)*64 + ((pix + cb + 1) & 63)];
    o.z = tile[(cb+2)*64 + ((pix + cb + 2) & 63)];
    o.w = tile[(cb+3)*64 + ((pix + cb + 3) & 63)];
    *(float4*)(xb + ((size_t)blk*64 + pix)*192 + cb) = o;
  }
}

// ================= SPLIT PATH kernel 1: LN1 + qkv + window attention -> ctx ==========
// LDS (XOR-swizzled rows, byte_in_row ^= (row&7)<<4):
//   h16 @0      [64 tok][384B]  LN1 out (PERSISTS all pairs; no recompute)  24576
//   ctx @24576  [64 tok][128B]  pair attention out (2 heads x 32d)           8192
//   qkp @32768  [2 head][64 tok][128B: q|k]                                 16384
//   vT  @49152  [2 head][32 d][128B]                                         8192
//   ps  @57344  [64 tok][128B]  P bf16                                       8192
// total 65536 B exactly -> 2 blocks/CU; (256,2) -> 256-reg budget, no spill.
__launch_bounds__(256, 2)
__global__ void attn_qkv_kernel(const float* __restrict__ xb, unsigned short* __restrict__ ctxg,
                                const float* __restrict__ ln1w, const float* __restrict__ ln1b,
                                const unsigned short* __restrict__ qkvB, const float* __restrict__ qkvb,
                                const float* __restrict__ rpb){
  __shared__ __align__(16) unsigned char smem[65536];

  const int tid = threadIdx.x;
  const int blk = blockIdx.x;
  const int b = blk >> 8, wloc = blk & 255, wh = wloc >> 4, ww = wloc & 15;
  const int lane = tid & 63, wv = tid >> 6;
  const int ln15 = lane & 15, l16 = lane >> 4;
  const f32x4 zero4 = {0.f, 0.f, 0.f, 0.f};

  const int t = tid >> 2, q4 = tid & 3, c0 = q4 * 48;
  const int tr = t >> 3, tc = t & 7;
  const int sh = (wh*8 + tr + 4) & 127, sw = (ww*8 + tc + 4) & 127;
  const float* xrow = xb + (size_t)((((b << 7) + sh) << 7) + sw) * 192;
  const int hswz = (t & 7) << 4;

  // ---- LN1 (thread t = token, q4 = channel quarter); xb read ONCE ----
  {
    float4 xt[12];
    float s = 0.f, s2 = 0.f;
    #pragma unroll
    for (int i = 0; i < 12; i++){
      xt[i] = *(const float4*)(xrow + c0 + i*4);
      s  += xt[i].x + xt[i].y + xt[i].z + xt[i].w;
      s2 += xt[i].x*xt[i].x + xt[i].y*xt[i].y + xt[i].z*xt[i].z + xt[i].w*xt[i].w;
    }
    s  += __shfl_xor(s, 1);  s  += __shfl_xor(s, 2);
    s2 += __shfl_xor(s2, 1); s2 += __shfl_xor(s2, 2);
    const float lnm = s * (1.f/192.f);
    const float lnr = rsqrtf(s2 * (1.f/192.f) - lnm*lnm + 1e-5f);
    #pragma unroll
    for (int i = 0; i < 12; i++){
      int cb = c0 + i*4;
      float4 w4 = *(const float4*)(ln1w + cb);
      float4 b4 = *(const float4*)(ln1b + cb);
      uint2 u;
      u.x = pack2((xt[i].x - lnm)*lnr*w4.x + b4.x, (xt[i].y - lnm)*lnr*w4.y + b4.y);
      u.y = pack2((xt[i].z - lnm)*lnr*w4.z + b4.z, (xt[i].w - lnm)*lnr*w4.w + b4.w);
      *(uint2*)(smem + t*384 + ((cb*2) ^ hswz)) = u;
    }
  }
  __syncthreads();

  const float scale = 0.17677669529663687f;

  // region ids for mask (computed inline; no LDS)
  int regi[4], regj[4];
  #pragma unroll
  for (int r = 0; r < 4; r++) regi[r] = region_of(wv*16 + l16*4 + r, wh, ww);
  #pragma unroll
  for (int nt = 0; nt < 4; nt++) regj[nt] = region_of(nt*16 + ln15, wh, ww);

  #pragma unroll 1
  for (int hp = 0; hp < 3; hp++){
    const int h0 = hp * 2;

    // ---- qkv for heads h0,h0+1 (12 col-tiles of 16; wave does 3) ----
    #pragma unroll 1
    for (int tt0 = 0; tt0 < 3; tt0++){
      const int tt = wv*3 + tt0;
      const int which = tt >> 2, sub = tt & 3;     // wave-uniform
      const int colb = which*192 + h0*32 + sub*16;
      const unsigned short* bp = qkvB + (size_t)(colb + ln15)*192 + l16*8;
      bf16x8 bw[6];
      #pragma unroll
      for (int ks = 0; ks < 6; ks++) bw[ks] = *(const bf16x8*)(bp + ks*32);
      f32x4 acc[4];
      #pragma unroll
      for (int mt = 0; mt < 4; mt++){
        acc[mt] = zero4;
        const int arow = mt*16 + ln15;
        const unsigned char* ap = smem + arow*384;
        const int aswz = (arow & 7) << 4;
        #pragma unroll
        for (int ks = 0; ks < 6; ks++){
          bf16x8 af = *(const bf16x8*)(ap + ((ks*64 + l16*16) ^ aswz));
          acc[mt] = MFMA16(af, bw[ks], acc[mt]);
        }
      }
      // scatter to q/k/vT
      const float bias = qkvb[colb + ln15];
      const int local = sub*16 + ln15;
      const int hl = local >> 5, d = local & 31;
      if (which == 2){
        unsigned char* vbase = smem + 49152 + hl*4096 + d*128;
        const int vswz = (d & 7) << 4;
        #pragma unroll
        for (int mt = 0; mt < 4; mt++){
          const int tk2 = (mt*16 + l16*4) * 2;
          *(unsigned int*)(vbase + ((tk2    ) ^ vswz)) = pack2(acc[mt][0] + bias, acc[mt][1] + bias);
          *(unsigned int*)(vbase + ((tk2 + 4) ^ vswz)) = pack2(acc[mt][2] + bias, acc[mt][3] + bias);
        }
      } else {
        unsigned char* qkb = smem + 32768 + hl*8192;
        const int koff = which ? 64 : 0;
        const float mul = which ? 1.f : scale;
        #pragma unroll
        for (int mt = 0; mt < 4; mt++)
          #pragma unroll
          for (int reg = 0; reg < 4; reg++){
            const int tok = mt*16 + l16*4 + reg;
            *(unsigned short*)(qkb + tok*128 + ((koff + d*2) ^ ((tok & 7) << 4))) =
                f2bf((acc[mt][reg] + bias) * mul);
          }
      }
    }
    __syncthreads();   // qkv ready

    // ---- attention: both heads (ps/ctx writes are wave-private rows) ----
    #pragma unroll 1
    for (int e = 0; e < 2; e++){
      const int h = h0 + e;
      const unsigned char* qkb = smem + 32768 + e*8192;
      const int arow = wv*16 + ln15;
      const int aswz = (arow & 7) << 4;
      bf16x8 aq = *(const bf16x8*)(qkb + arow*128 + ((l16*16) ^ aswz));
      f32x4 sacc[4];
      #pragma unroll
      for (int nt = 0; nt < 4; nt++){
        const int brow = nt*16 + ln15;
        bf16x8 bk = *(const bf16x8*)(qkb + brow*128 + ((64 + l16*16) ^ ((brow & 7) << 4)));
        sacc[nt] = MFMA16(aq, bk, zero4);
      }
      // bias + mask
      #pragma unroll
      for (int nt = 0; nt < 4; nt++){
        const int j_tok = nt*16 + ln15;
        const int rj = j_tok >> 3, cj = j_tok & 7;
        #pragma unroll
        for (int reg = 0; reg < 4; reg++){
          const int i_tok = wv*16 + l16*4 + reg;
          const int ri = i_tok >> 3, ci = i_tok & 7;
          float bias = rpb[((ri - rj + 7)*15 + (ci - cj + 7))*6 + h];
          sacc[nt][reg] += bias + ((regi[reg] == regj[nt]) ? 0.f : -100.f);
        }
      }
      // softmax across 16 lanes (cols) x 4 nt, per reg
      float mx[4], sum[4];
      #pragma unroll
      for (int reg = 0; reg < 4; reg++){
        float m = fmaxf(fmaxf(sacc[0][reg], sacc[1][reg]), fmaxf(sacc[2][reg], sacc[3][reg]));
        m = fmaxf(m, __shfl_xor(m, 1));
        m = fmaxf(m, __shfl_xor(m, 2));
        m = fmaxf(m, __shfl_xor(m, 4));
        m = fmaxf(m, __shfl_xor(m, 8));
        mx[reg] = m; sum[reg] = 0.f;
      }
      #pragma unroll
      for (int nt = 0; nt < 4; nt++)
        #pragma unroll
        for (int reg = 0; reg < 4; reg++){
          float ex = __expf(sacc[nt][reg] - mx[reg]);
          sacc[nt][reg] = ex;
          sum[reg] += ex;
        }
      #pragma unroll
      for (int reg = 0; reg < 4; reg++){
        float sm = sum[reg];
        sm += __shfl_xor(sm, 1);
        sm += __shfl_xor(sm, 2);
        sm += __shfl_xor(sm, 4);
        sm += __shfl_xor(sm, 8);
        sum[reg] = 1.f / sm;
      }
      // write P (own rows only)
      #pragma unroll
      for (int nt = 0; nt < 4; nt++)
        #pragma unroll
        for (int reg = 0; reg < 4; reg++){
          const int tok = wv*16 + l16*4 + reg;
          *(unsigned short*)(smem + 57344 + tok*128 + (((nt*16 + ln15)*2) ^ ((tok & 7) << 4))) =
              f2bf(sacc[nt][reg] * sum[reg]);
        }
      // PV (K=64 -> 2 ks; 2 d-tiles)
      f32x4 cacc[2] = {zero4, zero4};
      #pragma unroll
      for (int ks = 0; ks < 2; ks++){
        bf16x8 pa = *(const bf16x8*)(smem + 57344 + arow*128 + ((ks*64 + l16*16) ^ aswz));
        #pragma unroll
        for (int nt2 = 0; nt2 < 2; nt2++){
          const int drow = nt2*16 + ln15;
          bf16x8 bv = *(const bf16x8*)(smem + 49152 + e*4096 + drow*128 +
                                       ((ks*64 + l16*16) ^ ((drow & 7) << 4)));
          cacc[nt2] = MFMA16(pa, bv, cacc[nt2]);
        }
      }
      // ctx (own rows, this head's 32 cols of the pair's 64)
      #pragma unroll
      for (int nt2 = 0; nt2 < 2; nt2++)
        #pragma unroll
        for (int reg = 0; reg < 4; reg++){
          const int tok = wv*16 + l16*4 + reg;
          const int col = e*32 + nt2*16 + ln15;
          *(unsigned short*)(smem + 24576 + tok*128 + ((col*2) ^ ((tok & 7) << 4))) =
              f2bf(cacc[nt2][reg]);
        }
    }
    __syncthreads();   // ctx complete (all 64 rows, both heads)

    // ---- stream ctx pair-block to global: 32B/thread, coalesced ----
    {
      const int tok = tid >> 2, part = tid & 3;
      const int s = (tok & 7) << 4;
      bf16x8 v0 = *(const bf16x8*)(smem + 24576 + tok*128 + ((part*32     ) ^ s));
      bf16x8 v1 = *(const bf16x8*)(smem + 24576 + tok*128 + ((part*32 + 16) ^ s));
      unsigned short* dst = ctxg + (size_t)(blk*64 + tok)*192 + hp*64 + part*16;
      *(bf16x8*)(dst    ) = v0;
      *(bf16x8*)(dst + 8) = v1;
    }
    // no barrier needed: next pair's qkv writes qkp/vT (disjoint from ctx),
    // and its post-qkv barrier orders the next ctx overwrite.
  }
}

// ================= SPLIT PATH kernel 2: proj GEMM + residual -> xb2 =================
// swapped-operand MFMA (verified in mlp r5): D[oc][tok]; ep staged as float4.
__launch_bounds__(256, 3)
__global__ void proj_kernel(const unsigned short* __restrict__ ctxg, const float* __restrict__ xb,
                            float* __restrict__ xb2,
                            const unsigned short* __restrict__ projB, const float* __restrict__ projb){
  // cstage [64 tok][384B] bf16 swz @0 (24576) | ep [64][768B] fp32 swz @0 alias
  __shared__ __align__(16) unsigned char smem[49152];

  const int tid = threadIdx.x;
  const int blk = blockIdx.x;
  const int b = blk >> 8, wloc = blk & 255, wh = wloc >> 4, ww = wloc & 15;
  const int lane = tid & 63, wv = tid >> 6;
  const int ln15 = lane & 15, l16 = lane >> 4;
  const f32x4 zero4 = {0.f, 0.f, 0.f, 0.f};

  const int t = tid >> 2, q4 = tid & 3;
  const int hswz = (t & 7) << 4;

  // ---- stage ctx rows into LDS (coalesced 16B granules) ----
  {
    const unsigned short* crow = ctxg + (size_t)(blk*64 + t)*192;
    #pragma unroll
    for (int j = 0; j < 6; j++){
      bf16x8 v = *(const bf16x8*)(crow + q4*48 + j*8);
      *(bf16x8*)(smem + t*384 + ((q4*96 + j*16) ^ hswz)) = v;
    }
  }
  __syncthreads();

  // ---- proj: out[oc][tok], oc tiles 3/wave, K=192 (6 chunks) ----
  f32x4 acc[4][3];
  #pragma unroll
  for (int mt = 0; mt < 4; mt++)
    #pragma unroll
    for (int nt = 0; nt < 3; nt++)
      acc[mt][nt] = zero4;

  #pragma unroll 1
  for (int ks = 0; ks < 6; ks++){
    bf16x8 bw3[3];
    #pragma unroll
    for (int nt3 = 0; nt3 < 3; nt3++)
      bw3[nt3] = *(const bf16x8*)(projB + (size_t)(wv*48 + nt3*16 + ln15)*192 + ks*32 + l16*8);
    #pragma unroll
    for (int mt = 0; mt < 4; mt++){
      const int brow = mt*16 + ln15;
      bf16x8 cf = *(const bf16x8*)(smem + brow*384 + ((ks*64 + l16*16) ^ ((brow & 7) << 4)));
      #pragma unroll
      for (int nt3 = 0; nt3 < 3; nt3++)
        acc[mt][nt3] = MFMA16(bw3[nt3], cf, acc[mt][nt3]);
    }
  }
  __syncthreads();   // cstage dead; reuse as ep

  // ---- ep staging: float4 (thread holds 4 consecutive oc per token) ----
  #pragma unroll
  for (int mt = 0; mt < 4; mt++){
    const int tok = mt*16 + ln15;
    const int tswz = (tok & 7) << 4;
    unsigned char* rp = smem + tok*768;
    #pragma unroll
    for (int nt3 = 0; nt3 < 3; nt3++)
      *(f32x4*)(rp + ((wv*192 + nt3*64 + l16*16) ^ tswz)) = acc[mt][nt3];
  }
  __syncthreads();

  // ---- coalesced read-modify-write: xb2 = xb + proj + projb ----
  #pragma unroll
  for (int i = 0; i < 12; i++){
    const int id = i*256 + tid;
    const int tok = id / 48, c4 = id - tok*48;
    const int trr = tok >> 3, tcc = tok & 7;
    const int shh = (wh*8 + trr + 4) & 127, sww = (ww*8 + tcc + 4) & 127;
    const size_t goff = ((size_t)((((b << 7) + shh) << 7) + sww)) * 192 + c4*4;
    float4 pv  = *(const float4*)(smem + tok*768 + ((c4*16) ^ ((tok & 7) << 4)));
    float4 xr  = *(const float4*)(xb + goff);
    float4 pb4 = *(const float4*)(projb + c4*4);
    float4 o;
    o.x = xr.x + pv.x + pb4.x;
    o.y = xr.y + pv.y + pb4.y;
    o.z = xr.z + pv.z + pb4.z;
    o.w = xr.w + pv.w + pb4.w;
    *(float4*)(xb2 + goff) = o;
  }
}

// ---------------- FALLBACK: fused window attention (r5, passing) ----------------
__launch_bounds__(256, 3)
__global__ void attn_kernel(const float* __restrict__ xb, float* __restrict__ xb2,
                            const float* __restrict__ ln1w, const float* __restrict__ ln1b,
                            const unsigned short* __restrict__ qkvB, const float* __restrict__ qkvb,
                            const unsigned short* __restrict__ projB, const float* __restrict__ projb,
                            const float* __restrict__ rpb){
  __shared__ __align__(16) unsigned char smem[49408];
  int* regions = (int*)(smem + 49152);

  const int tid = threadIdx.x;
  const int blk = blockIdx.x;
  const int b = blk >> 8, wloc = blk & 255, wh = wloc >> 4, ww = wloc & 15;
  const int lane = tid & 63, wv = tid >> 6;
  const int ln15 = lane & 15, l16 = lane >> 4;
  const f32x4 zero4 = {0.f, 0.f, 0.f, 0.f};

  const int t = tid >> 2, q4 = tid & 3, c0 = q4 * 48;
  const int tr = t >> 3, tc = t & 7;
  const int sh = (wh*8 + tr + 4) & 127, sw = (ww*8 + tc + 4) & 127;
  const float* xrow = xb + (size_t)((((b << 7) + sh) << 7) + sw) * 192;
  float lnm, lnr;
  const int hswz = (t & 7) << 4;

  {
    float4 xt[12];
    float s = 0.f, s2 = 0.f;
    #pragma unroll
    for (int i = 0; i < 12; i++){
      xt[i] = *(const float4*)(xrow + c0 + i*4);
      s  += xt[i].x + xt[i].y + xt[i].z + xt[i].w;
      s2 += xt[i].x*xt[i].x + xt[i].y*xt[i].y + xt[i].z*xt[i].z + xt[i].w*xt[i].w;
    }
    s  += __shfl_xor(s, 1);  s  += __shfl_xor(s, 2);
    s2 += __shfl_xor(s2, 1); s2 += __shfl_xor(s2, 2);
    lnm = s * (1.f/192.f);
    lnr = rsqrtf(s2 * (1.f/192.f) - lnm*lnm + 1e-5f);
    #pragma unroll
    for (int i = 0; i < 12; i++){
      int cb = c0 + i*4;
      float4 w4 = *(const float4*)(ln1w + cb);
      float4 b4 = *(const float4*)(ln1b + cb);
      uint2 u;
      u.x = pack2((xt[i].x - lnm)*lnr*w4.x + b4.x, (xt[i].y - lnm)*lnr*w4.y + b4.y);
      u.y = pack2((xt[i].z - lnm)*lnr*w4.z + b4.z, (xt[i].w - lnm)*lnr*w4.w + b4.w);
      *(uint2*)(smem + t*384 + ((cb*2) ^ hswz)) = u;
    }
    if (q4 == 0){
      int gh = wh*8 + tr, gw = ww*8 + tc;
      regions[t] = (gh < 120 ? 0 : (gh < 124 ? 1 : 2)) * 3 + (gw < 120 ? 0 : (gw < 124 ? 1 : 2));
    }
  }
  __syncthreads();

  f32x4 pacc[4][3];
  #pragma unroll
  for (int mt = 0; mt < 4; mt++)
    #pragma unroll
    for (int nt = 0; nt < 3; nt++)
      pacc[mt][nt] = zero4;

  const float scale = 0.17677669529663687f;

  #pragma unroll 1
  for (int hp = 0; hp < 3; hp++){
    const int h0 = hp * 2;
    if (hp){
      __syncthreads();
      #pragma unroll 2
      for (int i = 0; i < 12; i++){
        int cb = c0 + i*4;
        float4 xi = *(const float4*)(xrow + cb);
        float4 w4 = *(const float4*)(ln1w + cb);
        float4 b4 = *(const float4*)(ln1b + cb);
        uint2 u;
        u.x = pack2((xi.x - lnm)*lnr*w4.x + b4.x, (xi.y - lnm)*lnr*w4.y + b4.y);
        u.y = pack2((xi.z - lnm)*lnr*w4.z + b4.z, (xi.w - lnm)*lnr*w4.w + b4.w);
        *(uint2*)(smem + t*384 + ((cb*2) ^ hswz)) = u;
      }
      __syncthreads();
    }

    #pragma unroll 1
    for (int tt0 = 0; tt0 < 3; tt0++){
      const int tt = wv*3 + tt0;
      const int which = tt >> 2, sub = tt & 3;
      const int colb = which*192 + h0*32 + sub*16;
      const unsigned short* bp = qkvB + (size_t)(colb + ln15)*192 + l16*8;
      bf16x8 bw[6];
      #pragma unroll
      for (int ks = 0; ks < 6; ks++) bw[ks] = *(const bf16x8*)(bp + ks*32);
      f32x4 acc[4];
      #pragma unroll
      for (int mt = 0; mt < 4; mt++){
        acc[mt] = zero4;
        const int arow = mt*16 + ln15;
        const unsigned char* ap = smem + arow*384;
        const int aswz = (arow & 7) << 4;
        #pragma unroll
        for (int ks = 0; ks < 6; ks++){
          bf16x8 af = *(const bf16x8*)(ap + ((ks*64 + l16*16) ^ aswz));
          acc[mt] = MFMA16(af, bw[ks], acc[mt]);
        }
      }
      const float bias = qkvb[colb + ln15];
      const int local = sub*16 + ln15;
      const int hl = local >> 5, d = local & 31;
      if (which == 2){
        unsigned char* vbase = smem + 40960 + hl*4096 + d*128;
        const int vswz = (d & 7) << 4;
        #pragma unroll
        for (int mt = 0; mt < 4; mt++){
          const int tk2 = (mt*16 + l16*4) * 2;
          *(unsigned int*)(vbase + ((tk2    ) ^ vswz)) = pack2(acc[mt][0] + bias, acc[mt][1] + bias);
          *(unsigned int*)(vbase + ((tk2 + 4) ^ vswz)) = pack2(acc[mt][2] + bias, acc[mt][3] + bias);
        }
      } else {
        unsigned char* qkb = smem + 24576 + hl*8192;
        const int koff = which ? 64 : 0;
        const float mul = which ? 1.f : scale;
        #pragma unroll
        for (int mt = 0; mt < 4; mt++)
          #pragma unroll
          for (int reg = 0; reg < 4; reg++){
            const int tok = mt*16 + l16*4 + reg;
            *(unsigned short*)(qkb + tok*128 + ((koff + d*2) ^ ((tok & 7) << 4))) =
                f2bf((acc[mt][reg] + bias) * mul);
          }
      }
    }
    __syncthreads();

    #pragma unroll 1
    for (int e = 0; e < 2; e++){
      const int h = h0 + e;
      const unsigned char* qkb = smem + 24576 + e*8192;
      const int arow = wv*16 + ln15;
      const int aswz = (arow & 7) << 4;
      bf16x8 aq = *(const bf16x8*)(qkb + arow*128 + ((l16*16) ^ aswz));
      f32x4 sacc[4];
      #pragma unroll
      for (int nt = 0; nt < 4; nt++){
        const int brow = nt*16 + ln15;
        bf16x8 bk = *(const bf16x8*)(qkb + brow*128 + ((64 + l16*16) ^ ((brow & 7) << 4)));
        sacc[nt] = MFMA16(aq, bk, zero4);
      }
      #pragma unroll
      for (int nt = 0; nt < 4; nt++){
        const int j_tok = nt*16 + ln15;
        const int rj = j_tok >> 3, cj = j_tok & 7;
        const int regj = regions[j_tok];
        #pragma unroll
        for (int reg = 0; reg < 4; reg++){
          const int i_tok = wv*16 + l16*4 + reg;
          const int ri = i_tok >> 3, ci = i_tok & 7;
          float bias = rpb[((ri - rj + 7)*15 + (ci - cj + 7))*6 + h];
          sacc[nt][reg] += bias + ((regions[i_tok] == regj) ? 0.f : -100.f);
        }
      }
      float mx[4], sum[4];
      #pragma unroll
      for (int reg = 0; reg < 4; reg++){
        float m = fmaxf(fmaxf(sacc[0][reg], sacc[1][reg]), fmaxf(sacc[2][reg], sacc[3][reg]));
        m = fmaxf(m, __shfl_xor(m, 1));
        m = fmaxf(m, __shfl_xor(m, 2));
        m = fmaxf(m, __shfl_xor(m, 4));
        m = fmaxf(m, __shfl_xor(m, 8));
        mx[reg] = m; sum[reg] = 0.f;
      }
      #pragma unroll
      for (int nt = 0; nt < 4; nt++)
        #pragma unroll
        for (int reg = 0; reg < 4; reg++){
          float ex = __expf(sacc[nt][reg] - mx[reg]);
          sacc[nt][reg] = ex;
          sum[reg] += ex;
        }
      #pragma unroll
      for (int reg = 0; reg < 4; reg++){
        float sm = sum[reg];
        sm += __shfl_xor(sm, 1);
        sm += __shfl_xor(sm, 2);
        sm += __shfl_xor(sm, 4);
        sm += __shfl_xor(sm, 8);
        sum[reg] = 1.f / sm;
      }
      #pragma unroll
      for (int nt = 0; nt < 4; nt++)
        #pragma unroll
        for (int reg = 0; reg < 4; reg++){
          const int tok = wv*16 + l16*4 + reg;
          *(unsigned short*)(smem + tok*128 + (((nt*16 + ln15)*2) ^ ((tok & 7) << 4))) =
              f2bf(sacc[nt][reg] * sum[reg]);
        }
      f32x4 cacc[2] = {zero4, zero4};
      #pragma unroll
      for (int ks = 0; ks < 2; ks++){
        bf16x8 pa = *(const bf16x8*)(smem + arow*128 + ((ks*64 + l16*16) ^ aswz));
        #pragma unroll
        for (int nt2 = 0; nt2 < 2; nt2++){
          const int drow = nt2*16 + ln15;
          bf16x8 bv = *(const bf16x8*)(smem + 40960 + e*4096 + drow*128 +
                                       ((ks*64 + l16*16) ^ ((drow & 7) << 4)));
          cacc[nt2] = MFMA16(pa, bv, cacc[nt2]);
        }
      }
      #pragma unroll
      for (int nt2 = 0; nt2 < 2; nt2++)
        #pragma unroll
        for (int reg = 0; reg < 4; reg++){
          const int tok = wv*16 + l16*4 + reg;
          const int col = e*32 + nt2*16 + ln15;
          *(unsigned short*)(smem + 8192 + tok*128 + ((col*2) ^ ((tok & 7) << 4))) =
              f2bf(cacc[nt2][reg]);
        }
    }
    __syncthreads();

    #pragma unroll
    for (int ks = 0; ks < 2; ks++){
      bf16x8 bw3[3];
      #pragma unroll
      for (int nt3 = 0; nt3 < 3; nt3++)
        bw3[nt3] = *(const bf16x8*)(projB + (size_t)(wv*48 + nt3*16 + ln15)*192 + h0*32 + ks*32 + l16*8);
      #pragma unroll
      for (int mt = 0; mt < 4; mt++){
        const int crow = mt*16 + ln15;
        bf16x8 ac = *(const bf16x8*)(smem + 8192 + crow*128 + ((ks*64 + l16*16) ^ ((crow & 7) << 4)));
        #pragma unroll
        for (int nt3 = 0; nt3 < 3; nt3++)
          pacc[mt][nt3] = MFMA16(ac, bw3[nt3], pacc[mt][nt3]);
      }
    }
  }
  __syncthreads();

  #pragma unroll
  for (int nt3 = 0; nt3 < 3; nt3++){
    const int col4 = (wv*48 + nt3*16 + ln15) * 4;
    #pragma unroll
    for (int mt = 0; mt < 4; mt++)
      #pragma unroll
      for (int reg = 0; reg < 4; reg++){
        const int row = mt*16 + l16*4 + reg;
        *(float*)(smem + row*768 + (col4 ^ ((row & 7) << 4))) = pacc[mt][nt3][reg];
      }
  }
  __syncthreads();
  {
    #pragma unroll
    for (int i = 0; i < 12; i++){
      const int id = i*256 + tid;
      const int tok = id / 48, c4 = id - tok*48;
      const int trr = tok >> 3, tcc = tok & 7;
      const int shh = (wh*8 + trr + 4) & 127, sww = (ww*8 + tcc + 4) & 127;
      const size_t goff = ((size_t)((((b << 7) + shh) << 7) + sww)) * 192 + c4*4;
      float4 pv  = *(const float4*)(smem + tok*768 + ((c4*16) ^ ((tok & 7) << 4)));
      float4 xr  = *(const float4*)(xb + goff);
      float4 pb4 = *(const float4*)(projb + c4*4);
      float4 o;
      o.x = xr.x + pv.x + pb4.x;
      o.y = xr.y + pv.y + pb4.y;
      o.z = xr.z + pv.z + pb4.z;
      o.w = xr.w + pv.w + pb4.w;
      *(float4*)(xb2 + goff) = o;
    }
  }
}

// ---------------- fused MLP (unchanged from r5) ----------------
__launch_bounds__(256, 3)
__global__ void mlp_kernel(const float* __restrict__ xb, float* __restrict__ xb2,
                           const float* __restrict__ ln2w, const float* __restrict__ ln2b,
                           const unsigned short* __restrict__ fc1B, const float* __restrict__ fc1b,
                           const unsigned short* __restrict__ fc2B, const float* __restrict__ fc2b,
                           float* __restrict__ outp, const int fuse){
  __shared__ __align__(16) unsigned char smem[49152];

  const int tid = threadIdx.x;
  const int lane = tid & 63, wv = tid >> 6;
  const int ln15 = lane & 15, l16 = lane >> 4;
  const size_t p0 = (size_t)blockIdx.x * 64;
  const f32x4 zero4 = {0.f, 0.f, 0.f, 0.f};

  const int t = tid >> 2, q4 = tid & 3, c0 = q4 * 48;
  const int hswz = (t & 7) << 4;
  const float* xrow2 = xb2 + (p0 + t)*192;

  {
    float4 xt[12];
    float s = 0.f, s2 = 0.f;
    #pragma unroll
    for (int i = 0; i < 12; i++){
      xt[i] = *(const float4*)(xrow2 + c0 + i*4);
      s  += xt[i].x + xt[i].y + xt[i].z + xt[i].w;
      s2 += xt[i].x*xt[i].x + xt[i].y*xt[i].y + xt[i].z*xt[i].z + xt[i].w*xt[i].w;
    }
    s  += __shfl_xor(s, 1);  s  += __shfl_xor(s, 2);
    s2 += __shfl_xor(s2, 1); s2 += __shfl_xor(s2, 2);
    const float mean = s * (1.f/192.f);
    const float rstd = rsqrtf(s2 * (1.f/192.f) - mean*mean + 1e-5f);
    #pragma unroll
    for (int i = 0; i < 12; i++){
      int cb = c0 + i*4;
      float4 w4 = *(const float4*)(ln2w + cb);
      float4 b4 = *(const float4*)(ln2b + cb);
      uint2 u;
      u.x = pack2((xt[i].x - mean)*rstd*w4.x + b4.x, (xt[i].y - mean)*rstd*w4.y + b4.y);
      u.y = pack2((xt[i].z - mean)*rstd*w4.z + b4.z, (xt[i].w - mean)*rstd*w4.w + b4.w);
      *(uint2*)(smem + t*384 + ((cb*2) ^ hswz)) = u;
    }
  }
  __syncthreads();

  f32x4 o2[4][3];
  #pragma unroll
  for (int mt = 0; mt < 4; mt++)
    #pragma unroll
    for (int nt = 0; nt < 3; nt++)
      o2[mt][nt] = zero4;

  {
    const unsigned short* bp1 = fc1B + (size_t)(wv*16 + ln15)*192 + l16*8;
    bf16x8 w1[6];
    #pragma unroll
    for (int ks = 0; ks < 6; ks++) w1[ks] = *(const bf16x8*)(bp1 + ks*32);
    const float4 b1 = *(const float4*)(fc1b + wv*16 + l16*4);
    unsigned char* hb = smem + 24576;
    #pragma unroll
    for (int mt = 0; mt < 4; mt++){
      f32x4 facc = zero4;
      const int arow = mt*16 + ln15;
      const unsigned char* ap = smem + arow*384;
      const int aswz = (arow & 7) << 4;
      #pragma unroll
      for (int ks = 0; ks < 6; ks++){
        bf16x8 af = *(const bf16x8*)(ap + ((ks*64 + l16*16) ^ aswz));
        facc = MFMA16(w1[ks], af, facc);
      }
      s16x4 hv;
      hv.x = (short)f2bf(gelu_f(facc[0] + b1.x));
      hv.y = (short)f2bf(gelu_f(facc[1] + b1.y));
      hv.z = (short)f2bf(gelu_f(facc[2] + b1.z));
      hv.w = (short)f2bf(gelu_f(facc[3] + b1.w));
      *(s16x4*)(hb + arow*128 + ((wv*32 + l16*8) ^ aswz)) = hv;
    }
  }
  __syncthreads();

  #pragma unroll 1
  for (int ch = 1; ch < 12; ch++){
    bf16x8 w2[3][2];
    #pragma unroll
    for (int nt3 = 0; nt3 < 3; nt3++)
      #pragma unroll
      for (int ks = 0; ks < 2; ks++)
        w2[nt3][ks] = *(const bf16x8*)(fc2B + (size_t)(wv*48 + nt3*16 + ln15)*768 +
                                       (ch-1)*64 + ks*32 + l16*8);
    const unsigned short* bp1 = fc1B + (size_t)(ch*64 + wv*16 + ln15)*192 + l16*8;
    bf16x8 w1[6];
    #pragma unroll
    for (int ks = 0; ks < 6; ks++) w1[ks] = *(const bf16x8*)(bp1 + ks*32);
    const float4 b1 = *(const float4*)(fc1b + ch*64 + wv*16 + l16*4);

    {
      const unsigned char* hb = smem + 24576 + ((ch-1)&1)*8192;
      #pragma unroll
      for (int mt = 0; mt < 4; mt++){
        const int brow = mt*16 + ln15;
        const unsigned char* bp = hb + brow*128;
        const int bswz = (brow & 7) << 4;
        #pragma unroll
        for (int ks = 0; ks < 2; ks++){
          bf16x8 hf = *(const bf16x8*)(bp + ((ks*64 + l16*16) ^ bswz));
          #pragma unroll
          for (int nt3 = 0; nt3 < 3; nt3++)
            o2[mt][nt3] = MFMA16(w2[nt3][ks], hf, o2[mt][nt3]);
        }
      }
    }
    {
      unsigned char* hb = smem + 24576 + (ch&1)*8192;
      #pragma unroll
      for (int mt = 0; mt < 4; mt++){
        f32x4 facc = zero4;
        const int arow = mt*16 + ln15;
        const unsigned char* ap = smem + arow*384;
        const int aswz = (arow & 7) << 4;
        #pragma unroll
        for (int ks = 0; ks < 6; ks++){
          bf16x8 af = *(const bf16x8*)(ap + ((ks*64 + l16*16) ^ aswz));
          facc = MFMA16(w1[ks], af, facc);
        }
        s16x4 hv;
        hv.x = (short)f2bf(gelu_f(facc[0] + b1.x));
        hv.y = (short)f2bf(gelu_f(facc[1] + b1.y));
        hv.z = (short)f2bf(gelu_f(facc[2] + b1.z));
        hv.w = (short)f2bf(gelu_f(facc[3] + b1.w));
        *(s16x4*)(hb + arow*128 + ((wv*32 + l16*8) ^ aswz)) = hv;
      }
    }
    __syncthreads();
  }

  {
    bf16x8 w2[3][2];
    #pragma unroll
    for (int nt3 = 0; nt3 < 3; nt3++)
      #pragma unroll
      for (int ks = 0; ks < 2; ks++)
        w2[nt3][ks] = *(const bf16x8*)(fc2B + (size_t)(wv*48 + nt3*16 + ln15)*768 +
                                       11*64 + ks*32 + l16*8);
    const unsigned char* hb = smem + 24576 + 8192;
    #pragma unroll
    for (int mt = 0; mt < 4; mt++){
      const int brow = mt*16 + ln15;
      const unsigned char* bp = hb + brow*128;
      const int bswz = (brow & 7) << 4;
      #pragma unroll
      for (int ks = 0; ks < 2; ks++){
        bf16x8 hf = *(const bf16x8*)(bp + ((ks*64 + l16*16) ^ bswz));
        #pragma unroll
        for (int nt3 = 0; nt3 < 3; nt3++)
          o2[mt][nt3] = MFMA16(w2[nt3][ks], hf, o2[mt][nt3]);
      }
    }
  }
  __syncthreads();

  #pragma unroll
  for (int mt = 0; mt < 4; mt++){
    const int tok = mt*16 + ln15;
    const int tswz = (tok & 7) << 4;
    unsigned char* rp = smem + tok*768;
    #pragma unroll
    for (int nt3 = 0; nt3 < 3; nt3++)
      *(f32x4*)(rp + ((wv*192 + nt3*64 + l16*16) ^ tswz)) = o2[mt][nt3];
  }
  __syncthreads();

  const float* xrow = xb + (p0 + t)*192;
  if (!fuse){
    float* orow = xb2 + (p0 + t)*192;
    #pragma unroll
    for (int i = 0; i < 12; i++){
      float4 mv  = *(const float4*)(smem + t*768 + ((c0*4 + i*16) ^ hswz));
      float4 x2  = *(const float4*)(xrow2 + c0 + i*4);
      float4 xr  = *(const float4*)(xrow + c0 + i*4);
      float4 fb4 = *(const float4*)(fc2b + c0 + i*4);
      float4 o;
      o.x = x2.x + xr.x + fb4.x + mv.x;
      o.y = x2.y + xr.y + fb4.y + mv.y;
      o.z = x2.z + xr.z + fb4.z + mv.z;
      o.w = x2.w + xr.w + fb4.w + mv.w;
      *(float4*)(orow + c0 + i*4) = o;
    }
  } else {
    #pragma unroll
    for (int i = 0; i < 12; i++){
      const int off = (c0*4 + i*16) ^ hswz;
      float4 mv  = *(const float4*)(smem + t*768 + off);
      float4 x2  = *(const float4*)(xrow2 + c0 + i*4);
      float4 xr  = *(const float4*)(xrow + c0 + i*4);
      float4 fb4 = *(const float4*)(fc2b + c0 + i*4);
      float4 o;
      o.x = fminf(fmaxf(x2.x + xr.x + fb4.x + mv.x, -10.f), 10.f);
      o.y = fminf(fmaxf(x2.y + xr.y + fb4.y + mv.y, -10.f), 10.f);
      o.z = fminf(fmaxf(x2.z + xr.z + fb4.z + mv.z, -10.f), 10.f);
      o.w = fminf(fmaxf(x2.w + xr.w + fb4.w + mv.w, -10.f), 10.f);
      *(float4*)(smem + t*768 + off) = o;
    }
    __syncthreads();
    const int bidx   = (int)(p0 >> 14);
    const int imgoff = (int)(p0 & 16383);
    #pragma unroll 1
    for (int i = 0; i < 12; i++){
      const int id = i*256 + tid;
      const int c = id >> 4, pq = id & 15;
      float4 o4;
      o4.x = *(const float*)(smem + (pq*4    )*768 + ((c*4) ^ (((pq*4    ) & 7) << 4)));
      o4.y = *(const float*)(smem + (pq*4 + 1)*768 + ((c*4) ^ (((pq*4 + 1) & 7) << 4)));
      o4.z = *(const float*)(smem + (pq*4 + 2)*768 + ((c*4) ^ (((pq*4 + 2) & 7) << 4)));
      o4.w = *(const float*)(smem + (pq*4 + 3)*768 + ((c*4) ^ (((pq*4 + 3) & 7) << 4)));
      *(float4*)(outp + (((size_t)(bidx*192 + c)) << 14) + imgoff + pq*4) = o4;
    }
  }
}

// ---------------- final NHWC -> NCHW + clamp (legacy path only) ----------------
__global__ void final_k(const float* __restrict__ xb2, float* __restrict__ out){
  __shared__ float tile[192*64];
  int blk = blockIdx.x, tid = threadIdx.x;
  int b = blk >> 8, p0 = (blk & 255) * 64;
  #pragma unroll 1
  for (int i = 0; i < 12; i++){
    int idx4 = i*256 + tid;
    int tt = idx4 / 48, c4 = idx4 - tt*48;
    int cb = c4 * 4;
    float4 v = *(const float4*)(xb2 + ((size_t)blk*64 + tt)*192 + cb);
    tile[(cb  )*64 + ((tt + cb    ) & 63)] = v.x;
    tile[(cb+1)*64 + ((tt + cb + 1) & 63)] = v.y;
    tile[(cb+2)*64 + ((tt + cb + 2) & 63)] = v.z;
    tile[(cb+3)*64 + ((tt + cb + 3) & 63)] = v.w;
  }
  __syncthreads();
  #pragma unroll 1
  for (int i = 0; i < 12; i++){
    int idx4 = i*256 + tid;
    int c = idx4 >> 4, pq = idx4 & 15;
    int pb_ = pq*4;
    float4 o;
    o.x = tile[c*64 + ((pb_     + c) & 63)];
    o.y = tile[c*64 + ((pb_ + 1 + c) & 63)];
    o.z = tile[c*64 + ((pb_ + 2 + c) & 63)];
    o.w = tile[c*64 + ((pb_ + 3 + c) & 63)];
    o.x = fminf(fmaxf(o.x, -10.f), 10.f);
    o.y = fminf(fmaxf(o.y, -10.f), 10.f);
    o.z = fminf(fmaxf(o.z, -10.f), 10.f);
    o.w = fminf(fmaxf(o.w, -10.f), 10.f);
    *(float4*)(out + (((size_t)b*192 + c) << 14) + p0 + pb_) = o;
  }
}

extern "C" void kernel_launch(void* const* d_in, const int* in_sizes, int n_in,
                              void* d_out, int out_size, void* d_ws, size_t ws_size,
                              hipStream_t stream){
  (void)in_sizes; (void)n_in; (void)out_size;
  const float* x     = (const float*)d_in[0];
  const float* gnw   = (const float*)d_in[1];
  const float* gnb   = (const float*)d_in[2];
  const float* ln1w  = (const float*)d_in[3];
  const float* ln1b  = (const float*)d_in[4];
  const float* qkvw  = (const float*)d_in[5];
  const float* qkvb  = (const float*)d_in[6];
  const float* projw = (const float*)d_in[7];
  const float* projb = (const float*)d_in[8];
  const float* rpb   = (const float*)d_in[9];
  const float* ln2w  = (const float*)d_in[10];
  const float* ln2b  = (const float*)d_in[11];
  const float* fc1w  = (const float*)d_in[12];
  const float* fc1b  = (const float*)d_in[13];
  const float* fc2w  = (const float*)d_in[14];
  const float* fc2b  = (const float*)d_in[15];
  float* out = (float*)d_out;

  float* ws    = (float*)d_ws;
  float* xb2   = ws;                       // [B,H,W,C] fp32 (100 MB)
  float* part  = xb2  + 25165824;
  float* stats = part + 3072;
  unsigned short* qkvB = (unsigned short*)(stats + 16);  // [576][192] bf16
  unsigned short* projB = qkvB + 110592;                 // [192][192]
  unsigned short* fc1B  = projB + 36864;                 // [768][192]
  unsigned short* fc2B  = fc1B + 147456;                 // [192][768]

  // mode 2: split attn (xb in ws, ctx bf16 in ws) ; mode 1: fused attn, mlp-fused final
  // mode 0: minimal (xb aliases out, final_k pass)
  const int mode = (ws_size >= 252555328ULL) ? 2 : ((ws_size >= 202223680ULL) ? 1 : 0);
  float* xb = (mode >= 1) ? (ws + 25390096) : out;
  unsigned short* ctxg = (unsigned short*)(ws + 50555920);   // 131072 x 192 bf16 (50 MB)

  transpose_cast_all<<<1728, 256, 0, stream>>>(qkvw, projw, fc1w, fc2w, qkvB, projB, fc1B, fc2B);
  gn_partial<<<1536, 256, 0, stream>>>(x, part);
  gn_final<<<8, 64, 0, stream>>>(part, stats);
  gn_apply<<<2048, 256, 0, stream>>>(x, stats, gnw, gnb, xb);
  if (mode == 2){
    attn_qkv_kernel<<<2048, 256, 0, stream>>>(xb, ctxg, ln1w, ln1b, qkvB, qkvb, rpb);
    proj_kernel<<<2048, 256, 0, stream>>>(ctxg, xb, xb2, projB, projb);
  } else {
    attn_kernel<<<2048, 256, 0, stream>>>(xb, xb2, ln1w, ln1b, qkvB, qkvb, projB, projb, rpb);
  }
  mlp_kernel<<<2048, 256, 0, stream>>>(xb, xb2, ln2w, ln2b, fc1B, fc1b, fc2B, fc2b, out, mode >= 1);
  if (mode == 0) final_k<<<2048, 256, 0, stream>>>(xb2, out);
}

// Round 7
// 665.655 us; speedup vs baseline: 1.6296x; 1.0076x over previous
//
#include <hip/hip_runtime.h>
#include <cstddef>

typedef __attribute__((ext_vector_type(8))) short bf16x8;
typedef __attribute__((ext_vector_type(4))) float f32x4;
typedef __attribute__((ext_vector_type(4))) short s16x4;

#define DEV __device__ __forceinline__
#define MFMA16(a,b,c) __builtin_amdgcn_mfma_f32_16x16x32_bf16((a),(b),(c),0,0,0)

DEV unsigned short f2bf(float f){
  unsigned int x = __float_as_uint(f);
  x += 0x7fffu + ((x >> 16) & 1u);
  return (unsigned short)(x >> 16);
}
DEV unsigned int pack2(float a, float b){
  return (unsigned int)f2bf(a) | ((unsigned int)f2bf(b) << 16);
}
// tanh-form GELU with raw v_rcp (|err vs erf-GELU| <= ~1e-3 abs; budget analysis r7:
// bf16 hid quantization already injects ~5x this into outputs; threshold 0.2, margin 3x+).
// Replaces full-precision divide sequence (~9 VALU slots) with 1 v_rcp_f32.
DEV float gelu_f(float x){
  float x2 = x*x;
  float y  = x*(0.7978845608028654f + 0.035677408136300125f*x2);
  float s  = __expf(-2.f*fabsf(y));
  float th = (1.f - s)*__builtin_amdgcn_rcpf(1.f + s);
  th = (y < 0.f) ? -th : th;
  return 0.5f*x*(1.f + th);
}

// ---------------- all weight transposes + bf16 cast in one launch ----------------
__global__ void transpose_cast_all(const float* __restrict__ qkvw, const float* __restrict__ projw,
                                   const float* __restrict__ fc1w, const float* __restrict__ fc2w,
                                   unsigned short* __restrict__ qkvB, unsigned short* __restrict__ projB,
                                   unsigned short* __restrict__ fc1B, unsigned short* __restrict__ fc2B){
  int blk = blockIdx.x;
  const float* in; unsigned short* outp; int K, N, idx;
  if (blk < 432){        in = qkvw; outp = qkvB; K = 192; N = 576; idx = blk*256 + threadIdx.x; }
  else if (blk < 576){   in = projw; outp = projB; K = 192; N = 192; idx = (blk-432)*256 + threadIdx.x; }
  else if (blk < 1152){  in = fc1w; outp = fc1B; K = 192; N = 768; idx = (blk-576)*256 + threadIdx.x; }
  else {                 in = fc2w; outp = fc2B; K = 768; N = 192; idx = (blk-1152)*256 + threadIdx.x; }
  if (idx < K * N){
    int n = idx / K, k = idx - n * K;
    outp[idx] = f2bf(in[k * N + n]);
  }
}

// ---------------- GroupNorm stage 1 ----------------
__global__ void gn_partial(const float* __restrict__ x, float* __restrict__ part){
  int bc = blockIdx.x, tid = threadIdx.x;
  const float4* p = (const float4*)(x + (size_t)bc * 16384);
  float s = 0.f, s2 = 0.f;
  for (int i = tid; i < 4096; i += 256){
    float4 v = p[i];
    s  += v.x + v.y + v.z + v.w;
    s2 += v.x*v.x + v.y*v.y + v.z*v.z + v.w*v.w;
  }
  #pragma unroll
  for (int off = 32; off; off >>= 1){ s += __shfl_down(s, off); s2 += __shfl_down(s2, off); }
  __shared__ float red[8];
  int wid = tid >> 6;
  if ((tid & 63) == 0){ red[wid*2] = s; red[wid*2+1] = s2; }
  __syncthreads();
  if (tid == 0){
    part[bc*2]   = red[0] + red[2] + red[4] + red[6];
    part[bc*2+1] = red[1] + red[3] + red[5] + red[7];
  }
}

// ---------------- GroupNorm stage 2 ----------------
__global__ void gn_final(const float* __restrict__ part, float* __restrict__ stats){
  int b = blockIdx.x, tid = threadIdx.x;
  float s = 0.f, s2 = 0.f;
  for (int c = tid; c < 192; c += 64){
    s  += part[(b*192 + c)*2];
    s2 += part[(b*192 + c)*2 + 1];
  }
  #pragma unroll
  for (int off = 32; off; off >>= 1){ s += __shfl_down(s, off); s2 += __shfl_down(s2, off); }
  if (tid == 0){
    const float inv = 1.f / (192.f * 16384.f);
    float mean = s * inv;
    float var  = s2 * inv - mean*mean;
    stats[b*2]   = mean;
    stats[b*2+1] = rsqrtf(var + 1e-5f);
  }
}

// ---------------- GN apply + NCHW -> NHWC ----------------
__global__ void gn_apply(const float* __restrict__ x, const float* __restrict__ stats,
                         const float* __restrict__ gnw, const float* __restrict__ gnb,
                         float* __restrict__ xb){
  __shared__ float tile[192*64];
  int blk = blockIdx.x, tid = threadIdx.x;
  int b = blk >> 8, p0 = (blk & 255) * 64;
  float mean = stats[b*2], rstd = stats[b*2+1];
  #pragma unroll 1
  for (int i = 0; i < 12; i++){
    int idx4 = i*256 + tid;
    int c = idx4 >> 4, pq = idx4 & 15;
    float4 v = *(const float4*)(x + (((size_t)b*192 + c) << 14) + p0 + pq*4);
    float w  = gnw[c] * rstd;
    float bb = gnb[c] - mean * rstd * gnw[c];
    int pb_ = pq*4;
    tile[c*64 + ((pb_     + c) & 63)] = v.x * w + bb;
    tile[c*64 + ((pb_ + 1 + c) & 63)] = v.y * w + bb;
    tile[c*64 + ((pb_ + 2 + c) & 63)] = v.z * w + bb;
    tile[c*64 + ((pb_ + 3 + c) & 63)] = v.w * w + bb;
  }
  __syncthreads();
  #pragma unroll 1
  for (int i = 0; i < 12; i++){
    int idx4 = i*256 + tid;
    int pix = idx4 / 48, c4 = idx4 - pix*48;
    int cb = c4 * 4;
    float4 o;
    o.x = tile[(cb  )*64 + ((pix + cb    ) & 63)];
    o.y = tile[(cb+1)*64 + ((pix + cb + 1) & 63)];
    o.z = tile[(cb+2)*64 + ((pix + cb + 2) & 63)];
    o.w = tile[(cb+3)*64 + ((pix + cb + 3) & 63)];
    *(float4*)(xb + ((size_t)blk*64 + pix)*192 + cb) = o;
  }
}

// ================= SPLIT PATH kernel 1: LN1 + qkv + window attention -> ctx ==========
__launch_bounds__(256, 2)
__global__ void attn_qkv_kernel(const float* __restrict__ xb, unsigned short* __restrict__ ctxg,
                                const float* __restrict__ ln1w, const float* __restrict__ ln1b,
                                const unsigned short* __restrict__ qkvB, const float* __restrict__ qkvb,
                                const float* __restrict__ rpb){
  __shared__ __align__(16) unsigned char smem[65536];

  const int tid = threadIdx.x;
  const int blk = blockIdx.x;
  const int b = blk >> 8, wloc = blk & 255, wh = wloc >> 4, ww = wloc & 15;
  const int lane = tid & 63, wv = tid >> 6;
  const int ln15 = lane & 15, l16 = lane >> 4;
  const f32x4 zero4 = {0.f, 0.f, 0.f, 0.f};

  const int t = tid >> 2, q4 = tid & 3, c0 = q4 * 48;
  const int tr = t >> 3, tc = t & 7;
  const int sh = (wh*8 + tr + 4) & 127, sw = (ww*8 + tc + 4) & 127;
  const float* xrow = xb + (size_t)((((b << 7) + sh) << 7) + sw) * 192;
  const int hswz = (t & 7) << 4;

  // ---- LN1 (thread t = token, q4 = channel quarter); xb read ONCE ----
  {
    float4 xt[12];
    float s = 0.f, s2 = 0.f;
    #pragma unroll
    for (int i = 0; i < 12; i++){
      xt[i] = *(const float4*)(xrow + c0 + i*4);
      s  += xt[i].x + xt[i].y + xt[i].z + xt[i].w;
      s2 += xt[i].x*xt[i].x + xt[i].y*xt[i].y + xt[i].z*xt[i].z + xt[i].w*xt[i].w;
    }
    s  += __shfl_xor(s, 1);  s  += __shfl_xor(s, 2);
    s2 += __shfl_xor(s2, 1); s2 += __shfl_xor(s2, 2);
    const float lnm = s * (1.f/192.f);
    const float lnr = rsqrtf(s2 * (1.f/192.f) - lnm*lnm + 1e-5f);
    #pragma unroll
    for (int i = 0; i < 12; i++){
      int cb = c0 + i*4;
      float4 w4 = *(const float4*)(ln1w + cb);
      float4 b4 = *(const float4*)(ln1b + cb);
      uint2 u;
      u.x = pack2((xt[i].x - lnm)*lnr*w4.x + b4.x, (xt[i].y - lnm)*lnr*w4.y + b4.y);
      u.y = pack2((xt[i].z - lnm)*lnr*w4.z + b4.z, (xt[i].w - lnm)*lnr*w4.w + b4.w);
      *(uint2*)(smem + t*384 + ((cb*2) ^ hswz)) = u;
    }
  }
  __syncthreads();

  const float scale = 0.17677669529663687f;

  // region ids for mask (computed inline; no LDS)
  int regi[4], regj[4];
  #pragma unroll
  for (int r = 0; r < 4; r++){
    int tok = wv*16 + l16*4 + r;
    int gh = wh*8 + (tok >> 3), gw = ww*8 + (tok & 7);
    regi[r] = (gh < 120 ? 0 : (gh < 124 ? 1 : 2)) * 3 + (gw < 120 ? 0 : (gw < 124 ? 1 : 2));
  }
  #pragma unroll
  for (int nt = 0; nt < 4; nt++){
    int tok = nt*16 + ln15;
    int gh = wh*8 + (tok >> 3), gw = ww*8 + (tok & 7);
    regj[nt] = (gh < 120 ? 0 : (gh < 124 ? 1 : 2)) * 3 + (gw < 120 ? 0 : (gw < 124 ? 1 : 2));
  }

  #pragma unroll 1
  for (int hp = 0; hp < 3; hp++){
    const int h0 = hp * 2;

    // ---- qkv for heads h0,h0+1 (12 col-tiles of 16; wave does 3) ----
    #pragma unroll 1
    for (int tt0 = 0; tt0 < 3; tt0++){
      const int tt = wv*3 + tt0;
      const int which = tt >> 2, sub = tt & 3;     // wave-uniform
      const int colb = which*192 + h0*32 + sub*16;
      const unsigned short* bp = qkvB + (size_t)(colb + ln15)*192 + l16*8;
      bf16x8 bw[6];
      #pragma unroll
      for (int ks = 0; ks < 6; ks++) bw[ks] = *(const bf16x8*)(bp + ks*32);
      f32x4 acc[4];
      #pragma unroll
      for (int mt = 0; mt < 4; mt++){
        acc[mt] = zero4;
        const int arow = mt*16 + ln15;
        const unsigned char* ap = smem + arow*384;
        const int aswz = (arow & 7) << 4;
        #pragma unroll
        for (int ks = 0; ks < 6; ks++){
          bf16x8 af = *(const bf16x8*)(ap + ((ks*64 + l16*16) ^ aswz));
          acc[mt] = MFMA16(af, bw[ks], acc[mt]);
        }
      }
      // scatter to q/k/vT
      const float bias = qkvb[colb + ln15];
      const int local = sub*16 + ln15;
      const int hl = local >> 5, d = local & 31;
      if (which == 2){
        unsigned char* vbase = smem + 49152 + hl*4096 + d*128;
        const int vswz = (d & 7) << 4;
        #pragma unroll
        for (int mt = 0; mt < 4; mt++){
          const int tk2 = (mt*16 + l16*4) * 2;
          *(unsigned int*)(vbase + ((tk2    ) ^ vswz)) = pack2(acc[mt][0] + bias, acc[mt][1] + bias);
          *(unsigned int*)(vbase + ((tk2 + 4) ^ vswz)) = pack2(acc[mt][2] + bias, acc[mt][3] + bias);
        }
      } else {
        unsigned char* qkb = smem + 32768 + hl*8192;
        const int koff = which ? 64 : 0;
        const float mul = which ? 1.f : scale;
        #pragma unroll
        for (int mt = 0; mt < 4; mt++)
          #pragma unroll
          for (int reg = 0; reg < 4; reg++){
            const int tok = mt*16 + l16*4 + reg;
            *(unsigned short*)(qkb + tok*128 + ((koff + d*2) ^ ((tok & 7) << 4))) =
                f2bf((acc[mt][reg] + bias) * mul);
          }
      }
    }
    __syncthreads();   // qkv ready

    // ---- attention: both heads (ps/ctx writes are wave-private rows) ----
    #pragma unroll 1
    for (int e = 0; e < 2; e++){
      const int h = h0 + e;
      const unsigned char* qkb = smem + 32768 + e*8192;
      const int arow = wv*16 + ln15;
      const int aswz = (arow & 7) << 4;
      bf16x8 aq = *(const bf16x8*)(qkb + arow*128 + ((l16*16) ^ aswz));
      f32x4 sacc[4];
      #pragma unroll
      for (int nt = 0; nt < 4; nt++){
        const int brow = nt*16 + ln15;
        bf16x8 bk = *(const bf16x8*)(qkb + brow*128 + ((64 + l16*16) ^ ((brow & 7) << 4)));
        sacc[nt] = MFMA16(aq, bk, zero4);
      }
      // bias + mask
      #pragma unroll
      for (int nt = 0; nt < 4; nt++){
        const int j_tok = nt*16 + ln15;
        const int rj = j_tok >> 3, cj = j_tok & 7;
        #pragma unroll
        for (int reg = 0; reg < 4; reg++){
          const int i_tok = wv*16 + l16*4 + reg;
          const int ri = i_tok >> 3, ci = i_tok & 7;
          float bias = rpb[((ri - rj + 7)*15 + (ci - cj + 7))*6 + h];
          sacc[nt][reg] += bias + ((regi[reg] == regj[nt]) ? 0.f : -100.f);
        }
      }
      // softmax across 16 lanes (cols) x 4 nt, per reg
      float mx[4], sum[4];
      #pragma unroll
      for (int reg = 0; reg < 4; reg++){
        float m = fmaxf(fmaxf(sacc[0][reg], sacc[1][reg]), fmaxf(sacc[2][reg], sacc[3][reg]));
        m = fmaxf(m, __shfl_xor(m, 1));
        m = fmaxf(m, __shfl_xor(m, 2));
        m = fmaxf(m, __shfl_xor(m, 4));
        m = fmaxf(m, __shfl_xor(m, 8));
        mx[reg] = m; sum[reg] = 0.f;
      }
      #pragma unroll
      for (int nt = 0; nt < 4; nt++)
        #pragma unroll
        for (int reg = 0; reg < 4; reg++){
          float ex = __expf(sacc[nt][reg] - mx[reg]);
          sacc[nt][reg] = ex;
          sum[reg] += ex;
        }
      #pragma unroll
      for (int reg = 0; reg < 4; reg++){
        float sm = sum[reg];
        sm += __shfl_xor(sm, 1);
        sm += __shfl_xor(sm, 2);
        sm += __shfl_xor(sm, 4);
        sm += __shfl_xor(sm, 8);
        sum[reg] = __builtin_amdgcn_rcpf(sm);   // v_rcp_f32 (rel err ~1e-7)
      }
      // write P (own rows only)
      #pragma unroll
      for (int nt = 0; nt < 4; nt++)
        #pragma unroll
        for (int reg = 0; reg < 4; reg++){
          const int tok = wv*16 + l16*4 + reg;
          *(unsigned short*)(smem + 57344 + tok*128 + (((nt*16 + ln15)*2) ^ ((tok & 7) << 4))) =
              f2bf(sacc[nt][reg] * sum[reg]);
        }
      // PV (K=64 -> 2 ks; 2 d-tiles)
      f32x4 cacc[2] = {zero4, zero4};
      #pragma unroll
      for (int ks = 0; ks < 2; ks++){
        bf16x8 pa = *(const bf16x8*)(smem + 57344 + arow*128 + ((ks*64 + l16*16) ^ aswz));
        #pragma unroll
        for (int nt2 = 0; nt2 < 2; nt2++){
          const int drow = nt2*16 + ln15;
          bf16x8 bv = *(const bf16x8*)(smem + 49152 + e*4096 + drow*128 +
                                       ((ks*64 + l16*16) ^ ((drow & 7) << 4)));
          cacc[nt2] = MFMA16(pa, bv, cacc[nt2]);
        }
      }
      // ctx (own rows, this head's 32 cols of the pair's 64)
      #pragma unroll
      for (int nt2 = 0; nt2 < 2; nt2++)
        #pragma unroll
        for (int reg = 0; reg < 4; reg++){
          const int tok = wv*16 + l16*4 + reg;
          const int col = e*32 + nt2*16 + ln15;
          *(unsigned short*)(smem + 24576 + tok*128 + ((col*2) ^ ((tok & 7) << 4))) =
              f2bf(cacc[nt2][reg]);
        }
    }
    __syncthreads();   // ctx complete (all 64 rows, both heads)

    // ---- stream ctx pair-block to global: 32B/thread, coalesced ----
    {
      const int tok = tid >> 2, part = tid & 3;
      const int s = (tok & 7) << 4;
      bf16x8 v0 = *(const bf16x8*)(smem + 24576 + tok*128 + ((part*32     ) ^ s));
      bf16x8 v1 = *(const bf16x8*)(smem + 24576 + tok*128 + ((part*32 + 16) ^ s));
      unsigned short* dst = ctxg + (size_t)(blk*64 + tok)*192 + hp*64 + part*16;
      *(bf16x8*)(dst    ) = v0;
      *(bf16x8*)(dst + 8) = v1;
    }
  }
}

// ================= SPLIT PATH kernel 2: proj GEMM + residual -> xb2 =================
__launch_bounds__(256, 3)
__global__ void proj_kernel(const unsigned short* __restrict__ ctxg, const float* __restrict__ xb,
                            float* __restrict__ xb2,
                            const unsigned short* __restrict__ projB, const float* __restrict__ projb){
  __shared__ __align__(16) unsigned char smem[49152];

  const int tid = threadIdx.x;
  const int blk = blockIdx.x;
  const int b = blk >> 8, wloc = blk & 255, wh = wloc >> 4, ww = wloc & 15;
  const int lane = tid & 63, wv = tid >> 6;
  const int ln15 = lane & 15, l16 = lane >> 4;
  const f32x4 zero4 = {0.f, 0.f, 0.f, 0.f};

  const int t = tid >> 2, q4 = tid & 3;
  const int hswz = (t & 7) << 4;

  // ---- stage ctx rows into LDS (coalesced 16B granules) ----
  {
    const unsigned short* crow = ctxg + (size_t)(blk*64 + t)*192;
    #pragma unroll
    for (int j = 0; j < 6; j++){
      bf16x8 v = *(const bf16x8*)(crow + q4*48 + j*8);
      *(bf16x8*)(smem + t*384 + ((q4*96 + j*16) ^ hswz)) = v;
    }
  }
  __syncthreads();

  // ---- proj: out[oc][tok], oc tiles 3/wave, K=192 (6 chunks) ----
  f32x4 acc[4][3];
  #pragma unroll
  for (int mt = 0; mt < 4; mt++)
    #pragma unroll
    for (int nt = 0; nt < 3; nt++)
      acc[mt][nt] = zero4;

  #pragma unroll 1
  for (int ks = 0; ks < 6; ks++){
    bf16x8 bw3[3];
    #pragma unroll
    for (int nt3 = 0; nt3 < 3; nt3++)
      bw3[nt3] = *(const bf16x8*)(projB + (size_t)(wv*48 + nt3*16 + ln15)*192 + ks*32 + l16*8);
    #pragma unroll
    for (int mt = 0; mt < 4; mt++){
      const int brow = mt*16 + ln15;
      bf16x8 cf = *(const bf16x8*)(smem + brow*384 + ((ks*64 + l16*16) ^ ((brow & 7) << 4)));
      #pragma unroll
      for (int nt3 = 0; nt3 < 3; nt3++)
        acc[mt][nt3] = MFMA16(bw3[nt3], cf, acc[mt][nt3]);
    }
  }
  __syncthreads();   // cstage dead; reuse as ep

  // ---- ep staging: float4 (thread holds 4 consecutive oc per token) ----
  #pragma unroll
  for (int mt = 0; mt < 4; mt++){
    const int tok = mt*16 + ln15;
    const int tswz = (tok & 7) << 4;
    unsigned char* rp = smem + tok*768;
    #pragma unroll
    for (int nt3 = 0; nt3 < 3; nt3++)
      *(f32x4*)(rp + ((wv*192 + nt3*64 + l16*16) ^ tswz)) = acc[mt][nt3];
  }
  __syncthreads();

  // ---- coalesced read-modify-write: xb2 = xb + proj + projb ----
  #pragma unroll
  for (int i = 0; i < 12; i++){
    const int id = i*256 + tid;
    const int tok = id / 48, c4 = id - tok*48;
    const int trr = tok >> 3, tcc = tok & 7;
    const int shh = (wh*8 + trr + 4) & 127, sww = (ww*8 + tcc + 4) & 127;
    const size_t goff = ((size_t)((((b << 7) + shh) << 7) + sww)) * 192 + c4*4;
    float4 pv  = *(const float4*)(smem + tok*768 + ((c4*16) ^ ((tok & 7) << 4)));
    float4 xr  = *(const float4*)(xb + goff);
    float4 pb4 = *(const float4*)(projb + c4*4);
    float4 o;
    o.x = xr.x + pv.x + pb4.x;
    o.y = xr.y + pv.y + pb4.y;
    o.z = xr.z + pv.z + pb4.z;
    o.w = xr.w + pv.w + pb4.w;
    *(float4*)(xb2 + goff) = o;
  }
}

// ---------------- FALLBACK: fused window attention (r5, passing) ----------------
__launch_bounds__(256, 3)
__global__ void attn_kernel(const float* __restrict__ xb, float* __restrict__ xb2,
                            const float* __restrict__ ln1w, const float* __restrict__ ln1b,
                            const unsigned short* __restrict__ qkvB, const float* __restrict__ qkvb,
                            const unsigned short* __restrict__ projB, const float* __restrict__ projb,
                            const float* __restrict__ rpb){
  __shared__ __align__(16) unsigned char smem[49408];
  int* regions = (int*)(smem + 49152);

  const int tid = threadIdx.x;
  const int blk = blockIdx.x;
  const int b = blk >> 8, wloc = blk & 255, wh = wloc >> 4, ww = wloc & 15;
  const int lane = tid & 63, wv = tid >> 6;
  const int ln15 = lane & 15, l16 = lane >> 4;
  const f32x4 zero4 = {0.f, 0.f, 0.f, 0.f};

  const int t = tid >> 2, q4 = tid & 3, c0 = q4 * 48;
  const int tr = t >> 3, tc = t & 7;
  const int sh = (wh*8 + tr + 4) & 127, sw = (ww*8 + tc + 4) & 127;
  const float* xrow = xb + (size_t)((((b << 7) + sh) << 7) + sw) * 192;
  float lnm, lnr;
  const int hswz = (t & 7) << 4;

  {
    float4 xt[12];
    float s = 0.f, s2 = 0.f;
    #pragma unroll
    for (int i = 0; i < 12; i++){
      xt[i] = *(const float4*)(xrow + c0 + i*4);
      s  += xt[i].x + xt[i].y + xt[i].z + xt[i].w;
      s2 += xt[i].x*xt[i].x + xt[i].y*xt[i].y + xt[i].z*xt[i].z + xt[i].w*xt[i].w;
    }
    s  += __shfl_xor(s, 1);  s  += __shfl_xor(s, 2);
    s2 += __shfl_xor(s2, 1); s2 += __shfl_xor(s2, 2);
    lnm = s * (1.f/192.f);
    lnr = rsqrtf(s2 * (1.f/192.f) - lnm*lnm + 1e-5f);
    #pragma unroll
    for (int i = 0; i < 12; i++){
      int cb = c0 + i*4;
      float4 w4 = *(const float4*)(ln1w + cb);
      float4 b4 = *(const float4*)(ln1b + cb);
      uint2 u;
      u.x = pack2((xt[i].x - lnm)*lnr*w4.x + b4.x, (xt[i].y - lnm)*lnr*w4.y + b4.y);
      u.y = pack2((xt[i].z - lnm)*lnr*w4.z + b4.z, (xt[i].w - lnm)*lnr*w4.w + b4.w);
      *(uint2*)(smem + t*384 + ((cb*2) ^ hswz)) = u;
    }
    if (q4 == 0){
      int gh = wh*8 + tr, gw = ww*8 + tc;
      regions[t] = (gh < 120 ? 0 : (gh < 124 ? 1 : 2)) * 3 + (gw < 120 ? 0 : (gw < 124 ? 1 : 2));
    }
  }
  __syncthreads();

  f32x4 pacc[4][3];
  #pragma unroll
  for (int mt = 0; mt < 4; mt++)
    #pragma unroll
    for (int nt = 0; nt < 3; nt++)
      pacc[mt][nt] = zero4;

  const float scale = 0.17677669529663687f;

  #pragma unroll 1
  for (int hp = 0; hp < 3; hp++){
    const int h0 = hp * 2;
    if (hp){
      __syncthreads();
      #pragma unroll 2
      for (int i = 0; i < 12; i++){
        int cb = c0 + i*4;
        float4 xi = *(const float4*)(xrow + cb);
        float4 w4 = *(const float4*)(ln1w + cb);
        float4 b4 = *(const float4*)(ln1b + cb);
        uint2 u;
        u.x = pack2((xi.x - lnm)*lnr*w4.x + b4.x, (xi.y - lnm)*lnr*w4.y + b4.y);
        u.y = pack2((xi.z - lnm)*lnr*w4.z + b4.z, (xi.w - lnm)*lnr*w4.w + b4.w);
        *(uint2*)(smem + t*384 + ((cb*2) ^ hswz)) = u;
      }
      __syncthreads();
    }

    #pragma unroll 1
    for (int tt0 = 0; tt0 < 3; tt0++){
      const int tt = wv*3 + tt0;
      const int which = tt >> 2, sub = tt & 3;
      const int colb = which*192 + h0*32 + sub*16;
      const unsigned short* bp = qkvB + (size_t)(colb + ln15)*192 + l16*8;
      bf16x8 bw[6];
      #pragma unroll
      for (int ks = 0; ks < 6; ks++) bw[ks] = *(const bf16x8*)(bp + ks*32);
      f32x4 acc[4];
      #pragma unroll
      for (int mt = 0; mt < 4; mt++){
        acc[mt] = zero4;
        const int arow = mt*16 + ln15;
        const unsigned char* ap = smem + arow*384;
        const int aswz = (arow & 7) << 4;
        #pragma unroll
        for (int ks = 0; ks < 6; ks++){
          bf16x8 af = *(const bf16x8*)(ap + ((ks*64 + l16*16) ^ aswz));
          acc[mt] = MFMA16(af, bw[ks], acc[mt]);
        }
      }
      const float bias = qkvb[colb + ln15];
      const int local = sub*16 + ln15;
      const int hl = local >> 5, d = local & 31;
      if (which == 2){
        unsigned char* vbase = smem + 40960 + hl*4096 + d*128;
        const int vswz = (d & 7) << 4;
        #pragma unroll
        for (int mt = 0; mt < 4; mt++){
          const int tk2 = (mt*16 + l16*4) * 2;
          *(unsigned int*)(vbase + ((tk2    ) ^ vswz)) = pack2(acc[mt][0] + bias, acc[mt][1] + bias);
          *(unsigned int*)(vbase + ((tk2 + 4) ^ vswz)) = pack2(acc[mt][2] + bias, acc[mt][3] + bias);
        }
      } else {
        unsigned char* qkb = smem + 24576 + hl*8192;
        const int koff = which ? 64 : 0;
        const float mul = which ? 1.f : scale;
        #pragma unroll
        for (int mt = 0; mt < 4; mt++)
          #pragma unroll
          for (int reg = 0; reg < 4; reg++){
            const int tok = mt*16 + l16*4 + reg;
            *(unsigned short*)(qkb + tok*128 + ((koff + d*2) ^ ((tok & 7) << 4))) =
                f2bf((acc[mt][reg] + bias) * mul);
          }
      }
    }
    __syncthreads();

    #pragma unroll 1
    for (int e = 0; e < 2; e++){
      const int h = h0 + e;
      const unsigned char* qkb = smem + 24576 + e*8192;
      const int arow = wv*16 + ln15;
      const int aswz = (arow & 7) << 4;
      bf16x8 aq = *(const bf16x8*)(qkb + arow*128 + ((l16*16) ^ aswz));
      f32x4 sacc[4];
      #pragma unroll
      for (int nt = 0; nt < 4; nt++){
        const int brow = nt*16 + ln15;
        bf16x8 bk = *(const bf16x8*)(qkb + brow*128 + ((64 + l16*16) ^ ((brow & 7) << 4)));
        sacc[nt] = MFMA16(aq, bk, zero4);
      }
      #pragma unroll
      for (int nt = 0; nt < 4; nt++){
        const int j_tok = nt*16 + ln15;
        const int rj = j_tok >> 3, cj = j_tok & 7;
        const int regj = regions[j_tok];
        #pragma unroll
        for (int reg = 0; reg < 4; reg++){
          const int i_tok = wv*16 + l16*4 + reg;
          const int ri = i_tok >> 3, ci = i_tok & 7;
          float bias = rpb[((ri - rj + 7)*15 + (ci - cj + 7))*6 + h];
          sacc[nt][reg] += bias + ((regions[i_tok] == regj) ? 0.f : -100.f);
        }
      }
      float mx[4], sum[4];
      #pragma unroll
      for (int reg = 0; reg < 4; reg++){
        float m = fmaxf(fmaxf(sacc[0][reg], sacc[1][reg]), fmaxf(sacc[2][reg], sacc[3][reg]));
        m = fmaxf(m, __shfl_xor(m, 1));
        m = fmaxf(m, __shfl_xor(m, 2));
        m = fmaxf(m, __shfl_xor(m, 4));
        m = fmaxf(m, __shfl_xor(m, 8));
        mx[reg] = m; sum[reg] = 0.f;
      }
      #pragma unroll
      for (int nt = 0; nt < 4; nt++)
        #pragma unroll
        for (int reg = 0; reg < 4; reg++){
          float ex = __expf(sacc[nt][reg] - mx[reg]);
          sacc[nt][reg] = ex;
          sum[reg] += ex;
        }
      #pragma unroll
      for (int reg = 0; reg < 4; reg++){
        float sm = sum[reg];
        sm += __shfl_xor(sm, 1);
        sm += __shfl_xor(sm, 2);
        sm += __shfl_xor(sm, 4);
        sm += __shfl_xor(sm, 8);
        sum[reg] = __builtin_amdgcn_rcpf(sm);
      }
      #pragma unroll
      for (int nt = 0; nt < 4; nt++)
        #pragma unroll
        for (int reg = 0; reg < 4; reg++){
          const int tok = wv*16 + l16*4 + reg;
          *(unsigned short*)(smem + tok*128 + (((nt*16 + ln15)*2) ^ ((tok & 7) << 4))) =
              f2bf(sacc[nt][reg] * sum[reg]);
        }
      f32x4 cacc[2] = {zero4, zero4};
      #pragma unroll
      for (int ks = 0; ks < 2; ks++){
        bf16x8 pa = *(const bf16x8*)(smem + arow*128 + ((ks*64 + l16*16) ^ aswz));
        #pragma unroll
        for (int nt2 = 0; nt2 < 2; nt2++){
          const int drow = nt2*16 + ln15;
          bf16x8 bv = *(const bf16x8*)(smem + 40960 + e*4096 + drow*128 +
                                       ((ks*64 + l16*16) ^ ((drow & 7) << 4)));
          cacc[nt2] = MFMA16(pa, bv, cacc[nt2]);
        }
      }
      #pragma unroll
      for (int nt2 = 0; nt2 < 2; nt2++)
        #pragma unroll
        for (int reg = 0; reg < 4; reg++){
          const int tok = wv*16 + l16*4 + reg;
          const int col = e*32 + nt2*16 + ln15;
          *(unsigned short*)(smem + 8192 + tok*128 + ((col*2) ^ ((tok & 7) << 4))) =
              f2bf(cacc[nt2][reg]);
        }
    }
    __syncthreads();

    #pragma unroll
    for (int ks = 0; ks < 2; ks++){
      bf16x8 bw3[3];
      #pragma unroll
      for (int nt3 = 0; nt3 < 3; nt3++)
        bw3[nt3] = *(const bf16x8*)(projB + (size_t)(wv*48 + nt3*16 + ln15)*192 + h0*32 + ks*32 + l16*8);
      #pragma unroll
      for (int mt = 0; mt < 4; mt++){
        const int crow = mt*16 + ln15;
        bf16x8 ac = *(const bf16x8*)(smem + 8192 + crow*128 + ((ks*64 + l16*16) ^ ((crow & 7) << 4)));
        #pragma unroll
        for (int nt3 = 0; nt3 < 3; nt3++)
          pacc[mt][nt3] = MFMA16(ac, bw3[nt3], pacc[mt][nt3]);
      }
    }
  }
  __syncthreads();

  #pragma unroll
  for (int nt3 = 0; nt3 < 3; nt3++){
    const int col4 = (wv*48 + nt3*16 + ln15) * 4;
    #pragma unroll
    for (int mt = 0; mt < 4; mt++)
      #pragma unroll
      for (int reg = 0; reg < 4; reg++){
        const int row = mt*16 + l16*4 + reg;
        *(float*)(smem + row*768 + (col4 ^ ((row & 7) << 4))) = pacc[mt][nt3][reg];
      }
  }
  __syncthreads();
  {
    #pragma unroll
    for (int i = 0; i < 12; i++){
      const int id = i*256 + tid;
      const int tok = id / 48, c4 = id - tok*48;
      const int trr = tok >> 3, tcc = tok & 7;
      const int shh = (wh*8 + trr + 4) & 127, sww = (ww*8 + tcc + 4) & 127;
      const size_t goff = ((size_t)((((b << 7) + shh) << 7) + sww)) * 192 + c4*4;
      float4 pv  = *(const float4*)(smem + tok*768 + ((c4*16) ^ ((tok & 7) << 4)));
      float4 xr  = *(const float4*)(xb + goff);
      float4 pb4 = *(const float4*)(projb + c4*4);
      float4 o;
      o.x = xr.x + pv.x + pb4.x;
      o.y = xr.y + pv.y + pb4.y;
      o.z = xr.z + pv.z + pb4.z;
      o.w = xr.w + pv.w + pb4.w;
      *(float4*)(xb2 + goff) = o;
    }
  }
}

// ---------------- fused MLP (r6 structure + cheap GELU) ----------------
__launch_bounds__(256, 3)
__global__ void mlp_kernel(const float* __restrict__ xb, float* __restrict__ xb2,
                           const float* __restrict__ ln2w, const float* __restrict__ ln2b,
                           const unsigned short* __restrict__ fc1B, const float* __restrict__ fc1b,
                           const unsigned short* __restrict__ fc2B, const float* __restrict__ fc2b,
                           float* __restrict__ outp, const int fuse){
  __shared__ __align__(16) unsigned char smem[49152];

  const int tid = threadIdx.x;
  const int lane = tid & 63, wv = tid >> 6;
  const int ln15 = lane & 15, l16 = lane >> 4;
  const size_t p0 = (size_t)blockIdx.x * 64;
  const f32x4 zero4 = {0.f, 0.f, 0.f, 0.f};

  const int t = tid >> 2, q4 = tid & 3, c0 = q4 * 48;
  const int hswz = (t & 7) << 4;
  const float* xrow2 = xb2 + (p0 + t)*192;

  {
    float4 xt[12];
    float s = 0.f, s2 = 0.f;
    #pragma unroll
    for (int i = 0; i < 12; i++){
      xt[i] = *(const float4*)(xrow2 + c0 + i*4);
      s  += xt[i].x + xt[i].y + xt[i].z + xt[i].w;
      s2 += xt[i].x*xt[i].x + xt[i].y*xt[i].y + xt[i].z*xt[i].z + xt[i].w*xt[i].w;
    }
    s  += __shfl_xor(s, 1);  s  += __shfl_xor(s, 2);
    s2 += __shfl_xor(s2, 1); s2 += __shfl_xor(s2, 2);
    const float mean = s * (1.f/192.f);
    const float rstd = rsqrtf(s2 * (1.f/192.f) - mean*mean + 1e-5f);
    #pragma unroll
    for (int i = 0; i < 12; i++){
      int cb = c0 + i*4;
      float4 w4 = *(const float4*)(ln2w + cb);
      float4 b4 = *(const float4*)(ln2b + cb);
      uint2 u;
      u.x = pack2((xt[i].x - mean)*rstd*w4.x + b4.x, (xt[i].y - mean)*rstd*w4.y + b4.y);
      u.y = pack2((xt[i].z - mean)*rstd*w4.z + b4.z, (xt[i].w - mean)*rstd*w4.w + b4.w);
      *(uint2*)(smem + t*384 + ((cb*2) ^ hswz)) = u;
    }
  }
  __syncthreads();

  f32x4 o2[4][3];
  #pragma unroll
  for (int mt = 0; mt < 4; mt++)
    #pragma unroll
    for (int nt = 0; nt < 3; nt++)
      o2[mt][nt] = zero4;

  {
    const unsigned short* bp1 = fc1B + (size_t)(wv*16 + ln15)*192 + l16*8;
    bf16x8 w1[6];
    #pragma unroll
    for (int ks = 0; ks < 6; ks++) w1[ks] = *(const bf16x8*)(bp1 + ks*32);
    const float4 b1 = *(const float4*)(fc1b + wv*16 + l16*4);
    unsigned char* hb = smem + 24576;
    #pragma unroll
    for (int mt = 0; mt < 4; mt++){
      f32x4 facc = zero4;
      const int arow = mt*16 + ln15;
      const unsigned char* ap = smem + arow*384;
      const int aswz = (arow & 7) << 4;
      #pragma unroll
      for (int ks = 0; ks < 6; ks++){
        bf16x8 af = *(const bf16x8*)(ap + ((ks*64 + l16*16) ^ aswz));
        facc = MFMA16(w1[ks], af, facc);
      }
      s16x4 hv;
      hv.x = (short)f2bf(gelu_f(facc[0] + b1.x));
      hv.y = (short)f2bf(gelu_f(facc[1] + b1.y));
      hv.z = (short)f2bf(gelu_f(facc[2] + b1.z));
      hv.w = (short)f2bf(gelu_f(facc[3] + b1.w));
      *(s16x4*)(hb + arow*128 + ((wv*32 + l16*8) ^ aswz)) = hv;
    }
  }
  __syncthreads();

  #pragma unroll 1
  for (int ch = 1; ch < 12; ch++){
    bf16x8 w2[3][2];
    #pragma unroll
    for (int nt3 = 0; nt3 < 3; nt3++)
      #pragma unroll
      for (int ks = 0; ks < 2; ks++)
        w2[nt3][ks] = *(const bf16x8*)(fc2B + (size_t)(wv*48 + nt3*16 + ln15)*768 +
                                       (ch-1)*64 + ks*32 + l16*8);
    const unsigned short* bp1 = fc1B + (size_t)(ch*64 + wv*16 + ln15)*192 + l16*8;
    bf16x8 w1[6];
    #pragma unroll
    for (int ks = 0; ks < 6; ks++) w1[ks] = *(const bf16x8*)(bp1 + ks*32);
    const float4 b1 = *(const float4*)(fc1b + ch*64 + wv*16 + l16*4);

    {
      const unsigned char* hb = smem + 24576 + ((ch-1)&1)*8192;
      #pragma unroll
      for (int mt = 0; mt < 4; mt++){
        const int brow = mt*16 + ln15;
        const unsigned char* bp = hb + brow*128;
        const int bswz = (brow & 7) << 4;
        #pragma unroll
        for (int ks = 0; ks < 2; ks++){
          bf16x8 hf = *(const bf16x8*)(bp + ((ks*64 + l16*16) ^ bswz));
          #pragma unroll
          for (int nt3 = 0; nt3 < 3; nt3++)
            o2[mt][nt3] = MFMA16(w2[nt3][ks], hf, o2[mt][nt3]);
        }
      }
    }
    {
      unsigned char* hb = smem + 24576 + (ch&1)*8192;
      #pragma unroll
      for (int mt = 0; mt < 4; mt++){
        f32x4 facc = zero4;
        const int arow = mt*16 + ln15;
        const unsigned char* ap = smem + arow*384;
        const int aswz = (arow & 7) << 4;
        #pragma unroll
        for (int ks = 0; ks < 6; ks++){
          bf16x8 af = *(const bf16x8*)(ap + ((ks*64 + l16*16) ^ aswz));
          facc = MFMA16(w1[ks], af, facc);
        }
        s16x4 hv;
        hv.x = (short)f2bf(gelu_f(facc[0] + b1.x));
        hv.y = (short)f2bf(gelu_f(facc[1] + b1.y));
        hv.z = (short)f2bf(gelu_f(facc[2] + b1.z));
        hv.w = (short)f2bf(gelu_f(facc[3] + b1.w));
        *(s16x4*)(hb + arow*128 + ((wv*32 + l16*8) ^ aswz)) = hv;
      }
    }
    __syncthreads();
  }

  {
    bf16x8 w2[3][2];
    #pragma unroll
    for (int nt3 = 0; nt3 < 3; nt3++)
      #pragma unroll
      for (int ks = 0; ks < 2; ks++)
        w2[nt3][ks] = *(const bf16x8*)(fc2B + (size_t)(wv*48 + nt3*16 + ln15)*768 +
                                       11*64 + ks*32 + l16*8);
    const unsigned char* hb = smem + 24576 + 8192;
    #pragma unroll
    for (int mt = 0; mt < 4; mt++){
      const int brow = mt*16 + ln15;
      const unsigned char* bp = hb + brow*128;
      const int bswz = (brow & 7) << 4;
      #pragma unroll
      for (int ks = 0; ks < 2; ks++){
        bf16x8 hf = *(const bf16x8*)(bp + ((ks*64 + l16*16) ^ bswz));
        #pragma unroll
        for (int nt3 = 0; nt3 < 3; nt3++)
          o2[mt][nt3] = MFMA16(w2[nt3][ks], hf, o2[mt][nt3]);
      }
    }
  }
  __syncthreads();

  #pragma unroll
  for (int mt = 0; mt < 4; mt++){
    const int tok = mt*16 + ln15;
    const int tswz = (tok & 7) << 4;
    unsigned char* rp = smem + tok*768;
    #pragma unroll
    for (int nt3 = 0; nt3 < 3; nt3++)
      *(f32x4*)(rp + ((wv*192 + nt3*64 + l16*16) ^ tswz)) = o2[mt][nt3];
  }
  __syncthreads();

  const float* xrow = xb + (p0 + t)*192;
  if (!fuse){
    float* orow = xb2 + (p0 + t)*192;
    #pragma unroll
    for (int i = 0; i < 12; i++){
      float4 mv  = *(const float4*)(smem + t*768 + ((c0*4 + i*16) ^ hswz));
      float4 x2  = *(const float4*)(xrow2 + c0 + i*4);
      float4 xr  = *(const float4*)(xrow + c0 + i*4);
      float4 fb4 = *(const float4*)(fc2b + c0 + i*4);
      float4 o;
      o.x = x2.x + xr.x + fb4.x + mv.x;
      o.y = x2.y + xr.y + fb4.y + mv.y;
      o.z = x2.z + xr.z + fb4.z + mv.z;
      o.w = x2.w + xr.w + fb4.w + mv.w;
      *(float4*)(orow + c0 + i*4) = o;
    }
  } else {
    #pragma unroll
    for (int i = 0; i < 12; i++){
      const int off = (c0*4 + i*16) ^ hswz;
      float4 mv  = *(const float4*)(smem + t*768 + off);
      float4 x2  = *(const float4*)(xrow2 + c0 + i*4);
      float4 xr  = *(const float4*)(xrow + c0 + i*4);
      float4 fb4 = *(const float4*)(fc2b + c0 + i*4);
      float4 o;
      o.x = fminf(fmaxf(x2.x + xr.x + fb4.x + mv.x, -10.f), 10.f);
      o.y = fminf(fmaxf(x2.y + xr.y + fb4.y + mv.y, -10.f), 10.f);
      o.z = fminf(fmaxf(x2.z + xr.z + fb4.z + mv.z, -10.f), 10.f);
      o.w = fminf(fmaxf(x2.w + xr.w + fb4.w + mv.w, -10.f), 10.f);
      *(float4*)(smem + t*768 + off) = o;
    }
    __syncthreads();
    const int bidx   = (int)(p0 >> 14);
    const int imgoff = (int)(p0 & 16383);
    #pragma unroll 1
    for (int i = 0; i < 12; i++){
      const int id = i*256 + tid;
      const int c = id >> 4, pq = id & 15;
      float4 o4;
      o4.x = *(const float*)(smem + (pq*4    )*768 + ((c*4) ^ (((pq*4    ) & 7) << 4)));
      o4.y = *(const float*)(smem + (pq*4 + 1)*768 + ((c*4) ^ (((pq*4 + 1) & 7) << 4)));
      o4.z = *(const float*)(smem + (pq*4 + 2)*768 + ((c*4) ^ (((pq*4 + 2) & 7) << 4)));
      o4.w = *(const float*)(smem + (pq*4 + 3)*768 + ((c*4) ^ (((pq*4 + 3) & 7) << 4)));
      *(float4*)(outp + (((size_t)(bidx*192 + c)) << 14) + imgoff + pq*4) = o4;
    }
  }
}

// ---------------- final NHWC -> NCHW + clamp (legacy path only) ----------------
__global__ void final_k(const float* __restrict__ xb2, float* __restrict__ out){
  __shared__ float tile[192*64];
  int blk = blockIdx.x, tid = threadIdx.x;
  int b = blk >> 8, p0 = (blk & 255) * 64;
  #pragma unroll 1
  for (int i = 0; i < 12; i++){
    int idx4 = i*256 + tid;
    int tt = idx4 / 48, c4 = idx4 - tt*48;
    int cb = c4 * 4;
    float4 v = *(const float4*)(xb2 + ((size_t)blk*64 + tt)*192 + cb);
    tile[(cb  )*64 + ((tt + cb    ) & 63)] = v.x;
    tile[(cb+1)*64 + ((tt + cb + 1) & 63)] = v.y;
    tile[(cb+2)*64 + ((tt + cb + 2) & 63)] = v.z;
    tile[(cb+3)*64 + ((tt + cb + 3) & 63)] = v.w;
  }
  __syncthreads();
  #pragma unroll 1
  for (int i = 0; i < 12; i++){
    int idx4 = i*256 + tid;
    int c = idx4 >> 4, pq = idx4 & 15;
    int pb_ = pq*4;
    float4 o;
    o.x = tile[c*64 + ((pb_     + c) & 63)];
    o.y = tile[c*64 + ((pb_ + 1 + c) & 63)];
    o.z = tile[c*64 + ((pb_ + 2 + c) & 63)];
    o.w = tile[c*64 + ((pb_ + 3 + c) & 63)];
    o.x = fminf(fmaxf(o.x, -10.f), 10.f);
    o.y = fminf(fmaxf(o.y, -10.f), 10.f);
    o.z = fminf(fmaxf(o.z, -10.f), 10.f);
    o.w = fminf(fmaxf(o.w, -10.f), 10.f);
    *(float4*)(out + (((size_t)b*192 + c) << 14) + p0 + pb_) = o;
  }
}

extern "C" void kernel_launch(void* const* d_in, const int* in_sizes, int n_in,
                              void* d_out, int out_size, void* d_ws, size_t ws_size,
                              hipStream_t stream){
  (void)in_sizes; (void)n_in; (void)out_size;
  const float* x     = (const float*)d_in[0];
  const float* gnw   = (const float*)d_in[1];
  const float* gnb   = (const float*)d_in[2];
  const float* ln1w  = (const float*)d_in[3];
  const float* ln1b  = (const float*)d_in[4];
  const float* qkvw  = (const float*)d_in[5];
  const float* qkvb  = (const float*)d_in[6];
  const float* projw = (const float*)d_in[7];
  const float* projb = (const float*)d_in[8];
  const float* rpb   = (const float*)d_in[9];
  const float* ln2w  = (const float*)d_in[10];
  const float* ln2b  = (const float*)d_in[11];
  const float* fc1w  = (const float*)d_in[12];
  const float* fc1b  = (const float*)d_in[13];
  const float* fc2w  = (const float*)d_in[14];
  const float* fc2b  = (const float*)d_in[15];
  float* out = (float*)d_out;

  float* ws    = (float*)d_ws;
  float* xb2   = ws;                       // [B,H,W,C] fp32 (100 MB)
  float* part  = xb2  + 25165824;
  float* stats = part + 3072;
  unsigned short* qkvB = (unsigned short*)(stats + 16);  // [576][192] bf16
  unsigned short* projB = qkvB + 110592;                 // [192][192]
  unsigned short* fc1B  = projB + 36864;                 // [768][192]
  unsigned short* fc2B  = fc1B + 147456;                 // [192][768]

  const int mode = (ws_size >= 252555328ULL) ? 2 : ((ws_size >= 202223680ULL) ? 1 : 0);
  float* xb = (mode >= 1) ? (ws + 25390096) : out;
  unsigned short* ctxg = (unsigned short*)(ws + 50555920);   // 131072 x 192 bf16 (50 MB)

  transpose_cast_all<<<1728, 256, 0, stream>>>(qkvw, projw, fc1w, fc2w, qkvB, projB, fc1B, fc2B);
  gn_partial<<<1536, 256, 0, stream>>>(x, part);
  gn_final<<<8, 64, 0, stream>>>(part, stats);
  gn_apply<<<2048, 256, 0, stream>>>(x, stats, gnw, gnb, xb);
  if (mode == 2){
    attn_qkv_kernel<<<2048, 256, 0, stream>>>(xb, ctxg, ln1w, ln1b, qkvB, qkvb, rpb);
    proj_kernel<<<2048, 256, 0, stream>>>(ctxg, xb, xb2, projB, projb);
  } else {
    attn_kernel<<<2048, 256, 0, stream>>>(xb, xb2, ln1w, ln1b, qkvB, qkvb, projB, projb, rpb);
  }
  mlp_kernel<<<2048, 256, 0, stream>>>(xb, xb2, ln2w, ln2b, fc1B, fc1b, fc2B, fc2b, out, mode >= 1);
  if (mode == 0) final_k<<<2048, 256, 0, stream>>>(xb2, out);
}